// Round 5
// baseline (592.000 us; speedup 1.0000x reference)
//
#include <hip/hip_runtime.h>
#include <cstddef>

#define N_NODES_C 100000
#define N_EDGES_C 1600000

#define NPB 64               // nodes per block tile (= GEMM M-tile)
#define NB 1563              // ceil(100000/64)
#define SENT_ROW 100000      // zeroed sentinel row in feature tables

#define NCB 98               // coarse buckets of 1024 nodes: ceil(100000/1024)
#define K2_EPB 8192          // edges per coarse-scatter block
#define K2_BLOCKS 196        // ceil(1600000/8192)

#define CONV_BLOCKS 12500    // 3.2M float4 / 256
#define WB_BLOCKS 512        // weight transpose blocks
#define CH_BLOCKS 1563       // 400128 int4 slots / 256 (coarse hist)

typedef unsigned short u16;
typedef __attribute__((ext_vector_type(8))) short bf16x8;
typedef __attribute__((ext_vector_type(4))) float f32x4;

__device__ __forceinline__ u16 f2bf(float f) {
    unsigned u = __float_as_uint(f);
    u += 0x7fffu + ((u >> 16) & 1);  // round-to-nearest-even
    return (u16)(u >> 16);
}
__device__ __forceinline__ float lo16f(unsigned v) {
    return __uint_as_float(v << 16);
}
__device__ __forceinline__ float hi16f(unsigned v) {
    return __uint_as_float(v & 0xffff0000u);
}

// ---------------------------------------------------------------------------
// Front fused: x fp32->bf16 convert | weight transpose+convert | coarse
// (node>>10) histogram via LDS | sentinel-row zeroing
// ---------------------------------------------------------------------------

__global__ __launch_bounds__(256) void front_fused(
    const float* __restrict__ x, const int* __restrict__ dst,
    const float* __restrict__ W1l, const float* __restrict__ W1r,
    const float* __restrict__ W2l, const float* __restrict__ W2r,
    u16* __restrict__ x_bf, u16* __restrict__ T1l, u16* __restrict__ T1r,
    u16* __restrict__ T2l, u16* __restrict__ T2r,
    int* __restrict__ chist, u16* __restrict__ p2z) {
    const int b = blockIdx.x;
    const int t = threadIdx.x;
    if (b < CONV_BLOCKS) {
        int i = b * 256 + t;
        if (i < 3200000) {
            float4 v = ((const float4*)x)[i];
            ushort4 o;
            o.x = f2bf(v.x); o.y = f2bf(v.y); o.z = f2bf(v.z); o.w = f2bf(v.w);
            ((ushort4*)x_bf)[i] = o;
        }
    } else if (b < CONV_BLOCKS + WB_BLOCKS) {
        int id = (b - CONV_BLOCKS) * 256 + t;  // 0..131071
        int which = id >> 15;
        int r = id & 32767;
        if (which == 0) {        // [128][256] -> [256][128]
            int n = r >> 7, k = r & 127;
            T1l[r] = f2bf(W1l[k * 256 + n]);
        } else if (which == 1) {
            int n = r >> 7, k = r & 127;
            T1r[r] = f2bf(W1r[k * 256 + n]);
        } else if (which == 2) {  // [256][128] -> [128][256]
            int n = r >> 8, k = r & 255;
            T2l[r] = f2bf(W2l[k * 128 + n]);
        } else {
            int n = r >> 8, k = r & 255;
            T2r[r] = f2bf(W2r[k * 128 + n]);
        }
    } else if (b < CONV_BLOCKS + WB_BLOCKS + CH_BLOCKS) {
        __shared__ int hist[NCB];
        for (int j = t; j < NCB; j += 256) hist[j] = 0;
        __syncthreads();
        int i = (b - CONV_BLOCKS - WB_BLOCKS) * 256 + t;  // int4 index
        if (i * 4 < N_EDGES_C) {
            int4 d = ((const int4*)dst)[i];
            atomicAdd(&hist[d.x >> 10], 1);
            atomicAdd(&hist[d.y >> 10], 1);
            atomicAdd(&hist[d.z >> 10], 1);
            atomicAdd(&hist[d.w >> 10], 1);
        }
        __syncthreads();
        for (int j = t; j < NCB; j += 256) {
            int c = hist[j];
            if (c) atomicAdd(&chist[j], c);
        }
    } else {
        // zero the sentinel rows (row SENT_ROW of x_bf and p2)
        uint4 z; z.x = 0; z.y = 0; z.z = 0; z.w = 0;
        if (t < 16)
            ((uint4*)(x_bf + (size_t)SENT_ROW * 128))[t] = z;
        else if (t < 32)
            ((uint4*)(p2z + (size_t)SENT_ROW * 128))[t - 16] = z;
    }
}

// ---------------------------------------------------------------------------
// Coarse scan: exclusive scan of the 98 coarse-bucket counts.
// ---------------------------------------------------------------------------

__global__ __launch_bounds__(128) void cscan(const int* __restrict__ chist,
                                             int* __restrict__ cbase,
                                             int* __restrict__ ccursor) {
    __shared__ int s[128];
    int t = threadIdx.x;
    int v = (t < NCB) ? chist[t] : 0;
    s[t] = v;
    __syncthreads();
    for (int off = 1; off < 128; off <<= 1) {
        int u = (t >= off) ? s[t - off] : 0;
        __syncthreads();
        s[t] += u;
        __syncthreads();
    }
    if (t < NCB) {
        int e = s[t] - v;
        cbase[t] = e;
        ccursor[t] = e;
    }
}

// ---------------------------------------------------------------------------
// K2: coarse scatter. Block-local LDS counting-sort of 8192 edges by coarse
// bucket, then contiguous run-writes (avg ~335B/run) into epkt2.
// packed = (local10 << 17) | src17
// ---------------------------------------------------------------------------

__global__ __launch_bounds__(1024) void coarse_scatter(
    const int* __restrict__ src, const int* __restrict__ dst,
    int* __restrict__ ccursor, unsigned* __restrict__ epkt2) {
    __shared__ unsigned spkt[K2_EPB];
    __shared__ unsigned char scb[K2_EPB];
    __shared__ int hist[NCB], lstart[NCB], lcur[NCB], grun[NCB], stmp[NCB];

    const int t = threadIdx.x;
    const int e0 = blockIdx.x * K2_EPB;
    const int cnt = min(K2_EPB, N_EDGES_C - e0);

    if (t < NCB) hist[t] = 0;
    __syncthreads();

    int4 dd[2], ss[2];
    int vi[2];
#pragma unroll
    for (int r = 0; r < 2; ++r) {
        int i = (e0 >> 2) + r * 1024 + t;  // int4 index
        vi[r] = (i * 4 < N_EDGES_C);
        if (vi[r]) {
            dd[r] = ((const int4*)dst)[i];
            ss[r] = ((const int4*)src)[i];
            atomicAdd(&hist[dd[r].x >> 10], 1);
            atomicAdd(&hist[dd[r].y >> 10], 1);
            atomicAdd(&hist[dd[r].z >> 10], 1);
            atomicAdd(&hist[dd[r].w >> 10], 1);
        }
    }
    __syncthreads();

    if (t < NCB) stmp[t] = hist[t];
    __syncthreads();
    for (int off = 1; off < NCB; off <<= 1) {
        int v = 0;
        if (t < NCB && t >= off) v = stmp[t - off];
        __syncthreads();
        if (t < NCB) stmp[t] += v;
        __syncthreads();
    }
    if (t < NCB) {
        int excl = stmp[t] - hist[t];
        lstart[t] = excl;
        lcur[t] = excl;
        if (hist[t]) grun[t] = atomicAdd(&ccursor[t], hist[t]);
    }
    __syncthreads();

#pragma unroll
    for (int r = 0; r < 2; ++r) {
        if (vi[r]) {
            int4 d = dd[r];
            int4 s4 = ss[r];
            {
                int cb = d.x >> 10;
                int pos = atomicAdd(&lcur[cb], 1);
                spkt[pos] = ((unsigned)(d.x & 1023) << 17) | (unsigned)s4.x;
                scb[pos] = (unsigned char)cb;
            }
            {
                int cb = d.y >> 10;
                int pos = atomicAdd(&lcur[cb], 1);
                spkt[pos] = ((unsigned)(d.y & 1023) << 17) | (unsigned)s4.y;
                scb[pos] = (unsigned char)cb;
            }
            {
                int cb = d.z >> 10;
                int pos = atomicAdd(&lcur[cb], 1);
                spkt[pos] = ((unsigned)(d.z & 1023) << 17) | (unsigned)s4.z;
                scb[pos] = (unsigned char)cb;
            }
            {
                int cb = d.w >> 10;
                int pos = atomicAdd(&lcur[cb], 1);
                spkt[pos] = ((unsigned)(d.w & 1023) << 17) | (unsigned)s4.w;
                scb[pos] = (unsigned char)cb;
            }
        }
    }
    __syncthreads();

#pragma unroll
    for (int k = 0; k < K2_EPB / 1024; ++k) {
        int i = k * 1024 + t;
        if (i < cnt) {
            int cb = scb[i];
            epkt2[grun[cb] + (i - lstart[cb])] = spkt[i];
        }
    }
}

// ---------------------------------------------------------------------------
// K3: fine sort within each coarse bucket. One block per coarse bucket
// (~16.3K edges, L2-resident window). Produces node-contiguous esrc plus
// deg[] and base[] (global = sorted-by-dst order).
// ---------------------------------------------------------------------------

__global__ __launch_bounds__(1024) void fine_sort(
    const int* __restrict__ cbase, const int* __restrict__ chist,
    const unsigned* __restrict__ epkt2, unsigned* __restrict__ esrc,
    int* __restrict__ deg, int* __restrict__ base) {
    __shared__ int hist[1024], lstart[1024], lcur[1024], stmp[1024];
    const int t = threadIdx.x;
    const int c = blockIdx.x;
    const int s0 = cbase[c];
    const int cnt = chist[c];

    hist[t] = 0;
    __syncthreads();

    for (int i = t; i < cnt; i += 1024)
        atomicAdd(&hist[epkt2[s0 + i] >> 17], 1);
    __syncthreads();

    stmp[t] = hist[t];
    __syncthreads();
    for (int off = 1; off < 1024; off <<= 1) {
        int v = (t >= off) ? stmp[t - off] : 0;
        __syncthreads();
        stmp[t] += v;
        __syncthreads();
    }
    int excl = stmp[t] - hist[t];
    lstart[t] = excl;
    lcur[t] = excl;
    int node = c * 1024 + t;
    if (node < N_NODES_C) {
        deg[node] = hist[t];
        base[node] = s0 + excl;
    }
    __syncthreads();

    for (int i = t; i < cnt; i += 1024) {
        unsigned p = epkt2[s0 + i];
        int pos = atomicAdd(&lcur[p >> 17], 1);
        esrc[s0 + pos] = p & 0x1ffffu;
    }
}

// ---------------------------------------------------------------------------
// Fused per-bucket kernel (512 thr = 8 waves, 4 blocks/CU = 32 waves/CU):
//   gather: mean_{src->node} x_bf -> meanS (LDS, chunk-swizzled)
//   xS: block's own x rows staged async (pre-swizzled source)
//   phase A: h = relu(meanS@W1l + xS@W1r + b1) -> hfrag (aliases meanS|xS)
//   phase B: p2 = h@W2l, outp = h@W2r + b2
// B-operand fragments read DIRECTLY from global (T tables are L2-hot,
// 64-128KB each) — no Bs LDS staging, no k-loop barriers. 3 barriers total.
// ---------------------------------------------------------------------------

__global__ __launch_bounds__(512, 8) void fused_gemm_agg(
    const u16* __restrict__ x_bf, const int* __restrict__ deg,
    const int* __restrict__ base, const unsigned* __restrict__ esrc,
    const u16* __restrict__ T1l, const u16* __restrict__ T1r,   // [256][128]
    const u16* __restrict__ T2l, const u16* __restrict__ T2r,   // [128][256]
    const float* __restrict__ b1, const float* __restrict__ b2,
    u16* __restrict__ p2, u16* __restrict__ outp, int M) {
    alignas(16) __shared__ u16 uni[64 * 256];  // 32KB: [meanS|xS] then hfrag

    u16* const meanS = uni;           // [64][128], 16B-chunk ^ (row&7)
    u16* const xS = uni + 64 * 128;   // [64][128], same swizzle
    u16* const hfrag = uni;           // phase-B alias (32KB)

    const int tid = threadIdx.x;
    const int lane = tid & 63;
    const int wave = tid >> 6;
    const int qm = lane & 15;
    const int quad = lane >> 4;
    const int b = blockIdx.x;
    const int m0 = b * 64;

    // ---- issue xS staging early (lands during gather) ----
#pragma unroll
    for (int r = 0; r < 2; ++r) {
        int c = r * 512 + tid;          // 1024 chunks of 16B
        int row = c >> 4, q16 = c & 15;
        __builtin_amdgcn_global_load_lds(
            (const __attribute__((address_space(1))) unsigned*)(
                x_bf + (size_t)(m0 + row) * 128 + ((q16 ^ (row & 7)) * 8)),
            (__attribute__((address_space(3))) unsigned*)(xS + c * 8), 16, 0, 0);
    }

    // ---- gather + mean -> meanS (bf16, swizzled) ----
    const int li8 = qm * 8;
    const int gbase = lane & 48;  // group base lane within wave

    for (int pass = 0; pass < 2; ++pass) {
        int n = pass * 32 + wave * 4 + quad;   // 0..63
        int node = m0 + n;
        int d = 0, s0 = 0;
        if (node < N_NODES_C) { d = deg[node]; s0 = base[node]; }
        int dmax = max(d, __shfl_xor(d, 16, 64));
        dmax = max(dmax, __shfl_xor(dmax, 32, 64));

        float a0 = 0.f, a1 = 0.f, a2 = 0.f, a3 = 0.f;
        float a4 = 0.f, a5 = 0.f, a6 = 0.f, a7 = 0.f;

        for (int j = 0; j < dmax; j += 16) {
            int jj = j + qm;
            unsigned sidx = (jj < d) ? esrc[s0 + jj] : (unsigned)SENT_ROW;
            for (int u = 0; u < 16 && j + u < dmax; u += 4) {
                unsigned i0 = __shfl(sidx, gbase + u, 64);
                unsigned i1 = __shfl(sidx, gbase + u + 1, 64);
                unsigned i2 = __shfl(sidx, gbase + u + 2, 64);
                unsigned i3 = __shfl(sidx, gbase + u + 3, 64);
                uint4 r0 = *(const uint4*)(x_bf + (size_t)i0 * 128 + li8);
                uint4 r1 = *(const uint4*)(x_bf + (size_t)i1 * 128 + li8);
                uint4 r2 = *(const uint4*)(x_bf + (size_t)i2 * 128 + li8);
                uint4 r3 = *(const uint4*)(x_bf + (size_t)i3 * 128 + li8);
                a0 += lo16f(r0.x); a1 += hi16f(r0.x);
                a2 += lo16f(r0.y); a3 += hi16f(r0.y);
                a4 += lo16f(r0.z); a5 += hi16f(r0.z);
                a6 += lo16f(r0.w); a7 += hi16f(r0.w);
                a0 += lo16f(r1.x); a1 += hi16f(r1.x);
                a2 += lo16f(r1.y); a3 += hi16f(r1.y);
                a4 += lo16f(r1.z); a5 += hi16f(r1.z);
                a6 += lo16f(r1.w); a7 += hi16f(r1.w);
                a0 += lo16f(r2.x); a1 += hi16f(r2.x);
                a2 += lo16f(r2.y); a3 += hi16f(r2.y);
                a4 += lo16f(r2.z); a5 += hi16f(r2.z);
                a6 += lo16f(r2.w); a7 += hi16f(r2.w);
                a0 += lo16f(r3.x); a1 += hi16f(r3.x);
                a2 += lo16f(r3.y); a3 += hi16f(r3.y);
                a4 += lo16f(r3.z); a5 += hi16f(r3.z);
                a6 += lo16f(r3.w); a7 += hi16f(r3.w);
            }
        }

        float inv = d > 0 ? 1.f / (float)d : 0.f;
        uint4 o;
        o.x = (unsigned)f2bf(a0 * inv) | ((unsigned)f2bf(a1 * inv) << 16);
        o.y = (unsigned)f2bf(a2 * inv) | ((unsigned)f2bf(a3 * inv) << 16);
        o.z = (unsigned)f2bf(a4 * inv) | ((unsigned)f2bf(a5 * inv) << 16);
        o.w = (unsigned)f2bf(a6 * inv) | ((unsigned)f2bf(a7 * inv) << 16);
        *(uint4*)(meanS + n * 128 + ((qm ^ (n & 7)) * 8)) = o;
    }
    __syncthreads();   // meanS written, xS landed

    // ---------------- phase A: h tile (8 waves: 4M x 2N) ----------------
    const int wr0 = (wave >> 1) * 16;   // rows 0/16/32/48
    const int wc0 = (wave & 1) * 128;   // cols 0/128
    f32x4 acch[8];
#pragma unroll
    for (int j = 0; j < 8; ++j) acch[j] = (f32x4){0.f, 0.f, 0.f, 0.f};

#pragma unroll
    for (int mat = 0; mat < 2; ++mat) {
        const u16* __restrict__ W = mat ? T1r : T1l;
        const u16* Al = mat ? xS : meanS;
#pragma unroll
        for (int k0 = 0; k0 < 128; k0 += 32) {
            int ch0 = k0 >> 3;
            int rowA = wr0 + qm;
            bf16x8 af = *(const bf16x8*)(Al + rowA * 128 +
                                         (((ch0 + quad) ^ (rowA & 7)) * 8));
#pragma unroll
            for (int j = 0; j < 8; ++j) {
                int rB = wc0 + j * 16 + qm;
                bf16x8 bv = *(const bf16x8*)(W + (size_t)rB * 128 + k0 + quad * 8);
                acch[j] = __builtin_amdgcn_mfma_f32_16x16x32_bf16(af, bv,
                                                                  acch[j], 0, 0, 0);
            }
        }
    }
    __syncthreads();   // all phase-A LDS reads complete before hfrag overwrite

    // epilogue A: +b1, relu, write to hfrag (aliases meanS/xS — dead now)
#pragma unroll
    for (int j = 0; j < 8; ++j) {
        int n = wc0 + j * 16 + qm;
        float bb = b1[n];
        int ks = n >> 5, quadB = (n >> 3) & 3, jB = n & 7;
#pragma unroll
        for (int r = 0; r < 4; ++r) {
            int mloc = wr0 + quad * 4 + r;
            float v = fmaxf(acch[j][r] + bb, 0.f);
            hfrag[((ks * 4 + (mloc >> 4)) * 16 + (mloc & 15)) * 32 + quadB * 8 + jB] =
                f2bf(v);
        }
    }
    __syncthreads();

    // ---------------- phase B: p2 / outp (8 waves: 4M x 2N) ----------------
    const int wrB = (wave >> 1) * 16;   // rows 0/16/32/48
    const int wcB = (wave & 1) * 64;    // cols 0/64 (of 128)
    f32x4 accp[4], acco[4];
#pragma unroll
    for (int j = 0; j < 4; ++j) {
        accp[j] = (f32x4){0.f, 0.f, 0.f, 0.f};
        acco[j] = (f32x4){0.f, 0.f, 0.f, 0.f};
    }

#pragma unroll
    for (int ks = 0; ks < 8; ++ks) {
        bf16x8 af = *(const bf16x8*)(hfrag +
                                     ((ks * 4 + (wrB >> 4)) * 16 + qm) * 32 + quad * 8);
#pragma unroll
        for (int j = 0; j < 4; ++j) {
            int rB = wcB + j * 16 + qm;
            bf16x8 bl = *(const bf16x8*)(T2l + (size_t)rB * 256 + ks * 32 + quad * 8);
            bf16x8 br = *(const bf16x8*)(T2r + (size_t)rB * 256 + ks * 32 + quad * 8);
            accp[j] = __builtin_amdgcn_mfma_f32_16x16x32_bf16(af, bl,
                                                              accp[j], 0, 0, 0);
            acco[j] = __builtin_amdgcn_mfma_f32_16x16x32_bf16(af, br,
                                                              acco[j], 0, 0, 0);
        }
    }

    // epilogue B
#pragma unroll
    for (int j = 0; j < 4; ++j) {
        int n = wcB + j * 16 + qm;
        float bb2 = b2[n];
#pragma unroll
        for (int r = 0; r < 4; ++r) {
            int row = m0 + wrB + quad * 4 + r;
            if (row < M) {
                p2[(size_t)row * 128 + n] = f2bf(accp[j][r]);
                outp[(size_t)row * 128 + n] = f2bf(acco[j][r] + bb2);
            }
        }
    }
}

// ---------------------------------------------------------------------------
// Final aggregation: out = mean_{src->node} p2 + outp  (fp32). LDS-free.
// ---------------------------------------------------------------------------

__global__ __launch_bounds__(256, 8) void agg_final(const u16* __restrict__ tbl,
                                                    const int* __restrict__ deg,
                                                    const int* __restrict__ base,
                                                    const unsigned* __restrict__ esrc,
                                                    const u16* __restrict__ resid,
                                                    float* __restrict__ outv) {
    const int t = threadIdx.x;
    const int wave = t >> 6;
    const int lane = t & 63;
    const int qm = lane & 15;
    const int quad = lane >> 4;
    const int b = blockIdx.x;
    const int li8 = qm * 8;
    const int gbase = lane & 48;

    for (int pass = 0; pass < 4; ++pass) {
        int n = pass * 16 + wave * 4 + quad;   // 0..63
        int node = b * NPB + n;
        bool valid = node < N_NODES_C;
        int d = 0, s0 = 0;
        if (valid) { d = deg[node]; s0 = base[node]; }
        int dmax = max(d, __shfl_xor(d, 16, 64));
        dmax = max(dmax, __shfl_xor(dmax, 32, 64));

        float a0 = 0.f, a1 = 0.f, a2 = 0.f, a3 = 0.f;
        float a4 = 0.f, a5 = 0.f, a6 = 0.f, a7 = 0.f;

        for (int j = 0; j < dmax; j += 16) {
            int jj = j + qm;
            unsigned sidx = (jj < d) ? esrc[s0 + jj] : (unsigned)SENT_ROW;
            for (int u = 0; u < 16 && j + u < dmax; u += 4) {
                unsigned i0 = __shfl(sidx, gbase + u, 64);
                unsigned i1 = __shfl(sidx, gbase + u + 1, 64);
                unsigned i2 = __shfl(sidx, gbase + u + 2, 64);
                unsigned i3 = __shfl(sidx, gbase + u + 3, 64);
                uint4 r0 = *(const uint4*)(tbl + (size_t)i0 * 128 + li8);
                uint4 r1 = *(const uint4*)(tbl + (size_t)i1 * 128 + li8);
                uint4 r2 = *(const uint4*)(tbl + (size_t)i2 * 128 + li8);
                uint4 r3 = *(const uint4*)(tbl + (size_t)i3 * 128 + li8);
                a0 += lo16f(r0.x); a1 += hi16f(r0.x);
                a2 += lo16f(r0.y); a3 += hi16f(r0.y);
                a4 += lo16f(r0.z); a5 += hi16f(r0.z);
                a6 += lo16f(r0.w); a7 += hi16f(r0.w);
                a0 += lo16f(r1.x); a1 += hi16f(r1.x);
                a2 += lo16f(r1.y); a3 += hi16f(r1.y);
                a4 += lo16f(r1.z); a5 += hi16f(r1.z);
                a6 += lo16f(r1.w); a7 += hi16f(r1.w);
                a0 += lo16f(r2.x); a1 += hi16f(r2.x);
                a2 += lo16f(r2.y); a3 += hi16f(r2.y);
                a4 += lo16f(r2.z); a5 += hi16f(r2.z);
                a6 += lo16f(r2.w); a7 += hi16f(r2.w);
                a0 += lo16f(r3.x); a1 += hi16f(r3.x);
                a2 += lo16f(r3.y); a3 += hi16f(r3.y);
                a4 += lo16f(r3.z); a5 += hi16f(r3.z);
                a6 += lo16f(r3.w); a7 += hi16f(r3.w);
            }
        }

        if (valid) {
            float inv = d > 0 ? 1.f / (float)d : 0.f;
            uint4 rp = *(const uint4*)(resid + (size_t)node * 128 + li8);
            float* op = outv + (size_t)node * 128 + li8;
            float4 o0, o1;
            o0.x = a0 * inv + lo16f(rp.x);
            o0.y = a1 * inv + hi16f(rp.x);
            o0.z = a2 * inv + lo16f(rp.y);
            o0.w = a3 * inv + hi16f(rp.y);
            o1.x = a4 * inv + lo16f(rp.z);
            o1.y = a5 * inv + hi16f(rp.z);
            o1.z = a6 * inv + lo16f(rp.w);
            o1.w = a7 * inv + hi16f(rp.w);
            *(float4*)op = o0;
            *(float4*)(op + 4) = o1;
        }
    }
}

// ---------------------------------------------------------------------------
// launch
// ---------------------------------------------------------------------------

extern "C" void kernel_launch(void* const* d_in, const int* in_sizes, int n_in,
                              void* d_out, int out_size, void* d_ws, size_t ws_size,
                              hipStream_t stream) {
    const float* x = (const float*)d_in[0];
    const int* ei = (const int*)d_in[1];
    const float* W1l = (const float*)d_in[2];
    const float* b1 = (const float*)d_in[3];
    const float* W1r = (const float*)d_in[4];
    const float* W2l = (const float*)d_in[5];
    const float* b2 = (const float*)d_in[6];
    const float* W2r = (const float*)d_in[7];
    float* out = (float*)d_out;

    const int* src = ei;
    const int* dst = ei + N_EDGES_C;

    // int workspace region (first 16 MiB)
    int* iw = (int*)d_ws;
    int* chist = iw;                              // 128 (98 used)
    int* cbase = iw + 128;                        // 128
    int* ccursor = iw + 256;                      // 128
    int* deg = iw + 384;                          // 100000
    int* base = iw + 100384;                      // 100000
    unsigned* epkt2 = (unsigned*)(iw + 200384);   // 1600000
    unsigned* esrc = (unsigned*)(iw + 1800384);   // 1600000 -> ends 3400384
    u16* T1l = (u16*)(iw + 3400448);              // 4 x 32768 u16 = 256 KB
    u16* T1r = T1l + 32768;
    u16* T2l = T1r + 32768;
    u16* T2r = T2l + 32768;                       // ends ~13.9 MB < 16 MiB
    // bf16 region at byte offset 16 MiB; stride 12.85M u16 (sentinel row pad)
    u16* ub = (u16*)((char*)d_ws + (16u << 20));
    u16* x_bf = ub;                               // [100001][128]
    u16* p2 = ub + 12850000;                      // [100001][128]
    u16* outp = ub + 25700000;                    // [100000][128]

    hipMemsetAsync(chist, 0, 512, stream);

    front_fused<<<CONV_BLOCKS + WB_BLOCKS + CH_BLOCKS + 1, 256, 0, stream>>>(
        x, dst, W1l, W1r, W2l, W2r, x_bf, T1l, T1r, T2l, T2r, chist, p2);
    cscan<<<1, 128, 0, stream>>>(chist, cbase, ccursor);
    coarse_scatter<<<K2_BLOCKS, 1024, 0, stream>>>(src, dst, ccursor, epkt2);
    fine_sort<<<NCB, 1024, 0, stream>>>(cbase, chist, epkt2, esrc, deg, base);

    // per bucket: gather-mean + GEMM L1 + GEMM L2 -> p2, outp
    fused_gemm_agg<<<NB, 512, 0, stream>>>(x_bf, deg, base, esrc, T1l, T1r, T2l,
                                           T2r, b1, b2, p2, outp, N_NODES_C);
    // out = mean_{src->node} p2 + outp   (fp32)
    agg_final<<<NB, 256, 0, stream>>>(p2, deg, base, esrc, outp, out);
}

// Round 6
// 531.275 us; speedup vs baseline: 1.1143x; 1.1143x over previous
//
#include <hip/hip_runtime.h>
#include <cstddef>

#define N_NODES_C 100000
#define N_EDGES_C 1600000

#define NPB 64               // nodes per block tile (= GEMM M-tile)
#define NB 1563              // ceil(100000/64)
#define SENT_ROW 100000      // zeroed sentinel row in feature tables

#define NCB 98               // coarse buckets of 1024 nodes: ceil(100000/1024)
#define K2_EPB 8192          // edges per coarse-scatter block
#define K2_BLOCKS 196        // ceil(1600000/8192)

#define CONV_BLOCKS 12500    // 3.2M float4 / 256
#define WB_BLOCKS 512        // weight transpose blocks
#define CH_BLOCKS 1563       // 400128 int4 slots / 256 (coarse hist)

typedef unsigned short u16;
typedef __attribute__((ext_vector_type(8))) short bf16x8;
typedef __attribute__((ext_vector_type(4))) float f32x4;

__device__ __forceinline__ u16 f2bf(float f) {
    unsigned u = __float_as_uint(f);
    u += 0x7fffu + ((u >> 16) & 1);  // round-to-nearest-even
    return (u16)(u >> 16);
}
__device__ __forceinline__ float lo16f(unsigned v) {
    return __uint_as_float(v << 16);
}
__device__ __forceinline__ float hi16f(unsigned v) {
    return __uint_as_float(v & 0xffff0000u);
}

// ---------------------------------------------------------------------------
// Front fused: x fp32->bf16 convert | weight transpose+convert | coarse
// (node>>10) histogram via LDS | sentinel-row zeroing
// ---------------------------------------------------------------------------

__global__ __launch_bounds__(256) void front_fused(
    const float* __restrict__ x, const int* __restrict__ dst,
    const float* __restrict__ W1l, const float* __restrict__ W1r,
    const float* __restrict__ W2l, const float* __restrict__ W2r,
    u16* __restrict__ x_bf, u16* __restrict__ T1l, u16* __restrict__ T1r,
    u16* __restrict__ T2l, u16* __restrict__ T2r,
    int* __restrict__ chist, u16* __restrict__ p2z) {
    const int b = blockIdx.x;
    const int t = threadIdx.x;
    if (b < CONV_BLOCKS) {
        int i = b * 256 + t;
        if (i < 3200000) {
            float4 v = ((const float4*)x)[i];
            ushort4 o;
            o.x = f2bf(v.x); o.y = f2bf(v.y); o.z = f2bf(v.z); o.w = f2bf(v.w);
            ((ushort4*)x_bf)[i] = o;
        }
    } else if (b < CONV_BLOCKS + WB_BLOCKS) {
        int id = (b - CONV_BLOCKS) * 256 + t;  // 0..131071
        int which = id >> 15;
        int r = id & 32767;
        if (which == 0) {        // [128][256] -> [256][128]
            int n = r >> 7, k = r & 127;
            T1l[r] = f2bf(W1l[k * 256 + n]);
        } else if (which == 1) {
            int n = r >> 7, k = r & 127;
            T1r[r] = f2bf(W1r[k * 256 + n]);
        } else if (which == 2) {  // [256][128] -> [128][256]
            int n = r >> 8, k = r & 255;
            T2l[r] = f2bf(W2l[k * 128 + n]);
        } else {
            int n = r >> 8, k = r & 255;
            T2r[r] = f2bf(W2r[k * 128 + n]);
        }
    } else if (b < CONV_BLOCKS + WB_BLOCKS + CH_BLOCKS) {
        __shared__ int hist[NCB];
        for (int j = t; j < NCB; j += 256) hist[j] = 0;
        __syncthreads();
        int i = (b - CONV_BLOCKS - WB_BLOCKS) * 256 + t;  // int4 index
        if (i * 4 < N_EDGES_C) {
            int4 d = ((const int4*)dst)[i];
            atomicAdd(&hist[d.x >> 10], 1);
            atomicAdd(&hist[d.y >> 10], 1);
            atomicAdd(&hist[d.z >> 10], 1);
            atomicAdd(&hist[d.w >> 10], 1);
        }
        __syncthreads();
        for (int j = t; j < NCB; j += 256) {
            int c = hist[j];
            if (c) atomicAdd(&chist[j], c);
        }
    } else {
        // zero the sentinel rows (row SENT_ROW of x_bf and p2)
        uint4 z; z.x = 0; z.y = 0; z.z = 0; z.w = 0;
        if (t < 16)
            ((uint4*)(x_bf + (size_t)SENT_ROW * 128))[t] = z;
        else if (t < 32)
            ((uint4*)(p2z + (size_t)SENT_ROW * 128))[t - 16] = z;
    }
}

// ---------------------------------------------------------------------------
// Coarse scan: exclusive scan of the 98 coarse-bucket counts.
// ---------------------------------------------------------------------------

__global__ __launch_bounds__(128) void cscan(const int* __restrict__ chist,
                                             int* __restrict__ cbase,
                                             int* __restrict__ ccursor) {
    __shared__ int s[128];
    int t = threadIdx.x;
    int v = (t < NCB) ? chist[t] : 0;
    s[t] = v;
    __syncthreads();
    for (int off = 1; off < 128; off <<= 1) {
        int u = (t >= off) ? s[t - off] : 0;
        __syncthreads();
        s[t] += u;
        __syncthreads();
    }
    if (t < NCB) {
        int e = s[t] - v;
        cbase[t] = e;
        ccursor[t] = e;
    }
}

// ---------------------------------------------------------------------------
// K2: coarse scatter. Block-local LDS counting-sort of 8192 edges by coarse
// bucket, then contiguous run-writes (avg ~335B/run) into epkt2.
// packed = (local10 << 17) | src17
// ---------------------------------------------------------------------------

__global__ __launch_bounds__(1024) void coarse_scatter(
    const int* __restrict__ src, const int* __restrict__ dst,
    int* __restrict__ ccursor, unsigned* __restrict__ epkt2) {
    __shared__ unsigned spkt[K2_EPB];
    __shared__ unsigned char scb[K2_EPB];
    __shared__ int hist[NCB], lstart[NCB], lcur[NCB], grun[NCB], stmp[NCB];

    const int t = threadIdx.x;
    const int e0 = blockIdx.x * K2_EPB;
    const int cnt = min(K2_EPB, N_EDGES_C - e0);

    if (t < NCB) hist[t] = 0;
    __syncthreads();

    int4 dd[2], ss[2];
    int vi[2];
#pragma unroll
    for (int r = 0; r < 2; ++r) {
        int i = (e0 >> 2) + r * 1024 + t;  // int4 index
        vi[r] = (i * 4 < N_EDGES_C);
        if (vi[r]) {
            dd[r] = ((const int4*)dst)[i];
            ss[r] = ((const int4*)src)[i];
            atomicAdd(&hist[dd[r].x >> 10], 1);
            atomicAdd(&hist[dd[r].y >> 10], 1);
            atomicAdd(&hist[dd[r].z >> 10], 1);
            atomicAdd(&hist[dd[r].w >> 10], 1);
        }
    }
    __syncthreads();

    if (t < NCB) stmp[t] = hist[t];
    __syncthreads();
    for (int off = 1; off < NCB; off <<= 1) {
        int v = 0;
        if (t < NCB && t >= off) v = stmp[t - off];
        __syncthreads();
        if (t < NCB) stmp[t] += v;
        __syncthreads();
    }
    if (t < NCB) {
        int excl = stmp[t] - hist[t];
        lstart[t] = excl;
        lcur[t] = excl;
        if (hist[t]) grun[t] = atomicAdd(&ccursor[t], hist[t]);
    }
    __syncthreads();

#pragma unroll
    for (int r = 0; r < 2; ++r) {
        if (vi[r]) {
            int4 d = dd[r];
            int4 s4 = ss[r];
            {
                int cb = d.x >> 10;
                int pos = atomicAdd(&lcur[cb], 1);
                spkt[pos] = ((unsigned)(d.x & 1023) << 17) | (unsigned)s4.x;
                scb[pos] = (unsigned char)cb;
            }
            {
                int cb = d.y >> 10;
                int pos = atomicAdd(&lcur[cb], 1);
                spkt[pos] = ((unsigned)(d.y & 1023) << 17) | (unsigned)s4.y;
                scb[pos] = (unsigned char)cb;
            }
            {
                int cb = d.z >> 10;
                int pos = atomicAdd(&lcur[cb], 1);
                spkt[pos] = ((unsigned)(d.z & 1023) << 17) | (unsigned)s4.z;
                scb[pos] = (unsigned char)cb;
            }
            {
                int cb = d.w >> 10;
                int pos = atomicAdd(&lcur[cb], 1);
                spkt[pos] = ((unsigned)(d.w & 1023) << 17) | (unsigned)s4.w;
                scb[pos] = (unsigned char)cb;
            }
        }
    }
    __syncthreads();

#pragma unroll
    for (int k = 0; k < K2_EPB / 1024; ++k) {
        int i = k * 1024 + t;
        if (i < cnt) {
            int cb = scb[i];
            epkt2[grun[cb] + (i - lstart[cb])] = spkt[i];
        }
    }
}

// ---------------------------------------------------------------------------
// K3: fine sort within each coarse bucket. One block per coarse bucket
// (~16.3K edges, L2-resident window). Produces node-contiguous esrc plus
// deg[] and base[] (global = sorted-by-dst order).
// ---------------------------------------------------------------------------

__global__ __launch_bounds__(1024) void fine_sort(
    const int* __restrict__ cbase, const int* __restrict__ chist,
    const unsigned* __restrict__ epkt2, unsigned* __restrict__ esrc,
    int* __restrict__ deg, int* __restrict__ base) {
    __shared__ int hist[1024], lstart[1024], lcur[1024], stmp[1024];
    const int t = threadIdx.x;
    const int c = blockIdx.x;
    const int s0 = cbase[c];
    const int cnt = chist[c];

    hist[t] = 0;
    __syncthreads();

    for (int i = t; i < cnt; i += 1024)
        atomicAdd(&hist[epkt2[s0 + i] >> 17], 1);
    __syncthreads();

    stmp[t] = hist[t];
    __syncthreads();
    for (int off = 1; off < 1024; off <<= 1) {
        int v = (t >= off) ? stmp[t - off] : 0;
        __syncthreads();
        stmp[t] += v;
        __syncthreads();
    }
    int excl = stmp[t] - hist[t];
    lstart[t] = excl;
    lcur[t] = excl;
    int node = c * 1024 + t;
    if (node < N_NODES_C) {
        deg[node] = hist[t];
        base[node] = s0 + excl;
    }
    __syncthreads();

    for (int i = t; i < cnt; i += 1024) {
        unsigned p = epkt2[s0 + i];
        int pos = atomicAdd(&lcur[p >> 17], 1);
        esrc[s0 + pos] = p & 0x1ffffu;
    }
}

// ---------------------------------------------------------------------------
// Fused per-bucket kernel (512 thr = 8 waves, 4 blocks/CU = 32 waves/CU):
//   gather: mean_{src->node} x_bf -> meanS (LDS, chunk-swizzled)
//   xS: block's own x rows staged async (pre-swizzled source)
//   phase A: h = relu(meanS@W1l + xS@W1r + b1) -> hfrag (aliases meanS|xS)
//   phase B: p2 = h@W2l, outp = h@W2r + b2
// B-operand fragments read DIRECTLY from global (T tables are L2-hot).
// NOTE launch bounds (512,4): round 5's (512,8) capped VGPR at 64 ->
// accumulator spill to scratch (+345MB HBM traffic, 3x slowdown).
// ---------------------------------------------------------------------------

__global__ __launch_bounds__(512, 4) void fused_gemm_agg(
    const u16* __restrict__ x_bf, const int* __restrict__ deg,
    const int* __restrict__ base, const unsigned* __restrict__ esrc,
    const u16* __restrict__ T1l, const u16* __restrict__ T1r,   // [256][128]
    const u16* __restrict__ T2l, const u16* __restrict__ T2r,   // [128][256]
    const float* __restrict__ b1, const float* __restrict__ b2,
    u16* __restrict__ p2, u16* __restrict__ outp, int M) {
    alignas(16) __shared__ u16 uni[64 * 256];  // 32KB: [meanS|xS] then hfrag

    u16* const meanS = uni;           // [64][128], 16B-chunk ^ (row&7)
    u16* const xS = uni + 64 * 128;   // [64][128], same swizzle
    u16* const hfrag = uni;           // phase-B alias (32KB)

    const int tid = threadIdx.x;
    const int lane = tid & 63;
    const int wave = tid >> 6;
    const int qm = lane & 15;
    const int quad = lane >> 4;
    const int b = blockIdx.x;
    const int m0 = b * 64;

    // ---- issue xS staging early (lands during gather) ----
#pragma unroll
    for (int r = 0; r < 2; ++r) {
        int c = r * 512 + tid;          // 1024 chunks of 16B
        int row = c >> 4, q16 = c & 15;
        __builtin_amdgcn_global_load_lds(
            (const __attribute__((address_space(1))) unsigned*)(
                x_bf + (size_t)(m0 + row) * 128 + ((q16 ^ (row & 7)) * 8)),
            (__attribute__((address_space(3))) unsigned*)(xS + c * 8), 16, 0, 0);
    }

    // ---- gather + mean -> meanS (bf16, swizzled) ----
    const int li8 = qm * 8;
    const int gbase = lane & 48;  // group base lane within wave

    for (int pass = 0; pass < 2; ++pass) {
        int n = pass * 32 + wave * 4 + quad;   // 0..63
        int node = m0 + n;
        int d = 0, s0 = 0;
        if (node < N_NODES_C) { d = deg[node]; s0 = base[node]; }
        int dmax = max(d, __shfl_xor(d, 16, 64));
        dmax = max(dmax, __shfl_xor(dmax, 32, 64));

        float a0 = 0.f, a1 = 0.f, a2 = 0.f, a3 = 0.f;
        float a4 = 0.f, a5 = 0.f, a6 = 0.f, a7 = 0.f;

        for (int j = 0; j < dmax; j += 16) {
            int jj = j + qm;
            unsigned sidx = (jj < d) ? esrc[s0 + jj] : (unsigned)SENT_ROW;
            for (int u = 0; u < 16 && j + u < dmax; u += 4) {
                unsigned i0 = __shfl(sidx, gbase + u, 64);
                unsigned i1 = __shfl(sidx, gbase + u + 1, 64);
                unsigned i2 = __shfl(sidx, gbase + u + 2, 64);
                unsigned i3 = __shfl(sidx, gbase + u + 3, 64);
                uint4 r0 = *(const uint4*)(x_bf + (size_t)i0 * 128 + li8);
                uint4 r1 = *(const uint4*)(x_bf + (size_t)i1 * 128 + li8);
                uint4 r2 = *(const uint4*)(x_bf + (size_t)i2 * 128 + li8);
                uint4 r3 = *(const uint4*)(x_bf + (size_t)i3 * 128 + li8);
                a0 += lo16f(r0.x); a1 += hi16f(r0.x);
                a2 += lo16f(r0.y); a3 += hi16f(r0.y);
                a4 += lo16f(r0.z); a5 += hi16f(r0.z);
                a6 += lo16f(r0.w); a7 += hi16f(r0.w);
                a0 += lo16f(r1.x); a1 += hi16f(r1.x);
                a2 += lo16f(r1.y); a3 += hi16f(r1.y);
                a4 += lo16f(r1.z); a5 += hi16f(r1.z);
                a6 += lo16f(r1.w); a7 += hi16f(r1.w);
                a0 += lo16f(r2.x); a1 += hi16f(r2.x);
                a2 += lo16f(r2.y); a3 += hi16f(r2.y);
                a4 += lo16f(r2.z); a5 += hi16f(r2.z);
                a6 += lo16f(r2.w); a7 += hi16f(r2.w);
                a0 += lo16f(r3.x); a1 += hi16f(r3.x);
                a2 += lo16f(r3.y); a3 += hi16f(r3.y);
                a4 += lo16f(r3.z); a5 += hi16f(r3.z);
                a6 += lo16f(r3.w); a7 += hi16f(r3.w);
            }
        }

        float inv = d > 0 ? 1.f / (float)d : 0.f;
        uint4 o;
        o.x = (unsigned)f2bf(a0 * inv) | ((unsigned)f2bf(a1 * inv) << 16);
        o.y = (unsigned)f2bf(a2 * inv) | ((unsigned)f2bf(a3 * inv) << 16);
        o.z = (unsigned)f2bf(a4 * inv) | ((unsigned)f2bf(a5 * inv) << 16);
        o.w = (unsigned)f2bf(a6 * inv) | ((unsigned)f2bf(a7 * inv) << 16);
        *(uint4*)(meanS + n * 128 + ((qm ^ (n & 7)) * 8)) = o;
    }
    __syncthreads();   // meanS written, xS landed

    // ---------------- phase A: h tile (8 waves: 4M x 2N) ----------------
    const int wr0 = (wave >> 1) * 16;   // rows 0/16/32/48
    const int wc0 = (wave & 1) * 128;   // cols 0/128
    f32x4 acch[8];
#pragma unroll
    for (int j = 0; j < 8; ++j) acch[j] = (f32x4){0.f, 0.f, 0.f, 0.f};

#pragma unroll
    for (int mat = 0; mat < 2; ++mat) {
        const u16* __restrict__ W = mat ? T1r : T1l;
        const u16* Al = mat ? xS : meanS;
#pragma unroll
        for (int k0 = 0; k0 < 128; k0 += 32) {
            int ch0 = k0 >> 3;
            int rowA = wr0 + qm;
            bf16x8 af = *(const bf16x8*)(Al + rowA * 128 +
                                         (((ch0 + quad) ^ (rowA & 7)) * 8));
#pragma unroll
            for (int j = 0; j < 8; ++j) {
                int rB = wc0 + j * 16 + qm;
                bf16x8 bv = *(const bf16x8*)(W + (size_t)rB * 128 + k0 + quad * 8);
                acch[j] = __builtin_amdgcn_mfma_f32_16x16x32_bf16(af, bv,
                                                                  acch[j], 0, 0, 0);
            }
        }
    }
    __syncthreads();   // all phase-A LDS reads complete before hfrag overwrite

    // epilogue A: +b1, relu, write to hfrag (aliases meanS/xS — dead now)
#pragma unroll
    for (int j = 0; j < 8; ++j) {
        int n = wc0 + j * 16 + qm;
        float bb = b1[n];
        int ks = n >> 5, quadB = (n >> 3) & 3, jB = n & 7;
#pragma unroll
        for (int r = 0; r < 4; ++r) {
            int mloc = wr0 + quad * 4 + r;
            float v = fmaxf(acch[j][r] + bb, 0.f);
            hfrag[((ks * 4 + (mloc >> 4)) * 16 + (mloc & 15)) * 32 + quadB * 8 + jB] =
                f2bf(v);
        }
    }
    __syncthreads();

    // ---------------- phase B: p2 / outp (8 waves: 4M x 2N) ----------------
    const int wrB = (wave >> 1) * 16;   // rows 0/16/32/48
    const int wcB = (wave & 1) * 64;    // cols 0/64 (of 128)
    f32x4 accp[4], acco[4];
#pragma unroll
    for (int j = 0; j < 4; ++j) {
        accp[j] = (f32x4){0.f, 0.f, 0.f, 0.f};
        acco[j] = (f32x4){0.f, 0.f, 0.f, 0.f};
    }

#pragma unroll
    for (int ks = 0; ks < 8; ++ks) {
        bf16x8 af = *(const bf16x8*)(hfrag +
                                     ((ks * 4 + (wrB >> 4)) * 16 + qm) * 32 + quad * 8);
#pragma unroll
        for (int j = 0; j < 4; ++j) {
            int rB = wcB + j * 16 + qm;
            bf16x8 bl = *(const bf16x8*)(T2l + (size_t)rB * 256 + ks * 32 + quad * 8);
            bf16x8 br = *(const bf16x8*)(T2r + (size_t)rB * 256 + ks * 32 + quad * 8);
            accp[j] = __builtin_amdgcn_mfma_f32_16x16x32_bf16(af, bl,
                                                              accp[j], 0, 0, 0);
            acco[j] = __builtin_amdgcn_mfma_f32_16x16x32_bf16(af, br,
                                                              acco[j], 0, 0, 0);
        }
    }

    // epilogue B
#pragma unroll
    for (int j = 0; j < 4; ++j) {
        int n = wcB + j * 16 + qm;
        float bb2 = b2[n];
#pragma unroll
        for (int r = 0; r < 4; ++r) {
            int row = m0 + wrB + quad * 4 + r;
            if (row < M) {
                p2[(size_t)row * 128 + n] = f2bf(accp[j][r]);
                outp[(size_t)row * 128 + n] = f2bf(acco[j][r] + bb2);
            }
        }
    }
}

// ---------------------------------------------------------------------------
// Final aggregation: out = mean_{src->node} p2 + outp  (fp32). LDS-free.
// ---------------------------------------------------------------------------

__global__ __launch_bounds__(256, 8) void agg_final(const u16* __restrict__ tbl,
                                                    const int* __restrict__ deg,
                                                    const int* __restrict__ base,
                                                    const unsigned* __restrict__ esrc,
                                                    const u16* __restrict__ resid,
                                                    float* __restrict__ outv) {
    const int t = threadIdx.x;
    const int wave = t >> 6;
    const int lane = t & 63;
    const int qm = lane & 15;
    const int quad = lane >> 4;
    const int b = blockIdx.x;
    const int li8 = qm * 8;
    const int gbase = lane & 48;

    for (int pass = 0; pass < 4; ++pass) {
        int n = pass * 16 + wave * 4 + quad;   // 0..63
        int node = b * NPB + n;
        bool valid = node < N_NODES_C;
        int d = 0, s0 = 0;
        if (valid) { d = deg[node]; s0 = base[node]; }
        int dmax = max(d, __shfl_xor(d, 16, 64));
        dmax = max(dmax, __shfl_xor(dmax, 32, 64));

        float a0 = 0.f, a1 = 0.f, a2 = 0.f, a3 = 0.f;
        float a4 = 0.f, a5 = 0.f, a6 = 0.f, a7 = 0.f;

        for (int j = 0; j < dmax; j += 16) {
            int jj = j + qm;
            unsigned sidx = (jj < d) ? esrc[s0 + jj] : (unsigned)SENT_ROW;
            for (int u = 0; u < 16 && j + u < dmax; u += 4) {
                unsigned i0 = __shfl(sidx, gbase + u, 64);
                unsigned i1 = __shfl(sidx, gbase + u + 1, 64);
                unsigned i2 = __shfl(sidx, gbase + u + 2, 64);
                unsigned i3 = __shfl(sidx, gbase + u + 3, 64);
                uint4 r0 = *(const uint4*)(tbl + (size_t)i0 * 128 + li8);
                uint4 r1 = *(const uint4*)(tbl + (size_t)i1 * 128 + li8);
                uint4 r2 = *(const uint4*)(tbl + (size_t)i2 * 128 + li8);
                uint4 r3 = *(const uint4*)(tbl + (size_t)i3 * 128 + li8);
                a0 += lo16f(r0.x); a1 += hi16f(r0.x);
                a2 += lo16f(r0.y); a3 += hi16f(r0.y);
                a4 += lo16f(r0.z); a5 += hi16f(r0.z);
                a6 += lo16f(r0.w); a7 += hi16f(r0.w);
                a0 += lo16f(r1.x); a1 += hi16f(r1.x);
                a2 += lo16f(r1.y); a3 += hi16f(r1.y);
                a4 += lo16f(r1.z); a5 += hi16f(r1.z);
                a6 += lo16f(r1.w); a7 += hi16f(r1.w);
                a0 += lo16f(r2.x); a1 += hi16f(r2.x);
                a2 += lo16f(r2.y); a3 += hi16f(r2.y);
                a4 += lo16f(r2.z); a5 += hi16f(r2.z);
                a6 += lo16f(r2.w); a7 += hi16f(r2.w);
                a0 += lo16f(r3.x); a1 += hi16f(r3.x);
                a2 += lo16f(r3.y); a3 += hi16f(r3.y);
                a4 += lo16f(r3.z); a5 += hi16f(r3.z);
                a6 += lo16f(r3.w); a7 += hi16f(r3.w);
            }
        }

        if (valid) {
            float inv = d > 0 ? 1.f / (float)d : 0.f;
            uint4 rp = *(const uint4*)(resid + (size_t)node * 128 + li8);
            float* op = outv + (size_t)node * 128 + li8;
            float4 o0, o1;
            o0.x = a0 * inv + lo16f(rp.x);
            o0.y = a1 * inv + hi16f(rp.x);
            o0.z = a2 * inv + lo16f(rp.y);
            o0.w = a3 * inv + hi16f(rp.y);
            o1.x = a4 * inv + lo16f(rp.z);
            o1.y = a5 * inv + hi16f(rp.z);
            o1.z = a6 * inv + lo16f(rp.w);
            o1.w = a7 * inv + hi16f(rp.w);
            *(float4*)op = o0;
            *(float4*)(op + 4) = o1;
        }
    }
}

// ---------------------------------------------------------------------------
// launch
// ---------------------------------------------------------------------------

extern "C" void kernel_launch(void* const* d_in, const int* in_sizes, int n_in,
                              void* d_out, int out_size, void* d_ws, size_t ws_size,
                              hipStream_t stream) {
    const float* x = (const float*)d_in[0];
    const int* ei = (const int*)d_in[1];
    const float* W1l = (const float*)d_in[2];
    const float* b1 = (const float*)d_in[3];
    const float* W1r = (const float*)d_in[4];
    const float* W2l = (const float*)d_in[5];
    const float* b2 = (const float*)d_in[6];
    const float* W2r = (const float*)d_in[7];
    float* out = (float*)d_out;

    const int* src = ei;
    const int* dst = ei + N_EDGES_C;

    // int workspace region (first 16 MiB)
    int* iw = (int*)d_ws;
    int* chist = iw;                              // 128 (98 used)
    int* cbase = iw + 128;                        // 128
    int* ccursor = iw + 256;                      // 128
    int* deg = iw + 384;                          // 100000
    int* base = iw + 100384;                      // 100000
    unsigned* epkt2 = (unsigned*)(iw + 200384);   // 1600000
    unsigned* esrc = (unsigned*)(iw + 1800384);   // 1600000 -> ends 3400384
    u16* T1l = (u16*)(iw + 3400448);              // 4 x 32768 u16 = 256 KB
    u16* T1r = T1l + 32768;
    u16* T2l = T1r + 32768;
    u16* T2r = T2l + 32768;                       // ends ~13.9 MB < 16 MiB
    // bf16 region at byte offset 16 MiB; stride 12.85M u16 (sentinel row pad)
    u16* ub = (u16*)((char*)d_ws + (16u << 20));
    u16* x_bf = ub;                               // [100001][128]
    u16* p2 = ub + 12850000;                      // [100001][128]
    u16* outp = ub + 25700000;                    // [100000][128]

    hipMemsetAsync(chist, 0, 512, stream);

    front_fused<<<CONV_BLOCKS + WB_BLOCKS + CH_BLOCKS + 1, 256, 0, stream>>>(
        x, dst, W1l, W1r, W2l, W2r, x_bf, T1l, T1r, T2l, T2r, chist, p2);
    cscan<<<1, 128, 0, stream>>>(chist, cbase, ccursor);
    coarse_scatter<<<K2_BLOCKS, 1024, 0, stream>>>(src, dst, ccursor, epkt2);
    fine_sort<<<NCB, 1024, 0, stream>>>(cbase, chist, epkt2, esrc, deg, base);

    // per bucket: gather-mean + GEMM L1 + GEMM L2 -> p2, outp
    fused_gemm_agg<<<NB, 512, 0, stream>>>(x_bf, deg, base, esrc, T1l, T1r, T2l,
                                           T2r, b1, b2, p2, outp, N_NODES_C);
    // out = mean_{src->node} p2 + outp   (fp32)
    agg_final<<<NB, 256, 0, stream>>>(p2, deg, base, esrc, outp, out);
}

// Round 7
// 365.092 us; speedup vs baseline: 1.6215x; 1.4552x over previous
//
#include <hip/hip_runtime.h>
#include <cstddef>

#define N_NODES_C 100000
#define N_EDGES_C 1600000

#define NPB 64               // nodes per block tile (= GEMM M-tile)
#define NB 1563              // ceil(100000/64)
#define SENT_ROW 100000      // zeroed sentinel row in feature tables

#define NCB 196              // coarse buckets of 512 nodes: ceil(100000/512)
#define K2_EPB 8192          // edges per coarse-scatter block
#define K2_BLOCKS 196        // ceil(1600000/8192)

#define CONV_BLOCKS 12500    // 3.2M float4 / 256
#define WB_BLOCKS 512        // weight transpose blocks
#define CH_BLOCKS 1563       // 400128 int4 slots / 256 (coarse hist)

typedef unsigned short u16;
typedef __attribute__((ext_vector_type(8))) short bf16x8;
typedef __attribute__((ext_vector_type(4))) float f32x4;

__device__ __forceinline__ u16 f2bf(float f) {
    unsigned u = __float_as_uint(f);
    u += 0x7fffu + ((u >> 16) & 1);  // round-to-nearest-even
    return (u16)(u >> 16);
}
__device__ __forceinline__ float lo16f(unsigned v) {
    return __uint_as_float(v << 16);
}
__device__ __forceinline__ float hi16f(unsigned v) {
    return __uint_as_float(v & 0xffff0000u);
}

// ---------------------------------------------------------------------------
// Front fused: x fp32->bf16 convert | weight transpose+convert | coarse
// (node>>9) histogram via LDS | sentinel-row zeroing
// ---------------------------------------------------------------------------

__global__ __launch_bounds__(256) void front_fused(
    const float* __restrict__ x, const int* __restrict__ dst,
    const float* __restrict__ W1l, const float* __restrict__ W1r,
    const float* __restrict__ W2l, const float* __restrict__ W2r,
    u16* __restrict__ x_bf, u16* __restrict__ T1l, u16* __restrict__ T1r,
    u16* __restrict__ T2l, u16* __restrict__ T2r,
    int* __restrict__ chist, u16* __restrict__ p2z) {
    const int b = blockIdx.x;
    const int t = threadIdx.x;
    if (b < CONV_BLOCKS) {
        int i = b * 256 + t;
        if (i < 3200000) {
            float4 v = ((const float4*)x)[i];
            ushort4 o;
            o.x = f2bf(v.x); o.y = f2bf(v.y); o.z = f2bf(v.z); o.w = f2bf(v.w);
            ((ushort4*)x_bf)[i] = o;
        }
    } else if (b < CONV_BLOCKS + WB_BLOCKS) {
        int id = (b - CONV_BLOCKS) * 256 + t;  // 0..131071
        int which = id >> 15;
        int r = id & 32767;
        if (which == 0) {        // [128][256] -> [256][128]
            int n = r >> 7, k = r & 127;
            T1l[r] = f2bf(W1l[k * 256 + n]);
        } else if (which == 1) {
            int n = r >> 7, k = r & 127;
            T1r[r] = f2bf(W1r[k * 256 + n]);
        } else if (which == 2) {  // [256][128] -> [128][256]
            int n = r >> 8, k = r & 255;
            T2l[r] = f2bf(W2l[k * 128 + n]);
        } else {
            int n = r >> 8, k = r & 255;
            T2r[r] = f2bf(W2r[k * 128 + n]);
        }
    } else if (b < CONV_BLOCKS + WB_BLOCKS + CH_BLOCKS) {
        __shared__ int hist[NCB];
        for (int j = t; j < NCB; j += 256) hist[j] = 0;
        __syncthreads();
        int i = (b - CONV_BLOCKS - WB_BLOCKS) * 256 + t;  // int4 index
        if (i * 4 < N_EDGES_C) {
            int4 d = ((const int4*)dst)[i];
            atomicAdd(&hist[d.x >> 9], 1);
            atomicAdd(&hist[d.y >> 9], 1);
            atomicAdd(&hist[d.z >> 9], 1);
            atomicAdd(&hist[d.w >> 9], 1);
        }
        __syncthreads();
        for (int j = t; j < NCB; j += 256) {
            int c = hist[j];
            if (c) atomicAdd(&chist[j], c);
        }
    } else {
        // zero the sentinel rows (row SENT_ROW of x_bf and p2)
        uint4 z; z.x = 0; z.y = 0; z.z = 0; z.w = 0;
        if (t < 16)
            ((uint4*)(x_bf + (size_t)SENT_ROW * 128))[t] = z;
        else if (t < 32)
            ((uint4*)(p2z + (size_t)SENT_ROW * 128))[t - 16] = z;
    }
}

// ---------------------------------------------------------------------------
// Coarse scan: exclusive scan of the 196 coarse-bucket counts.
// ---------------------------------------------------------------------------

__global__ __launch_bounds__(256) void cscan(const int* __restrict__ chist,
                                             int* __restrict__ cbase,
                                             int* __restrict__ ccursor) {
    __shared__ int s[256];
    int t = threadIdx.x;
    int v = (t < NCB) ? chist[t] : 0;
    s[t] = v;
    __syncthreads();
    for (int off = 1; off < 256; off <<= 1) {
        int u = (t >= off) ? s[t - off] : 0;
        __syncthreads();
        s[t] += u;
        __syncthreads();
    }
    if (t < NCB) {
        int e = s[t] - v;
        cbase[t] = e;
        ccursor[t] = e;
    }
}

// ---------------------------------------------------------------------------
// K2: coarse scatter. Block-local LDS counting-sort of 8192 edges by coarse
// bucket, then contiguous run-writes into epkt2.
// packed = (local9 << 17) | src17
// ---------------------------------------------------------------------------

__global__ __launch_bounds__(1024) void coarse_scatter(
    const int* __restrict__ src, const int* __restrict__ dst,
    int* __restrict__ ccursor, unsigned* __restrict__ epkt2) {
    __shared__ unsigned spkt[K2_EPB];
    __shared__ unsigned char scb[K2_EPB];
    __shared__ int hist[NCB], lstart[NCB], lcur[NCB], grun[NCB], stmp[NCB];

    const int t = threadIdx.x;
    const int e0 = blockIdx.x * K2_EPB;
    const int cnt = min(K2_EPB, N_EDGES_C - e0);

    if (t < NCB) hist[t] = 0;
    __syncthreads();

    int4 dd[2], ss[2];
    int vi[2];
#pragma unroll
    for (int r = 0; r < 2; ++r) {
        int i = (e0 >> 2) + r * 1024 + t;  // int4 index
        vi[r] = (i * 4 < N_EDGES_C);
        if (vi[r]) {
            dd[r] = ((const int4*)dst)[i];
            ss[r] = ((const int4*)src)[i];
            atomicAdd(&hist[dd[r].x >> 9], 1);
            atomicAdd(&hist[dd[r].y >> 9], 1);
            atomicAdd(&hist[dd[r].z >> 9], 1);
            atomicAdd(&hist[dd[r].w >> 9], 1);
        }
    }
    __syncthreads();

    if (t < NCB) stmp[t] = hist[t];
    __syncthreads();
    for (int off = 1; off < NCB; off <<= 1) {
        int v = 0;
        if (t < NCB && t >= off) v = stmp[t - off];
        __syncthreads();
        if (t < NCB) stmp[t] += v;
        __syncthreads();
    }
    if (t < NCB) {
        int excl = stmp[t] - hist[t];
        lstart[t] = excl;
        lcur[t] = excl;
        if (hist[t]) grun[t] = atomicAdd(&ccursor[t], hist[t]);
    }
    __syncthreads();

#pragma unroll
    for (int r = 0; r < 2; ++r) {
        if (vi[r]) {
            int4 d = dd[r];
            int4 s4 = ss[r];
            {
                int cb = d.x >> 9;
                int pos = atomicAdd(&lcur[cb], 1);
                spkt[pos] = ((unsigned)(d.x & 511) << 17) | (unsigned)s4.x;
                scb[pos] = (unsigned char)cb;
            }
            {
                int cb = d.y >> 9;
                int pos = atomicAdd(&lcur[cb], 1);
                spkt[pos] = ((unsigned)(d.y & 511) << 17) | (unsigned)s4.y;
                scb[pos] = (unsigned char)cb;
            }
            {
                int cb = d.z >> 9;
                int pos = atomicAdd(&lcur[cb], 1);
                spkt[pos] = ((unsigned)(d.z & 511) << 17) | (unsigned)s4.z;
                scb[pos] = (unsigned char)cb;
            }
            {
                int cb = d.w >> 9;
                int pos = atomicAdd(&lcur[cb], 1);
                spkt[pos] = ((unsigned)(d.w & 511) << 17) | (unsigned)s4.w;
                scb[pos] = (unsigned char)cb;
            }
        }
    }
    __syncthreads();

#pragma unroll
    for (int k = 0; k < K2_EPB / 1024; ++k) {
        int i = k * 1024 + t;
        if (i < cnt) {
            int cb = scb[i];
            epkt2[grun[cb] + (i - lstart[cb])] = spkt[i];
        }
    }
}

// ---------------------------------------------------------------------------
// K3: fine sort within each coarse bucket. One block per coarse bucket
// (~8.2K edges, L2-resident window). Produces node-contiguous esrc plus
// deg[] and base[].
// ---------------------------------------------------------------------------

__global__ __launch_bounds__(1024) void fine_sort(
    const int* __restrict__ cbase, const int* __restrict__ chist,
    const unsigned* __restrict__ epkt2, unsigned* __restrict__ esrc,
    int* __restrict__ deg, int* __restrict__ base) {
    __shared__ int hist[512], lstart[512], lcur[512], stmp[512];
    const int t = threadIdx.x;
    const int c = blockIdx.x;
    const int s0 = cbase[c];
    const int cnt = chist[c];

    if (t < 512) hist[t] = 0;
    __syncthreads();

    for (int i = t; i < cnt; i += 1024)
        atomicAdd(&hist[epkt2[s0 + i] >> 17], 1);
    __syncthreads();

    if (t < 512) stmp[t] = hist[t];
    __syncthreads();
    for (int off = 1; off < 512; off <<= 1) {
        int v = 0;
        if (t < 512 && t >= off) v = stmp[t - off];
        __syncthreads();
        if (t < 512) stmp[t] += v;
        __syncthreads();
    }
    if (t < 512) {
        int excl = stmp[t] - hist[t];
        lstart[t] = excl;
        lcur[t] = excl;
        int node = c * 512 + t;
        if (node < N_NODES_C) {
            deg[node] = hist[t];
            base[node] = s0 + excl;
        }
    }
    __syncthreads();

    for (int i = t; i < cnt; i += 1024) {
        unsigned p = epkt2[s0 + i];
        int pos = atomicAdd(&lcur[p >> 17], 1);
        esrc[s0 + pos] = p & 0x1ffffu;
    }
}

// ---------------------------------------------------------------------------
// Fused per-bucket kernel (512 thr = 8 waves) — round-4 proven structure:
//   gather: mean_{src->node} x_bf -> meanS (LDS, chunk-swizzled)
//   xS: block's own x rows staged async (pre-swizzled source)
//   phase A: h = relu(meanS@W1l + xS@W1r + b1) -> hfrag (aliases meanS|xS)
//   phase B: p2 = h@W2l, outp = h@W2r + b2
// Weights staged through Bs via global_load_lds (direct global B-reads are
// latency-serialized — round 6 regression). LDS 48KB -> 3 blocks/CU.
// ---------------------------------------------------------------------------

__global__ __launch_bounds__(512, 6) void fused_gemm_agg(
    const u16* __restrict__ x_bf, const int* __restrict__ deg,
    const int* __restrict__ base, const unsigned* __restrict__ esrc,
    const u16* __restrict__ T1l, const u16* __restrict__ T1r,   // [256][128]
    const u16* __restrict__ T2l, const u16* __restrict__ T2r,   // [128][256]
    const float* __restrict__ b1, const float* __restrict__ b2,
    u16* __restrict__ p2, u16* __restrict__ outp, int M) {
    alignas(16) __shared__ u16 uni[64 * 256];  // 32KB: [meanS|xS] then hfrag
    alignas(16) __shared__ u16 Bs[8192];       // 16KB weight staging

    u16* const meanS = uni;           // [64][128], 16B-chunk ^ (row&7)
    u16* const xS = uni + 64 * 128;   // [64][128], same swizzle
    u16* const hfrag = uni;           // phase-B alias (32KB)

    const int tid = threadIdx.x;
    const int lane = tid & 63;
    const int wave = tid >> 6;
    const int qm = lane & 15;
    const int quad = lane >> 4;
    const int b = blockIdx.x;
    const int m0 = b * 64;

    // ---- issue xS staging early (lands during gather) ----
#pragma unroll
    for (int r = 0; r < 2; ++r) {
        int c = r * 512 + tid;          // 1024 chunks of 16B
        int row = c >> 4, q16 = c & 15;
        __builtin_amdgcn_global_load_lds(
            (const __attribute__((address_space(1))) unsigned*)(
                x_bf + (size_t)(m0 + row) * 128 + ((q16 ^ (row & 7)) * 8)),
            (__attribute__((address_space(3))) unsigned*)(xS + c * 8), 16, 0, 0);
    }

    // ---- gather + mean -> meanS (bf16, swizzled) ----
    const int li8 = qm * 8;
    const int gbase = lane & 48;  // group base lane within wave

    for (int pass = 0; pass < 2; ++pass) {
        int n = pass * 32 + wave * 4 + quad;   // 0..63
        int node = m0 + n;
        int d = 0, s0 = 0;
        if (node < N_NODES_C) { d = deg[node]; s0 = base[node]; }
        int dmax = max(d, __shfl_xor(d, 16, 64));
        dmax = max(dmax, __shfl_xor(dmax, 32, 64));

        float a0 = 0.f, a1 = 0.f, a2 = 0.f, a3 = 0.f;
        float a4 = 0.f, a5 = 0.f, a6 = 0.f, a7 = 0.f;

        for (int j = 0; j < dmax; j += 16) {
            int jj = j + qm;
            unsigned sidx = (jj < d) ? esrc[s0 + jj] : (unsigned)SENT_ROW;
            for (int u = 0; u < 16 && j + u < dmax; u += 4) {
                unsigned i0 = __shfl(sidx, gbase + u, 64);
                unsigned i1 = __shfl(sidx, gbase + u + 1, 64);
                unsigned i2 = __shfl(sidx, gbase + u + 2, 64);
                unsigned i3 = __shfl(sidx, gbase + u + 3, 64);
                uint4 r0 = *(const uint4*)(x_bf + (size_t)i0 * 128 + li8);
                uint4 r1 = *(const uint4*)(x_bf + (size_t)i1 * 128 + li8);
                uint4 r2 = *(const uint4*)(x_bf + (size_t)i2 * 128 + li8);
                uint4 r3 = *(const uint4*)(x_bf + (size_t)i3 * 128 + li8);
                a0 += lo16f(r0.x); a1 += hi16f(r0.x);
                a2 += lo16f(r0.y); a3 += hi16f(r0.y);
                a4 += lo16f(r0.z); a5 += hi16f(r0.z);
                a6 += lo16f(r0.w); a7 += hi16f(r0.w);
                a0 += lo16f(r1.x); a1 += hi16f(r1.x);
                a2 += lo16f(r1.y); a3 += hi16f(r1.y);
                a4 += lo16f(r1.z); a5 += hi16f(r1.z);
                a6 += lo16f(r1.w); a7 += hi16f(r1.w);
                a0 += lo16f(r2.x); a1 += hi16f(r2.x);
                a2 += lo16f(r2.y); a3 += hi16f(r2.y);
                a4 += lo16f(r2.z); a5 += hi16f(r2.z);
                a6 += lo16f(r2.w); a7 += hi16f(r2.w);
                a0 += lo16f(r3.x); a1 += hi16f(r3.x);
                a2 += lo16f(r3.y); a3 += hi16f(r3.y);
                a4 += lo16f(r3.z); a5 += hi16f(r3.z);
                a6 += lo16f(r3.w); a7 += hi16f(r3.w);
            }
        }

        float inv = d > 0 ? 1.f / (float)d : 0.f;
        uint4 o;
        o.x = (unsigned)f2bf(a0 * inv) | ((unsigned)f2bf(a1 * inv) << 16);
        o.y = (unsigned)f2bf(a2 * inv) | ((unsigned)f2bf(a3 * inv) << 16);
        o.z = (unsigned)f2bf(a4 * inv) | ((unsigned)f2bf(a5 * inv) << 16);
        o.w = (unsigned)f2bf(a6 * inv) | ((unsigned)f2bf(a7 * inv) << 16);
        *(uint4*)(meanS + n * 128 + ((qm ^ (n & 7)) * 8)) = o;
    }
    __syncthreads();

    // ---------------- phase A: h tile (8 waves: 4M x 2N) ----------------
    const int wr0 = (wave >> 1) * 16;   // rows 0/16/32/48
    const int wc0 = (wave & 1) * 128;   // cols 0/128
    f32x4 acch[8];
#pragma unroll
    for (int j = 0; j < 8; ++j) acch[j] = (f32x4){0.f, 0.f, 0.f, 0.f};

#pragma unroll
    for (int mat = 0; mat < 2; ++mat) {
        const u16* __restrict__ W = mat ? T1r : T1l;
        const u16* Al = mat ? xS : meanS;
#pragma unroll
        for (int k0 = 0; k0 < 128; k0 += 32) {
            // Bs: 256x32 (1024 chunks, 2/thread), source pre-swizzled (^row&3)
#pragma unroll
            for (int r = 0; r < 2; ++r) {
                int c = r * 512 + tid;
                int row = c >> 2, kc = c & 3;
                __builtin_amdgcn_global_load_lds(
                    (const __attribute__((address_space(1))) unsigned*)(
                        W + (size_t)row * 128 + k0 + ((kc ^ (row & 3)) * 8)),
                    (__attribute__((address_space(3))) unsigned*)(Bs + c * 8), 16, 0, 0);
            }
            __syncthreads();
            int ch0 = k0 >> 3;
            int rowA = wr0 + qm;
            bf16x8 af = *(const bf16x8*)(Al + rowA * 128 +
                                         (((ch0 + quad) ^ (rowA & 7)) * 8));
            bf16x8 bfv[8];
#pragma unroll
            for (int j = 0; j < 8; ++j) {
                int rB = wc0 + j * 16 + qm;
                bfv[j] = *(const bf16x8*)(Bs + rB * 32 + ((quad ^ (rB & 3)) * 8));
            }
#pragma unroll
            for (int j = 0; j < 8; ++j)
                acch[j] = __builtin_amdgcn_mfma_f32_16x16x32_bf16(af, bfv[j],
                                                                  acch[j], 0, 0, 0);
            __syncthreads();
        }
    }

    // epilogue A: +b1, relu, write to hfrag (aliases meanS/xS — dead now)
#pragma unroll
    for (int j = 0; j < 8; ++j) {
        int n = wc0 + j * 16 + qm;
        float bb = b1[n];
        int ks = n >> 5, quadB = (n >> 3) & 3, jB = n & 7;
#pragma unroll
        for (int r = 0; r < 4; ++r) {
            int mloc = wr0 + quad * 4 + r;
            float v = fmaxf(acch[j][r] + bb, 0.f);
            hfrag[((ks * 4 + (mloc >> 4)) * 16 + (mloc & 15)) * 32 + quadB * 8 + jB] =
                f2bf(v);
        }
    }
    __syncthreads();

    // ---------------- phase B: p2 / outp (8 waves: 4M x 2N) ----------------
    const int wrB = (wave >> 1) * 16;   // rows 0/16/32/48
    const int wcB = (wave & 1) * 64;    // cols 0/64 (of 128)
    f32x4 accp[4], acco[4];
#pragma unroll
    for (int j = 0; j < 4; ++j) {
        accp[j] = (f32x4){0.f, 0.f, 0.f, 0.f};
        acco[j] = (f32x4){0.f, 0.f, 0.f, 0.f};
    }

#pragma unroll
    for (int ks = 0; ks < 8; ++ks) {
        // stage W2l|W2r k-chunk: Bs[mat][128][32], 1024 chunks, 2/thread
#pragma unroll
        for (int r = 0; r < 2; ++r) {
            int c = r * 512 + tid;
            int matc = c >> 9;
            int row = (c >> 2) & 127;
            int kc = c & 3;
            const u16* W = matc ? T2r : T2l;
            __builtin_amdgcn_global_load_lds(
                (const __attribute__((address_space(1))) unsigned*)(
                    W + (size_t)row * 256 + ks * 32 + ((kc ^ (row & 3)) * 8)),
                (__attribute__((address_space(3))) unsigned*)(Bs + c * 8), 16, 0, 0);
        }
        __syncthreads();
        bf16x8 af = *(const bf16x8*)(hfrag +
                                     ((ks * 4 + (wrB >> 4)) * 16 + qm) * 32 + quad * 8);
        bf16x8 bfl[4], bfr[4];
#pragma unroll
        for (int j = 0; j < 4; ++j) {
            int rB = wcB + j * 16 + qm;
            bfl[j] = *(const bf16x8*)(Bs + rB * 32 + ((quad ^ (rB & 3)) * 8));
            bfr[j] = *(const bf16x8*)(Bs + 4096 + rB * 32 + ((quad ^ (rB & 3)) * 8));
        }
#pragma unroll
        for (int j = 0; j < 4; ++j) {
            accp[j] = __builtin_amdgcn_mfma_f32_16x16x32_bf16(af, bfl[j],
                                                              accp[j], 0, 0, 0);
            acco[j] = __builtin_amdgcn_mfma_f32_16x16x32_bf16(af, bfr[j],
                                                              acco[j], 0, 0, 0);
        }
        __syncthreads();
    }

    // epilogue B
#pragma unroll
    for (int j = 0; j < 4; ++j) {
        int n = wcB + j * 16 + qm;
        float bb2 = b2[n];
#pragma unroll
        for (int r = 0; r < 4; ++r) {
            int row = m0 + wrB + quad * 4 + r;
            if (row < M) {
                p2[(size_t)row * 128 + n] = f2bf(accp[j][r]);
                outp[(size_t)row * 128 + n] = f2bf(acco[j][r] + bb2);
            }
        }
    }
}

// ---------------------------------------------------------------------------
// Final aggregation: out = mean_{src->node} p2 + outp  (fp32). LDS-free.
// ---------------------------------------------------------------------------

__global__ __launch_bounds__(256, 8) void agg_final(const u16* __restrict__ tbl,
                                                    const int* __restrict__ deg,
                                                    const int* __restrict__ base,
                                                    const unsigned* __restrict__ esrc,
                                                    const u16* __restrict__ resid,
                                                    float* __restrict__ outv) {
    const int t = threadIdx.x;
    const int wave = t >> 6;
    const int lane = t & 63;
    const int qm = lane & 15;
    const int quad = lane >> 4;
    const int b = blockIdx.x;
    const int li8 = qm * 8;
    const int gbase = lane & 48;

    for (int pass = 0; pass < 4; ++pass) {
        int n = pass * 16 + wave * 4 + quad;   // 0..63
        int node = b * NPB + n;
        bool valid = node < N_NODES_C;
        int d = 0, s0 = 0;
        if (valid) { d = deg[node]; s0 = base[node]; }
        int dmax = max(d, __shfl_xor(d, 16, 64));
        dmax = max(dmax, __shfl_xor(dmax, 32, 64));

        float a0 = 0.f, a1 = 0.f, a2 = 0.f, a3 = 0.f;
        float a4 = 0.f, a5 = 0.f, a6 = 0.f, a7 = 0.f;

        for (int j = 0; j < dmax; j += 16) {
            int jj = j + qm;
            unsigned sidx = (jj < d) ? esrc[s0 + jj] : (unsigned)SENT_ROW;
            for (int u = 0; u < 16 && j + u < dmax; u += 4) {
                unsigned i0 = __shfl(sidx, gbase + u, 64);
                unsigned i1 = __shfl(sidx, gbase + u + 1, 64);
                unsigned i2 = __shfl(sidx, gbase + u + 2, 64);
                unsigned i3 = __shfl(sidx, gbase + u + 3, 64);
                uint4 r0 = *(const uint4*)(tbl + (size_t)i0 * 128 + li8);
                uint4 r1 = *(const uint4*)(tbl + (size_t)i1 * 128 + li8);
                uint4 r2 = *(const uint4*)(tbl + (size_t)i2 * 128 + li8);
                uint4 r3 = *(const uint4*)(tbl + (size_t)i3 * 128 + li8);
                a0 += lo16f(r0.x); a1 += hi16f(r0.x);
                a2 += lo16f(r0.y); a3 += hi16f(r0.y);
                a4 += lo16f(r0.z); a5 += hi16f(r0.z);
                a6 += lo16f(r0.w); a7 += hi16f(r0.w);
                a0 += lo16f(r1.x); a1 += hi16f(r1.x);
                a2 += lo16f(r1.y); a3 += hi16f(r1.y);
                a4 += lo16f(r1.z); a5 += hi16f(r1.z);
                a6 += lo16f(r1.w); a7 += hi16f(r1.w);
                a0 += lo16f(r2.x); a1 += hi16f(r2.x);
                a2 += lo16f(r2.y); a3 += hi16f(r2.y);
                a4 += lo16f(r2.z); a5 += hi16f(r2.z);
                a6 += lo16f(r2.w); a7 += hi16f(r2.w);
                a0 += lo16f(r3.x); a1 += hi16f(r3.x);
                a2 += lo16f(r3.y); a3 += hi16f(r3.y);
                a4 += lo16f(r3.z); a5 += hi16f(r3.z);
                a6 += lo16f(r3.w); a7 += hi16f(r3.w);
            }
        }

        if (valid) {
            float inv = d > 0 ? 1.f / (float)d : 0.f;
            uint4 rp = *(const uint4*)(resid + (size_t)node * 128 + li8);
            float* op = outv + (size_t)node * 128 + li8;
            float4 o0, o1;
            o0.x = a0 * inv + lo16f(rp.x);
            o0.y = a1 * inv + hi16f(rp.x);
            o0.z = a2 * inv + lo16f(rp.y);
            o0.w = a3 * inv + hi16f(rp.y);
            o1.x = a4 * inv + lo16f(rp.z);
            o1.y = a5 * inv + hi16f(rp.z);
            o1.z = a6 * inv + lo16f(rp.w);
            o1.w = a7 * inv + hi16f(rp.w);
            *(float4*)op = o0;
            *(float4*)(op + 4) = o1;
        }
    }
}

// ---------------------------------------------------------------------------
// launch
// ---------------------------------------------------------------------------

extern "C" void kernel_launch(void* const* d_in, const int* in_sizes, int n_in,
                              void* d_out, int out_size, void* d_ws, size_t ws_size,
                              hipStream_t stream) {
    const float* x = (const float*)d_in[0];
    const int* ei = (const int*)d_in[1];
    const float* W1l = (const float*)d_in[2];
    const float* b1 = (const float*)d_in[3];
    const float* W1r = (const float*)d_in[4];
    const float* W2l = (const float*)d_in[5];
    const float* b2 = (const float*)d_in[6];
    const float* W2r = (const float*)d_in[7];
    float* out = (float*)d_out;

    const int* src = ei;
    const int* dst = ei + N_EDGES_C;

    // int workspace region (first 16 MiB)
    int* iw = (int*)d_ws;
    int* chist = iw;                              // 256 (196 used)
    int* cbase = iw + 256;                        // 256
    int* ccursor = iw + 512;                      // 256
    int* deg = iw + 768;                          // 100000
    int* base = iw + 100768;                      // 100000
    unsigned* epkt2 = (unsigned*)(iw + 200768);   // 1600000
    unsigned* esrc = (unsigned*)(iw + 1800768);   // 1600000 -> ends 3400768
    u16* T1l = (u16*)(iw + 3400832);              // 4 x 32768 u16 = 256 KB
    u16* T1r = T1l + 32768;
    u16* T2l = T1r + 32768;
    u16* T2r = T2l + 32768;                       // ends ~13.9 MB < 16 MiB
    // bf16 region at byte offset 16 MiB; stride 12.85M u16 (sentinel row pad)
    u16* ub = (u16*)((char*)d_ws + (16u << 20));
    u16* x_bf = ub;                               // [100001][128]
    u16* p2 = ub + 12850000;                      // [100001][128]
    u16* outp = ub + 25700000;                    // [100000][128]

    hipMemsetAsync(chist, 0, 1024, stream);

    front_fused<<<CONV_BLOCKS + WB_BLOCKS + CH_BLOCKS + 1, 256, 0, stream>>>(
        x, dst, W1l, W1r, W2l, W2r, x_bf, T1l, T1r, T2l, T2r, chist, p2);
    cscan<<<1, 256, 0, stream>>>(chist, cbase, ccursor);
    coarse_scatter<<<K2_BLOCKS, 1024, 0, stream>>>(src, dst, ccursor, epkt2);
    fine_sort<<<NCB, 1024, 0, stream>>>(cbase, chist, epkt2, esrc, deg, base);

    // per bucket: gather-mean + GEMM L1 + GEMM L2 -> p2, outp
    fused_gemm_agg<<<NB, 512, 0, stream>>>(x_bf, deg, base, esrc, T1l, T1r, T2l,
                                           T2r, b1, b2, p2, outp, N_NODES_C);
    // out = mean_{src->node} p2 + outp   (fp32)
    agg_final<<<NB, 256, 0, stream>>>(p2, deg, base, esrc, outp, out);
}

// Round 8
// 343.491 us; speedup vs baseline: 1.7235x; 1.0629x over previous
//
#include <hip/hip_runtime.h>
#include <cstddef>

#define N_NODES_C 100000
#define N_EDGES_C 1600000

#define NPB 64               // nodes per block tile (= GEMM M-tile)
#define NB 1563              // ceil(100000/64)
#define SENT_ROW 100000      // zeroed sentinel row in feature tables

#define NCB 196              // coarse buckets of 512 nodes: ceil(100000/512)
#define K2_EPB 8192          // edges per coarse-scatter block
#define K2_BLOCKS 196        // ceil(1600000/8192)

#define CONV_BLOCKS 12500    // 3.2M float4 / 256
#define WB_BLOCKS 512        // weight transpose blocks

typedef unsigned short u16;
typedef __attribute__((ext_vector_type(8))) short bf16x8;
typedef __attribute__((ext_vector_type(4))) float f32x4;

__device__ __forceinline__ u16 f2bf(float f) {
    unsigned u = __float_as_uint(f);
    u += 0x7fffu + ((u >> 16) & 1);  // round-to-nearest-even
    return (u16)(u >> 16);
}
__device__ __forceinline__ float lo16f(unsigned v) {
    return __uint_as_float(v << 16);
}
__device__ __forceinline__ float hi16f(unsigned v) {
    return __uint_as_float(v & 0xffff0000u);
}

// ---------------------------------------------------------------------------
// Front fused: x fp32->bf16 convert | weight transpose+convert | sentinel
// zeroing. (Coarse hist moved to hist196 — the 1563-block LDS-hist flush was
// ~306K contended global atomics, ~23 us of per-address serialization.)
// ---------------------------------------------------------------------------

__global__ __launch_bounds__(256) void front_fused(
    const float* __restrict__ x,
    const float* __restrict__ W1l, const float* __restrict__ W1r,
    const float* __restrict__ W2l, const float* __restrict__ W2r,
    u16* __restrict__ x_bf, u16* __restrict__ T1l, u16* __restrict__ T1r,
    u16* __restrict__ T2l, u16* __restrict__ T2r, u16* __restrict__ p2z) {
    const int b = blockIdx.x;
    const int t = threadIdx.x;
    if (b < CONV_BLOCKS) {
        int i = b * 256 + t;
        if (i < 3200000) {
            float4 v = ((const float4*)x)[i];
            ushort4 o;
            o.x = f2bf(v.x); o.y = f2bf(v.y); o.z = f2bf(v.z); o.w = f2bf(v.w);
            ((ushort4*)x_bf)[i] = o;
        }
    } else if (b < CONV_BLOCKS + WB_BLOCKS) {
        int id = (b - CONV_BLOCKS) * 256 + t;  // 0..131071
        int which = id >> 15;
        int r = id & 32767;
        if (which == 0) {        // [128][256] -> [256][128]
            int n = r >> 7, k = r & 127;
            T1l[r] = f2bf(W1l[k * 256 + n]);
        } else if (which == 1) {
            int n = r >> 7, k = r & 127;
            T1r[r] = f2bf(W1r[k * 256 + n]);
        } else if (which == 2) {  // [256][128] -> [128][256]
            int n = r >> 8, k = r & 255;
            T2l[r] = f2bf(W2l[k * 128 + n]);
        } else {
            int n = r >> 8, k = r & 255;
            T2r[r] = f2bf(W2r[k * 128 + n]);
        }
    } else {
        // zero the sentinel rows (row SENT_ROW of x_bf and p2)
        uint4 z; z.x = 0; z.y = 0; z.z = 0; z.w = 0;
        if (t < 16)
            ((uint4*)(x_bf + (size_t)SENT_ROW * 128))[t] = z;
        else if (t < 32)
            ((uint4*)(p2z + (size_t)SENT_ROW * 128))[t - 16] = z;
    }
}

// ---------------------------------------------------------------------------
// Coarse histogram: 196 blocks, each LDS-hists its own 8192 edges, flushes
// <=196 global atomics per block (196 per address total — no storm).
// ---------------------------------------------------------------------------

__global__ __launch_bounds__(1024) void hist196(const int* __restrict__ dst,
                                                int* __restrict__ chist) {
    __shared__ int hist[NCB];
    const int t = threadIdx.x;
    if (t < NCB) hist[t] = 0;
    __syncthreads();
    const int e0 = blockIdx.x * K2_EPB;
#pragma unroll
    for (int r = 0; r < 2; ++r) {
        int i = (e0 >> 2) + r * 1024 + t;  // int4 index
        if (i * 4 < N_EDGES_C) {
            int4 d = ((const int4*)dst)[i];
            atomicAdd(&hist[d.x >> 9], 1);
            atomicAdd(&hist[d.y >> 9], 1);
            atomicAdd(&hist[d.z >> 9], 1);
            atomicAdd(&hist[d.w >> 9], 1);
        }
    }
    __syncthreads();
    if (t < NCB) {
        int c = hist[t];
        if (c) atomicAdd(&chist[t], c);
    }
}

// ---------------------------------------------------------------------------
// Coarse scan: exclusive scan of the 196 coarse-bucket counts.
// ---------------------------------------------------------------------------

__global__ __launch_bounds__(256) void cscan(const int* __restrict__ chist,
                                             int* __restrict__ cbase,
                                             int* __restrict__ ccursor) {
    __shared__ int s[256];
    int t = threadIdx.x;
    int v = (t < NCB) ? chist[t] : 0;
    s[t] = v;
    __syncthreads();
    for (int off = 1; off < 256; off <<= 1) {
        int u = (t >= off) ? s[t - off] : 0;
        __syncthreads();
        s[t] += u;
        __syncthreads();
    }
    if (t < NCB) {
        int e = s[t] - v;
        cbase[t] = e;
        ccursor[t] = e;
    }
}

// ---------------------------------------------------------------------------
// K2: coarse scatter. Block-local LDS counting-sort of 8192 edges by coarse
// bucket, then contiguous run-writes into epkt2.
// packed = (local9 << 17) | src17
// ---------------------------------------------------------------------------

__global__ __launch_bounds__(1024) void coarse_scatter(
    const int* __restrict__ src, const int* __restrict__ dst,
    int* __restrict__ ccursor, unsigned* __restrict__ epkt2) {
    __shared__ unsigned spkt[K2_EPB];
    __shared__ unsigned char scb[K2_EPB];
    __shared__ int hist[NCB], lstart[NCB], lcur[NCB], grun[NCB], stmp[NCB];

    const int t = threadIdx.x;
    const int e0 = blockIdx.x * K2_EPB;
    const int cnt = min(K2_EPB, N_EDGES_C - e0);

    if (t < NCB) hist[t] = 0;
    __syncthreads();

    int4 dd[2], ss[2];
    int vi[2];
#pragma unroll
    for (int r = 0; r < 2; ++r) {
        int i = (e0 >> 2) + r * 1024 + t;  // int4 index
        vi[r] = (i * 4 < N_EDGES_C);
        if (vi[r]) {
            dd[r] = ((const int4*)dst)[i];
            ss[r] = ((const int4*)src)[i];
            atomicAdd(&hist[dd[r].x >> 9], 1);
            atomicAdd(&hist[dd[r].y >> 9], 1);
            atomicAdd(&hist[dd[r].z >> 9], 1);
            atomicAdd(&hist[dd[r].w >> 9], 1);
        }
    }
    __syncthreads();

    if (t < NCB) stmp[t] = hist[t];
    __syncthreads();
    for (int off = 1; off < NCB; off <<= 1) {
        int v = 0;
        if (t < NCB && t >= off) v = stmp[t - off];
        __syncthreads();
        if (t < NCB) stmp[t] += v;
        __syncthreads();
    }
    if (t < NCB) {
        int excl = stmp[t] - hist[t];
        lstart[t] = excl;
        lcur[t] = excl;
        if (hist[t]) grun[t] = atomicAdd(&ccursor[t], hist[t]);
    }
    __syncthreads();

#pragma unroll
    for (int r = 0; r < 2; ++r) {
        if (vi[r]) {
            int4 d = dd[r];
            int4 s4 = ss[r];
            {
                int cb = d.x >> 9;
                int pos = atomicAdd(&lcur[cb], 1);
                spkt[pos] = ((unsigned)(d.x & 511) << 17) | (unsigned)s4.x;
                scb[pos] = (unsigned char)cb;
            }
            {
                int cb = d.y >> 9;
                int pos = atomicAdd(&lcur[cb], 1);
                spkt[pos] = ((unsigned)(d.y & 511) << 17) | (unsigned)s4.y;
                scb[pos] = (unsigned char)cb;
            }
            {
                int cb = d.z >> 9;
                int pos = atomicAdd(&lcur[cb], 1);
                spkt[pos] = ((unsigned)(d.z & 511) << 17) | (unsigned)s4.z;
                scb[pos] = (unsigned char)cb;
            }
            {
                int cb = d.w >> 9;
                int pos = atomicAdd(&lcur[cb], 1);
                spkt[pos] = ((unsigned)(d.w & 511) << 17) | (unsigned)s4.w;
                scb[pos] = (unsigned char)cb;
            }
        }
    }
    __syncthreads();

#pragma unroll
    for (int k = 0; k < K2_EPB / 1024; ++k) {
        int i = k * 1024 + t;
        if (i < cnt) {
            int cb = scb[i];
            epkt2[grun[cb] + (i - lstart[cb])] = spkt[i];
        }
    }
}

// ---------------------------------------------------------------------------
// K3: fine sort within each coarse bucket. One block per coarse bucket
// (~8.2K edges, L2-resident window). Produces node-contiguous esrc plus
// deg[] and base[].
// ---------------------------------------------------------------------------

__global__ __launch_bounds__(1024) void fine_sort(
    const int* __restrict__ cbase, const int* __restrict__ chist,
    const unsigned* __restrict__ epkt2, unsigned* __restrict__ esrc,
    int* __restrict__ deg, int* __restrict__ base) {
    __shared__ int hist[512], lstart[512], lcur[512], stmp[512];
    const int t = threadIdx.x;
    const int c = blockIdx.x;
    const int s0 = cbase[c];
    const int cnt = chist[c];

    if (t < 512) hist[t] = 0;
    __syncthreads();

    for (int i = t; i < cnt; i += 1024)
        atomicAdd(&hist[epkt2[s0 + i] >> 17], 1);
    __syncthreads();

    if (t < 512) stmp[t] = hist[t];
    __syncthreads();
    for (int off = 1; off < 512; off <<= 1) {
        int v = 0;
        if (t < 512 && t >= off) v = stmp[t - off];
        __syncthreads();
        if (t < 512) stmp[t] += v;
        __syncthreads();
    }
    if (t < 512) {
        int excl = stmp[t] - hist[t];
        lstart[t] = excl;
        lcur[t] = excl;
        int node = c * 512 + t;
        if (node < N_NODES_C) {
            deg[node] = hist[t];
            base[node] = s0 + excl;
        }
    }
    __syncthreads();

    for (int i = t; i < cnt; i += 1024) {
        unsigned p = epkt2[s0 + i];
        int pos = atomicAdd(&lcur[p >> 17], 1);
        esrc[s0 + pos] = p & 0x1ffffu;
    }
}

// ---------------------------------------------------------------------------
// Fused per-bucket kernel (512 thr = 8 waves) — round-4 proven structure:
//   gather: mean_{src->node} x_bf -> meanS (LDS, chunk-swizzled)
//   xS: block's own x rows staged async (pre-swizzled source)
//   phase A: h = relu(meanS@W1l + xS@W1r + b1) -> hfrag (aliases meanS|xS)
//   phase B: p2 = h@W2l, outp = h@W2r + b2
// Weights staged through Bs via global_load_lds (direct global B-reads are
// latency-serialized — round 6 regression). LDS 48KB -> 3 blocks/CU.
// ---------------------------------------------------------------------------

__global__ __launch_bounds__(512, 6) void fused_gemm_agg(
    const u16* __restrict__ x_bf, const int* __restrict__ deg,
    const int* __restrict__ base, const unsigned* __restrict__ esrc,
    const u16* __restrict__ T1l, const u16* __restrict__ T1r,   // [256][128]
    const u16* __restrict__ T2l, const u16* __restrict__ T2r,   // [128][256]
    const float* __restrict__ b1, const float* __restrict__ b2,
    u16* __restrict__ p2, u16* __restrict__ outp, int M) {
    alignas(16) __shared__ u16 uni[64 * 256];  // 32KB: [meanS|xS] then hfrag
    alignas(16) __shared__ u16 Bs[8192];       // 16KB weight staging

    u16* const meanS = uni;           // [64][128], 16B-chunk ^ (row&7)
    u16* const xS = uni + 64 * 128;   // [64][128], same swizzle
    u16* const hfrag = uni;           // phase-B alias (32KB)

    const int tid = threadIdx.x;
    const int lane = tid & 63;
    const int wave = tid >> 6;
    const int qm = lane & 15;
    const int quad = lane >> 4;
    const int b = blockIdx.x;
    const int m0 = b * 64;

    // ---- issue xS staging early (lands during gather) ----
#pragma unroll
    for (int r = 0; r < 2; ++r) {
        int c = r * 512 + tid;          // 1024 chunks of 16B
        int row = c >> 4, q16 = c & 15;
        __builtin_amdgcn_global_load_lds(
            (const __attribute__((address_space(1))) unsigned*)(
                x_bf + (size_t)(m0 + row) * 128 + ((q16 ^ (row & 7)) * 8)),
            (__attribute__((address_space(3))) unsigned*)(xS + c * 8), 16, 0, 0);
    }

    // ---- gather + mean -> meanS (bf16, swizzled) ----
    const int li8 = qm * 8;
    const int gbase = lane & 48;  // group base lane within wave

    for (int pass = 0; pass < 2; ++pass) {
        int n = pass * 32 + wave * 4 + quad;   // 0..63
        int node = m0 + n;
        int d = 0, s0 = 0;
        if (node < N_NODES_C) { d = deg[node]; s0 = base[node]; }
        int dmax = max(d, __shfl_xor(d, 16, 64));
        dmax = max(dmax, __shfl_xor(dmax, 32, 64));

        float a0 = 0.f, a1 = 0.f, a2 = 0.f, a3 = 0.f;
        float a4 = 0.f, a5 = 0.f, a6 = 0.f, a7 = 0.f;

        for (int j = 0; j < dmax; j += 16) {
            int jj = j + qm;
            unsigned sidx = (jj < d) ? esrc[s0 + jj] : (unsigned)SENT_ROW;
            for (int u = 0; u < 16 && j + u < dmax; u += 4) {
                unsigned i0 = __shfl(sidx, gbase + u, 64);
                unsigned i1 = __shfl(sidx, gbase + u + 1, 64);
                unsigned i2 = __shfl(sidx, gbase + u + 2, 64);
                unsigned i3 = __shfl(sidx, gbase + u + 3, 64);
                uint4 r0 = *(const uint4*)(x_bf + (size_t)i0 * 128 + li8);
                uint4 r1 = *(const uint4*)(x_bf + (size_t)i1 * 128 + li8);
                uint4 r2 = *(const uint4*)(x_bf + (size_t)i2 * 128 + li8);
                uint4 r3 = *(const uint4*)(x_bf + (size_t)i3 * 128 + li8);
                a0 += lo16f(r0.x); a1 += hi16f(r0.x);
                a2 += lo16f(r0.y); a3 += hi16f(r0.y);
                a4 += lo16f(r0.z); a5 += hi16f(r0.z);
                a6 += lo16f(r0.w); a7 += hi16f(r0.w);
                a0 += lo16f(r1.x); a1 += hi16f(r1.x);
                a2 += lo16f(r1.y); a3 += hi16f(r1.y);
                a4 += lo16f(r1.z); a5 += hi16f(r1.z);
                a6 += lo16f(r1.w); a7 += hi16f(r1.w);
                a0 += lo16f(r2.x); a1 += hi16f(r2.x);
                a2 += lo16f(r2.y); a3 += hi16f(r2.y);
                a4 += lo16f(r2.z); a5 += hi16f(r2.z);
                a6 += lo16f(r2.w); a7 += hi16f(r2.w);
                a0 += lo16f(r3.x); a1 += hi16f(r3.x);
                a2 += lo16f(r3.y); a3 += hi16f(r3.y);
                a4 += lo16f(r3.z); a5 += hi16f(r3.z);
                a6 += lo16f(r3.w); a7 += hi16f(r3.w);
            }
        }

        float inv = d > 0 ? 1.f / (float)d : 0.f;
        uint4 o;
        o.x = (unsigned)f2bf(a0 * inv) | ((unsigned)f2bf(a1 * inv) << 16);
        o.y = (unsigned)f2bf(a2 * inv) | ((unsigned)f2bf(a3 * inv) << 16);
        o.z = (unsigned)f2bf(a4 * inv) | ((unsigned)f2bf(a5 * inv) << 16);
        o.w = (unsigned)f2bf(a6 * inv) | ((unsigned)f2bf(a7 * inv) << 16);
        *(uint4*)(meanS + n * 128 + ((qm ^ (n & 7)) * 8)) = o;
    }
    __syncthreads();

    // ---------------- phase A: h tile (8 waves: 4M x 2N) ----------------
    const int wr0 = (wave >> 1) * 16;   // rows 0/16/32/48
    const int wc0 = (wave & 1) * 128;   // cols 0/128
    f32x4 acch[8];
#pragma unroll
    for (int j = 0; j < 8; ++j) acch[j] = (f32x4){0.f, 0.f, 0.f, 0.f};

#pragma unroll
    for (int mat = 0; mat < 2; ++mat) {
        const u16* __restrict__ W = mat ? T1r : T1l;
        const u16* Al = mat ? xS : meanS;
#pragma unroll
        for (int k0 = 0; k0 < 128; k0 += 32) {
            // Bs: 256x32 (1024 chunks, 2/thread), source pre-swizzled (^row&3)
#pragma unroll
            for (int r = 0; r < 2; ++r) {
                int c = r * 512 + tid;
                int row = c >> 2, kc = c & 3;
                __builtin_amdgcn_global_load_lds(
                    (const __attribute__((address_space(1))) unsigned*)(
                        W + (size_t)row * 128 + k0 + ((kc ^ (row & 3)) * 8)),
                    (__attribute__((address_space(3))) unsigned*)(Bs + c * 8), 16, 0, 0);
            }
            __syncthreads();
            int ch0 = k0 >> 3;
            int rowA = wr0 + qm;
            bf16x8 af = *(const bf16x8*)(Al + rowA * 128 +
                                         (((ch0 + quad) ^ (rowA & 7)) * 8));
            bf16x8 bfv[8];
#pragma unroll
            for (int j = 0; j < 8; ++j) {
                int rB = wc0 + j * 16 + qm;
                bfv[j] = *(const bf16x8*)(Bs + rB * 32 + ((quad ^ (rB & 3)) * 8));
            }
#pragma unroll
            for (int j = 0; j < 8; ++j)
                acch[j] = __builtin_amdgcn_mfma_f32_16x16x32_bf16(af, bfv[j],
                                                                  acch[j], 0, 0, 0);
            __syncthreads();
        }
    }

    // epilogue A: +b1, relu, write to hfrag (aliases meanS/xS — dead now)
#pragma unroll
    for (int j = 0; j < 8; ++j) {
        int n = wc0 + j * 16 + qm;
        float bb = b1[n];
        int ks = n >> 5, quadB = (n >> 3) & 3, jB = n & 7;
#pragma unroll
        for (int r = 0; r < 4; ++r) {
            int mloc = wr0 + quad * 4 + r;
            float v = fmaxf(acch[j][r] + bb, 0.f);
            hfrag[((ks * 4 + (mloc >> 4)) * 16 + (mloc & 15)) * 32 + quadB * 8 + jB] =
                f2bf(v);
        }
    }
    __syncthreads();

    // ---------------- phase B: p2 / outp (8 waves: 4M x 2N) ----------------
    const int wrB = (wave >> 1) * 16;   // rows 0/16/32/48
    const int wcB = (wave & 1) * 64;    // cols 0/64 (of 128)
    f32x4 accp[4], acco[4];
#pragma unroll
    for (int j = 0; j < 4; ++j) {
        accp[j] = (f32x4){0.f, 0.f, 0.f, 0.f};
        acco[j] = (f32x4){0.f, 0.f, 0.f, 0.f};
    }

#pragma unroll
    for (int ks = 0; ks < 8; ++ks) {
        // stage W2l|W2r k-chunk: Bs[mat][128][32], 1024 chunks, 2/thread
#pragma unroll
        for (int r = 0; r < 2; ++r) {
            int c = r * 512 + tid;
            int matc = c >> 9;
            int row = (c >> 2) & 127;
            int kc = c & 3;
            const u16* W = matc ? T2r : T2l;
            __builtin_amdgcn_global_load_lds(
                (const __attribute__((address_space(1))) unsigned*)(
                    W + (size_t)row * 256 + ks * 32 + ((kc ^ (row & 3)) * 8)),
                (__attribute__((address_space(3))) unsigned*)(Bs + c * 8), 16, 0, 0);
        }
        __syncthreads();
        bf16x8 af = *(const bf16x8*)(hfrag +
                                     ((ks * 4 + (wrB >> 4)) * 16 + qm) * 32 + quad * 8);
        bf16x8 bfl[4], bfr[4];
#pragma unroll
        for (int j = 0; j < 4; ++j) {
            int rB = wcB + j * 16 + qm;
            bfl[j] = *(const bf16x8*)(Bs + rB * 32 + ((quad ^ (rB & 3)) * 8));
            bfr[j] = *(const bf16x8*)(Bs + 4096 + rB * 32 + ((quad ^ (rB & 3)) * 8));
        }
#pragma unroll
        for (int j = 0; j < 4; ++j) {
            accp[j] = __builtin_amdgcn_mfma_f32_16x16x32_bf16(af, bfl[j],
                                                              accp[j], 0, 0, 0);
            acco[j] = __builtin_amdgcn_mfma_f32_16x16x32_bf16(af, bfr[j],
                                                              acco[j], 0, 0, 0);
        }
        __syncthreads();
    }

    // epilogue B
#pragma unroll
    for (int j = 0; j < 4; ++j) {
        int n = wcB + j * 16 + qm;
        float bb2 = b2[n];
#pragma unroll
        for (int r = 0; r < 4; ++r) {
            int row = m0 + wrB + quad * 4 + r;
            if (row < M) {
                p2[(size_t)row * 128 + n] = f2bf(accp[j][r]);
                outp[(size_t)row * 128 + n] = f2bf(acco[j][r] + bb2);
            }
        }
    }
}

// ---------------------------------------------------------------------------
// Final aggregation: out = mean_{src->node} p2 + outp  (fp32). LDS-free.
// ---------------------------------------------------------------------------

__global__ __launch_bounds__(256, 8) void agg_final(const u16* __restrict__ tbl,
                                                    const int* __restrict__ deg,
                                                    const int* __restrict__ base,
                                                    const unsigned* __restrict__ esrc,
                                                    const u16* __restrict__ resid,
                                                    float* __restrict__ outv) {
    const int t = threadIdx.x;
    const int wave = t >> 6;
    const int lane = t & 63;
    const int qm = lane & 15;
    const int quad = lane >> 4;
    const int b = blockIdx.x;
    const int li8 = qm * 8;
    const int gbase = lane & 48;

    for (int pass = 0; pass < 4; ++pass) {
        int n = pass * 16 + wave * 4 + quad;   // 0..63
        int node = b * NPB + n;
        bool valid = node < N_NODES_C;
        int d = 0, s0 = 0;
        if (valid) { d = deg[node]; s0 = base[node]; }
        int dmax = max(d, __shfl_xor(d, 16, 64));
        dmax = max(dmax, __shfl_xor(dmax, 32, 64));

        float a0 = 0.f, a1 = 0.f, a2 = 0.f, a3 = 0.f;
        float a4 = 0.f, a5 = 0.f, a6 = 0.f, a7 = 0.f;

        for (int j = 0; j < dmax; j += 16) {
            int jj = j + qm;
            unsigned sidx = (jj < d) ? esrc[s0 + jj] : (unsigned)SENT_ROW;
            for (int u = 0; u < 16 && j + u < dmax; u += 4) {
                unsigned i0 = __shfl(sidx, gbase + u, 64);
                unsigned i1 = __shfl(sidx, gbase + u + 1, 64);
                unsigned i2 = __shfl(sidx, gbase + u + 2, 64);
                unsigned i3 = __shfl(sidx, gbase + u + 3, 64);
                uint4 r0 = *(const uint4*)(tbl + (size_t)i0 * 128 + li8);
                uint4 r1 = *(const uint4*)(tbl + (size_t)i1 * 128 + li8);
                uint4 r2 = *(const uint4*)(tbl + (size_t)i2 * 128 + li8);
                uint4 r3 = *(const uint4*)(tbl + (size_t)i3 * 128 + li8);
                a0 += lo16f(r0.x); a1 += hi16f(r0.x);
                a2 += lo16f(r0.y); a3 += hi16f(r0.y);
                a4 += lo16f(r0.z); a5 += hi16f(r0.z);
                a6 += lo16f(r0.w); a7 += hi16f(r0.w);
                a0 += lo16f(r1.x); a1 += hi16f(r1.x);
                a2 += lo16f(r1.y); a3 += hi16f(r1.y);
                a4 += lo16f(r1.z); a5 += hi16f(r1.z);
                a6 += lo16f(r1.w); a7 += hi16f(r1.w);
                a0 += lo16f(r2.x); a1 += hi16f(r2.x);
                a2 += lo16f(r2.y); a3 += hi16f(r2.y);
                a4 += lo16f(r2.z); a5 += hi16f(r2.z);
                a6 += lo16f(r2.w); a7 += hi16f(r2.w);
                a0 += lo16f(r3.x); a1 += hi16f(r3.x);
                a2 += lo16f(r3.y); a3 += hi16f(r3.y);
                a4 += lo16f(r3.z); a5 += hi16f(r3.z);
                a6 += lo16f(r3.w); a7 += hi16f(r3.w);
            }
        }

        if (valid) {
            float inv = d > 0 ? 1.f / (float)d : 0.f;
            uint4 rp = *(const uint4*)(resid + (size_t)node * 128 + li8);
            float* op = outv + (size_t)node * 128 + li8;
            float4 o0, o1;
            o0.x = a0 * inv + lo16f(rp.x);
            o0.y = a1 * inv + hi16f(rp.x);
            o0.z = a2 * inv + lo16f(rp.y);
            o0.w = a3 * inv + hi16f(rp.y);
            o1.x = a4 * inv + lo16f(rp.z);
            o1.y = a5 * inv + hi16f(rp.z);
            o1.z = a6 * inv + lo16f(rp.w);
            o1.w = a7 * inv + hi16f(rp.w);
            *(float4*)op = o0;
            *(float4*)(op + 4) = o1;
        }
    }
}

// ---------------------------------------------------------------------------
// launch
// ---------------------------------------------------------------------------

extern "C" void kernel_launch(void* const* d_in, const int* in_sizes, int n_in,
                              void* d_out, int out_size, void* d_ws, size_t ws_size,
                              hipStream_t stream) {
    const float* x = (const float*)d_in[0];
    const int* ei = (const int*)d_in[1];
    const float* W1l = (const float*)d_in[2];
    const float* b1 = (const float*)d_in[3];
    const float* W1r = (const float*)d_in[4];
    const float* W2l = (const float*)d_in[5];
    const float* b2 = (const float*)d_in[6];
    const float* W2r = (const float*)d_in[7];
    float* out = (float*)d_out;

    const int* src = ei;
    const int* dst = ei + N_EDGES_C;

    // int workspace region (first 16 MiB)
    int* iw = (int*)d_ws;
    int* chist = iw;                              // 256 (196 used)
    int* cbase = iw + 256;                        // 256
    int* ccursor = iw + 512;                      // 256
    int* deg = iw + 768;                          // 100000
    int* base = iw + 100768;                      // 100000
    unsigned* epkt2 = (unsigned*)(iw + 200768);   // 1600000
    unsigned* esrc = (unsigned*)(iw + 1800768);   // 1600000 -> ends 3400768
    u16* T1l = (u16*)(iw + 3400832);              // 4 x 32768 u16 = 256 KB
    u16* T1r = T1l + 32768;
    u16* T2l = T1r + 32768;
    u16* T2r = T2l + 32768;                       // ends ~13.9 MB < 16 MiB
    // bf16 region at byte offset 16 MiB; stride 12.85M u16 (sentinel row pad)
    u16* ub = (u16*)((char*)d_ws + (16u << 20));
    u16* x_bf = ub;                               // [100001][128]
    u16* p2 = ub + 12850000;                      // [100001][128]
    u16* outp = ub + 25700000;                    // [100000][128]

    hipMemsetAsync(chist, 0, 1024, stream);

    front_fused<<<CONV_BLOCKS + WB_BLOCKS + 1, 256, 0, stream>>>(
        x, W1l, W1r, W2l, W2r, x_bf, T1l, T1r, T2l, T2r, p2);
    hist196<<<K2_BLOCKS, 1024, 0, stream>>>(dst, chist);
    cscan<<<1, 256, 0, stream>>>(chist, cbase, ccursor);
    coarse_scatter<<<K2_BLOCKS, 1024, 0, stream>>>(src, dst, ccursor, epkt2);
    fine_sort<<<NCB, 1024, 0, stream>>>(cbase, chist, epkt2, esrc, deg, base);

    // per bucket: gather-mean + GEMM L1 + GEMM L2 -> p2, outp
    fused_gemm_agg<<<NB, 512, 0, stream>>>(x_bf, deg, base, esrc, T1l, T1r, T2l,
                                           T2r, b1, b2, p2, outp, N_NODES_C);
    // out = mean_{src->node} p2 + outp   (fp32)
    agg_final<<<NB, 256, 0, stream>>>(p2, deg, base, esrc, outp, out);
}

// Round 9
// 337.305 us; speedup vs baseline: 1.7551x; 1.0183x over previous
//
#include <hip/hip_runtime.h>
#include <cstddef>

#define N_NODES_C 100000
#define N_EDGES_C 1600000

#define NPB 64               // nodes per block tile (= GEMM M-tile)
#define NB 1563              // ceil(100000/64)
#define SENT_ROW 100000      // zeroed sentinel row in feature tables

#define NCB 196              // coarse buckets of 512 nodes: ceil(100000/512)
#define K2_EPB 8192          // edges per coarse-scatter block
#define K2_BLOCKS 196        // ceil(1600000/8192)

#define CONV1_BLOCKS 1563    // conv float4 blocks in scatter_conv (1024/blk)
#define CONV2_BLOCKS 1562    // conv float4 blocks in sort_conv

typedef unsigned short u16;
typedef __attribute__((ext_vector_type(8))) short bf16x8;
typedef __attribute__((ext_vector_type(4))) float f32x4;

__device__ __forceinline__ u16 f2bf(float f) {
    unsigned u = __float_as_uint(f);
    u += 0x7fffu + ((u >> 16) & 1);  // round-to-nearest-even
    return (u16)(u >> 16);
}
__device__ __forceinline__ float lo16f(unsigned v) {
    return __uint_as_float(v << 16);
}
__device__ __forceinline__ float hi16f(unsigned v) {
    return __uint_as_float(v & 0xffff0000u);
}

__device__ __forceinline__ void conv_chunk(const float* __restrict__ x,
                                           u16* __restrict__ x_bf, int i) {
    // one float4 -> ushort4 bf16 convert at index i (no bound check; caller
    // guarantees i < 3200000)
    float4 v = ((const float4*)x)[i];
    ushort4 o;
    o.x = f2bf(v.x); o.y = f2bf(v.y); o.z = f2bf(v.z); o.w = f2bf(v.w);
    ((ushort4*)x_bf)[i] = o;
}

// ---------------------------------------------------------------------------
// prep_a: coarse hist (196 blocks) | weight transpose (128 blocks) |
// sentinel zeroing (1 block). 1024 threads.
// ---------------------------------------------------------------------------

__global__ __launch_bounds__(1024) void prep_a(
    const int* __restrict__ dst,
    const float* __restrict__ W1l, const float* __restrict__ W1r,
    const float* __restrict__ W2l, const float* __restrict__ W2r,
    u16* __restrict__ T1l, u16* __restrict__ T1r,
    u16* __restrict__ T2l, u16* __restrict__ T2r,
    int* __restrict__ chist, u16* __restrict__ x_bf, u16* __restrict__ p2z) {
    const int b = blockIdx.x;
    const int t = threadIdx.x;
    if (b < K2_BLOCKS) {
        __shared__ int hist[NCB];
        if (t < NCB) hist[t] = 0;
        __syncthreads();
        const int e0 = b * K2_EPB;
#pragma unroll
        for (int r = 0; r < 2; ++r) {
            int i = (e0 >> 2) + r * 1024 + t;  // int4 index
            if (i * 4 < N_EDGES_C) {
                int4 d = ((const int4*)dst)[i];
                atomicAdd(&hist[d.x >> 9], 1);
                atomicAdd(&hist[d.y >> 9], 1);
                atomicAdd(&hist[d.z >> 9], 1);
                atomicAdd(&hist[d.w >> 9], 1);
            }
        }
        __syncthreads();
        if (t < NCB) {
            int c = hist[t];
            if (c) atomicAdd(&chist[t], c);
        }
    } else if (b < K2_BLOCKS + 128) {
        int id = (b - K2_BLOCKS) * 1024 + t;  // 0..131071
        int which = id >> 15;
        int r = id & 32767;
        if (which == 0) {        // [128][256] -> [256][128]
            int n = r >> 7, k = r & 127;
            T1l[r] = f2bf(W1l[k * 256 + n]);
        } else if (which == 1) {
            int n = r >> 7, k = r & 127;
            T1r[r] = f2bf(W1r[k * 256 + n]);
        } else if (which == 2) {  // [256][128] -> [128][256]
            int n = r >> 8, k = r & 255;
            T2l[r] = f2bf(W2l[k * 128 + n]);
        } else {
            int n = r >> 8, k = r & 255;
            T2r[r] = f2bf(W2r[k * 128 + n]);
        }
    } else {
        uint4 z; z.x = 0; z.y = 0; z.z = 0; z.w = 0;
        if (t < 16)
            ((uint4*)(x_bf + (size_t)SENT_ROW * 128))[t] = z;
        else if (t < 32)
            ((uint4*)(p2z + (size_t)SENT_ROW * 128))[t - 16] = z;
    }
}

// ---------------------------------------------------------------------------
// Coarse scan: exclusive scan of the 196 coarse-bucket counts.
// ---------------------------------------------------------------------------

__global__ __launch_bounds__(256) void cscan(const int* __restrict__ chist,
                                             int* __restrict__ cbase,
                                             int* __restrict__ ccursor) {
    __shared__ int s[256];
    int t = threadIdx.x;
    int v = (t < NCB) ? chist[t] : 0;
    s[t] = v;
    __syncthreads();
    for (int off = 1; off < 256; off <<= 1) {
        int u = (t >= off) ? s[t - off] : 0;
        __syncthreads();
        s[t] += u;
        __syncthreads();
    }
    if (t < NCB) {
        int e = s[t] - v;
        cbase[t] = e;
        ccursor[t] = e;
    }
}

// ---------------------------------------------------------------------------
// scatter_conv: coarse scatter (196 blocks) | x conversion part 1 (1563).
// Conversion's streaming BW fills CUs the latency-bound scatter leaves idle.
// packed = (local9 << 17) | src17
// ---------------------------------------------------------------------------

__global__ __launch_bounds__(1024) void scatter_conv(
    const int* __restrict__ src, const int* __restrict__ dst,
    int* __restrict__ ccursor, unsigned* __restrict__ epkt2,
    const float* __restrict__ x, u16* __restrict__ x_bf) {
    __shared__ unsigned spkt[K2_EPB];
    __shared__ unsigned char scb[K2_EPB];
    __shared__ int hist[NCB], lstart[NCB], lcur[NCB], grun[NCB], stmp[NCB];

    const int t = threadIdx.x;
    const int b = blockIdx.x;
    if (b >= K2_BLOCKS) {
        conv_chunk(x, x_bf, (b - K2_BLOCKS) * 1024 + t);  // i < 1600512
        return;
    }
    const int e0 = b * K2_EPB;
    const int cnt = min(K2_EPB, N_EDGES_C - e0);

    if (t < NCB) hist[t] = 0;
    __syncthreads();

    int4 dd[2], ss[2];
    int vi[2];
#pragma unroll
    for (int r = 0; r < 2; ++r) {
        int i = (e0 >> 2) + r * 1024 + t;  // int4 index
        vi[r] = (i * 4 < N_EDGES_C);
        if (vi[r]) {
            dd[r] = ((const int4*)dst)[i];
            ss[r] = ((const int4*)src)[i];
            atomicAdd(&hist[dd[r].x >> 9], 1);
            atomicAdd(&hist[dd[r].y >> 9], 1);
            atomicAdd(&hist[dd[r].z >> 9], 1);
            atomicAdd(&hist[dd[r].w >> 9], 1);
        }
    }
    __syncthreads();

    if (t < NCB) stmp[t] = hist[t];
    __syncthreads();
    for (int off = 1; off < NCB; off <<= 1) {
        int v = 0;
        if (t < NCB && t >= off) v = stmp[t - off];
        __syncthreads();
        if (t < NCB) stmp[t] += v;
        __syncthreads();
    }
    if (t < NCB) {
        int excl = stmp[t] - hist[t];
        lstart[t] = excl;
        lcur[t] = excl;
        if (hist[t]) grun[t] = atomicAdd(&ccursor[t], hist[t]);
    }
    __syncthreads();

#pragma unroll
    for (int r = 0; r < 2; ++r) {
        if (vi[r]) {
            int4 d = dd[r];
            int4 s4 = ss[r];
            {
                int cb = d.x >> 9;
                int pos = atomicAdd(&lcur[cb], 1);
                spkt[pos] = ((unsigned)(d.x & 511) << 17) | (unsigned)s4.x;
                scb[pos] = (unsigned char)cb;
            }
            {
                int cb = d.y >> 9;
                int pos = atomicAdd(&lcur[cb], 1);
                spkt[pos] = ((unsigned)(d.y & 511) << 17) | (unsigned)s4.y;
                scb[pos] = (unsigned char)cb;
            }
            {
                int cb = d.z >> 9;
                int pos = atomicAdd(&lcur[cb], 1);
                spkt[pos] = ((unsigned)(d.z & 511) << 17) | (unsigned)s4.z;
                scb[pos] = (unsigned char)cb;
            }
            {
                int cb = d.w >> 9;
                int pos = atomicAdd(&lcur[cb], 1);
                spkt[pos] = ((unsigned)(d.w & 511) << 17) | (unsigned)s4.w;
                scb[pos] = (unsigned char)cb;
            }
        }
    }
    __syncthreads();

#pragma unroll
    for (int k = 0; k < K2_EPB / 1024; ++k) {
        int i = k * 1024 + t;
        if (i < cnt) {
            int cb = scb[i];
            epkt2[grun[cb] + (i - lstart[cb])] = spkt[i];
        }
    }
}

// ---------------------------------------------------------------------------
// sort_conv: fine sort (196 blocks) | x conversion part 2 (1562 blocks).
// Produces node-contiguous esrc plus deg[] and base[].
// ---------------------------------------------------------------------------

__global__ __launch_bounds__(1024) void sort_conv(
    const int* __restrict__ cbase, const int* __restrict__ chist,
    const unsigned* __restrict__ epkt2, unsigned* __restrict__ esrc,
    int* __restrict__ deg, int* __restrict__ base,
    const float* __restrict__ x, u16* __restrict__ x_bf) {
    __shared__ int hist[512], lstart[512], lcur[512], stmp[512];
    const int t = threadIdx.x;
    const int c = blockIdx.x;
    if (c >= K2_BLOCKS) {
        conv_chunk(x, x_bf, 1600512 + (c - K2_BLOCKS) * 1024 + t);  // <3.2M
        return;
    }
    const int s0 = cbase[c];
    const int cnt = chist[c];

    if (t < 512) hist[t] = 0;
    __syncthreads();

    for (int i = t; i < cnt; i += 1024)
        atomicAdd(&hist[epkt2[s0 + i] >> 17], 1);
    __syncthreads();

    if (t < 512) stmp[t] = hist[t];
    __syncthreads();
    for (int off = 1; off < 512; off <<= 1) {
        int v = 0;
        if (t < 512 && t >= off) v = stmp[t - off];
        __syncthreads();
        if (t < 512) stmp[t] += v;
        __syncthreads();
    }
    if (t < 512) {
        int excl = stmp[t] - hist[t];
        lstart[t] = excl;
        lcur[t] = excl;
        int node = c * 512 + t;
        if (node < N_NODES_C) {
            deg[node] = hist[t];
            base[node] = s0 + excl;
        }
    }
    __syncthreads();

    for (int i = t; i < cnt; i += 1024) {
        unsigned p = epkt2[s0 + i];
        int pos = atomicAdd(&lcur[p >> 17], 1);
        esrc[s0 + pos] = p & 0x1ffffu;
    }
}

// ---------------------------------------------------------------------------
// Fused per-bucket kernel (512 thr = 8 waves) — round-4 proven structure:
//   gather: mean_{src->node} x_bf -> meanS (LDS, chunk-swizzled)
//   xS: block's own x rows staged async (pre-swizzled source)
//   phase A: h = relu(meanS@W1l + xS@W1r + b1) -> hfrag (aliases meanS|xS)
//   phase B: p2 = h@W2l, outp = h@W2r + b2
// Weights staged through Bs via global_load_lds (direct global B-reads are
// latency-serialized — round 6 regression). LDS 48KB -> 3 blocks/CU.
// ---------------------------------------------------------------------------

__global__ __launch_bounds__(512, 6) void fused_gemm_agg(
    const u16* __restrict__ x_bf, const int* __restrict__ deg,
    const int* __restrict__ base, const unsigned* __restrict__ esrc,
    const u16* __restrict__ T1l, const u16* __restrict__ T1r,   // [256][128]
    const u16* __restrict__ T2l, const u16* __restrict__ T2r,   // [128][256]
    const float* __restrict__ b1, const float* __restrict__ b2,
    u16* __restrict__ p2, u16* __restrict__ outp, int M) {
    alignas(16) __shared__ u16 uni[64 * 256];  // 32KB: [meanS|xS] then hfrag
    alignas(16) __shared__ u16 Bs[8192];       // 16KB weight staging

    u16* const meanS = uni;           // [64][128], 16B-chunk ^ (row&7)
    u16* const xS = uni + 64 * 128;   // [64][128], same swizzle
    u16* const hfrag = uni;           // phase-B alias (32KB)

    const int tid = threadIdx.x;
    const int lane = tid & 63;
    const int wave = tid >> 6;
    const int qm = lane & 15;
    const int quad = lane >> 4;
    const int b = blockIdx.x;
    const int m0 = b * 64;

    // ---- issue xS staging early (lands during gather) ----
#pragma unroll
    for (int r = 0; r < 2; ++r) {
        int c = r * 512 + tid;          // 1024 chunks of 16B
        int row = c >> 4, q16 = c & 15;
        __builtin_amdgcn_global_load_lds(
            (const __attribute__((address_space(1))) unsigned*)(
                x_bf + (size_t)(m0 + row) * 128 + ((q16 ^ (row & 7)) * 8)),
            (__attribute__((address_space(3))) unsigned*)(xS + c * 8), 16, 0, 0);
    }

    // ---- gather + mean -> meanS (bf16, swizzled) ----
    const int li8 = qm * 8;
    const int gbase = lane & 48;  // group base lane within wave

    for (int pass = 0; pass < 2; ++pass) {
        int n = pass * 32 + wave * 4 + quad;   // 0..63
        int node = m0 + n;
        int d = 0, s0 = 0;
        if (node < N_NODES_C) { d = deg[node]; s0 = base[node]; }
        int dmax = max(d, __shfl_xor(d, 16, 64));
        dmax = max(dmax, __shfl_xor(dmax, 32, 64));

        float a0 = 0.f, a1 = 0.f, a2 = 0.f, a3 = 0.f;
        float a4 = 0.f, a5 = 0.f, a6 = 0.f, a7 = 0.f;

        for (int j = 0; j < dmax; j += 16) {
            int jj = j + qm;
            unsigned sidx = (jj < d) ? esrc[s0 + jj] : (unsigned)SENT_ROW;
            for (int u = 0; u < 16 && j + u < dmax; u += 4) {
                unsigned i0 = __shfl(sidx, gbase + u, 64);
                unsigned i1 = __shfl(sidx, gbase + u + 1, 64);
                unsigned i2 = __shfl(sidx, gbase + u + 2, 64);
                unsigned i3 = __shfl(sidx, gbase + u + 3, 64);
                uint4 r0 = *(const uint4*)(x_bf + (size_t)i0 * 128 + li8);
                uint4 r1 = *(const uint4*)(x_bf + (size_t)i1 * 128 + li8);
                uint4 r2 = *(const uint4*)(x_bf + (size_t)i2 * 128 + li8);
                uint4 r3 = *(const uint4*)(x_bf + (size_t)i3 * 128 + li8);
                a0 += lo16f(r0.x); a1 += hi16f(r0.x);
                a2 += lo16f(r0.y); a3 += hi16f(r0.y);
                a4 += lo16f(r0.z); a5 += hi16f(r0.z);
                a6 += lo16f(r0.w); a7 += hi16f(r0.w);
                a0 += lo16f(r1.x); a1 += hi16f(r1.x);
                a2 += lo16f(r1.y); a3 += hi16f(r1.y);
                a4 += lo16f(r1.z); a5 += hi16f(r1.z);
                a6 += lo16f(r1.w); a7 += hi16f(r1.w);
                a0 += lo16f(r2.x); a1 += hi16f(r2.x);
                a2 += lo16f(r2.y); a3 += hi16f(r2.y);
                a4 += lo16f(r2.z); a5 += hi16f(r2.z);
                a6 += lo16f(r2.w); a7 += hi16f(r2.w);
                a0 += lo16f(r3.x); a1 += hi16f(r3.x);
                a2 += lo16f(r3.y); a3 += hi16f(r3.y);
                a4 += lo16f(r3.z); a5 += hi16f(r3.z);
                a6 += lo16f(r3.w); a7 += hi16f(r3.w);
            }
        }

        float inv = d > 0 ? 1.f / (float)d : 0.f;
        uint4 o;
        o.x = (unsigned)f2bf(a0 * inv) | ((unsigned)f2bf(a1 * inv) << 16);
        o.y = (unsigned)f2bf(a2 * inv) | ((unsigned)f2bf(a3 * inv) << 16);
        o.z = (unsigned)f2bf(a4 * inv) | ((unsigned)f2bf(a5 * inv) << 16);
        o.w = (unsigned)f2bf(a6 * inv) | ((unsigned)f2bf(a7 * inv) << 16);
        *(uint4*)(meanS + n * 128 + ((qm ^ (n & 7)) * 8)) = o;
    }
    __syncthreads();

    // ---------------- phase A: h tile (8 waves: 4M x 2N) ----------------
    const int wr0 = (wave >> 1) * 16;   // rows 0/16/32/48
    const int wc0 = (wave & 1) * 128;   // cols 0/128
    f32x4 acch[8];
#pragma unroll
    for (int j = 0; j < 8; ++j) acch[j] = (f32x4){0.f, 0.f, 0.f, 0.f};

#pragma unroll
    for (int mat = 0; mat < 2; ++mat) {
        const u16* __restrict__ W = mat ? T1r : T1l;
        const u16* Al = mat ? xS : meanS;
#pragma unroll
        for (int k0 = 0; k0 < 128; k0 += 32) {
            // Bs: 256x32 (1024 chunks, 2/thread), source pre-swizzled (^row&3)
#pragma unroll
            for (int r = 0; r < 2; ++r) {
                int c = r * 512 + tid;
                int row = c >> 2, kc = c & 3;
                __builtin_amdgcn_global_load_lds(
                    (const __attribute__((address_space(1))) unsigned*)(
                        W + (size_t)row * 128 + k0 + ((kc ^ (row & 3)) * 8)),
                    (__attribute__((address_space(3))) unsigned*)(Bs + c * 8), 16, 0, 0);
            }
            __syncthreads();
            int ch0 = k0 >> 3;
            int rowA = wr0 + qm;
            bf16x8 af = *(const bf16x8*)(Al + rowA * 128 +
                                         (((ch0 + quad) ^ (rowA & 7)) * 8));
            bf16x8 bfv[8];
#pragma unroll
            for (int j = 0; j < 8; ++j) {
                int rB = wc0 + j * 16 + qm;
                bfv[j] = *(const bf16x8*)(Bs + rB * 32 + ((quad ^ (rB & 3)) * 8));
            }
#pragma unroll
            for (int j = 0; j < 8; ++j)
                acch[j] = __builtin_amdgcn_mfma_f32_16x16x32_bf16(af, bfv[j],
                                                                  acch[j], 0, 0, 0);
            __syncthreads();
        }
    }

    // epilogue A: +b1, relu, write to hfrag (aliases meanS/xS — dead now)
#pragma unroll
    for (int j = 0; j < 8; ++j) {
        int n = wc0 + j * 16 + qm;
        float bb = b1[n];
        int ks = n >> 5, quadB = (n >> 3) & 3, jB = n & 7;
#pragma unroll
        for (int r = 0; r < 4; ++r) {
            int mloc = wr0 + quad * 4 + r;
            float v = fmaxf(acch[j][r] + bb, 0.f);
            hfrag[((ks * 4 + (mloc >> 4)) * 16 + (mloc & 15)) * 32 + quadB * 8 + jB] =
                f2bf(v);
        }
    }
    __syncthreads();

    // ---------------- phase B: p2 / outp (8 waves: 4M x 2N) ----------------
    const int wrB = (wave >> 1) * 16;   // rows 0/16/32/48
    const int wcB = (wave & 1) * 64;    // cols 0/64 (of 128)
    f32x4 accp[4], acco[4];
#pragma unroll
    for (int j = 0; j < 4; ++j) {
        accp[j] = (f32x4){0.f, 0.f, 0.f, 0.f};
        acco[j] = (f32x4){0.f, 0.f, 0.f, 0.f};
    }

#pragma unroll
    for (int ks = 0; ks < 8; ++ks) {
        // stage W2l|W2r k-chunk: Bs[mat][128][32], 1024 chunks, 2/thread
#pragma unroll
        for (int r = 0; r < 2; ++r) {
            int c = r * 512 + tid;
            int matc = c >> 9;
            int row = (c >> 2) & 127;
            int kc = c & 3;
            const u16* W = matc ? T2r : T2l;
            __builtin_amdgcn_global_load_lds(
                (const __attribute__((address_space(1))) unsigned*)(
                    W + (size_t)row * 256 + ks * 32 + ((kc ^ (row & 3)) * 8)),
                (__attribute__((address_space(3))) unsigned*)(Bs + c * 8), 16, 0, 0);
        }
        __syncthreads();
        bf16x8 af = *(const bf16x8*)(hfrag +
                                     ((ks * 4 + (wrB >> 4)) * 16 + qm) * 32 + quad * 8);
        bf16x8 bfl[4], bfr[4];
#pragma unroll
        for (int j = 0; j < 4; ++j) {
            int rB = wcB + j * 16 + qm;
            bfl[j] = *(const bf16x8*)(Bs + rB * 32 + ((quad ^ (rB & 3)) * 8));
            bfr[j] = *(const bf16x8*)(Bs + 4096 + rB * 32 + ((quad ^ (rB & 3)) * 8));
        }
#pragma unroll
        for (int j = 0; j < 4; ++j) {
            accp[j] = __builtin_amdgcn_mfma_f32_16x16x32_bf16(af, bfl[j],
                                                              accp[j], 0, 0, 0);
            acco[j] = __builtin_amdgcn_mfma_f32_16x16x32_bf16(af, bfr[j],
                                                              acco[j], 0, 0, 0);
        }
        __syncthreads();
    }

    // epilogue B
#pragma unroll
    for (int j = 0; j < 4; ++j) {
        int n = wcB + j * 16 + qm;
        float bb2 = b2[n];
#pragma unroll
        for (int r = 0; r < 4; ++r) {
            int row = m0 + wrB + quad * 4 + r;
            if (row < M) {
                p2[(size_t)row * 128 + n] = f2bf(accp[j][r]);
                outp[(size_t)row * 128 + n] = f2bf(acco[j][r] + bb2);
            }
        }
    }
}

// ---------------------------------------------------------------------------
// Final aggregation: out = mean_{src->node} p2 + outp  (fp32). LDS-free.
// ---------------------------------------------------------------------------

__global__ __launch_bounds__(256, 8) void agg_final(const u16* __restrict__ tbl,
                                                    const int* __restrict__ deg,
                                                    const int* __restrict__ base,
                                                    const unsigned* __restrict__ esrc,
                                                    const u16* __restrict__ resid,
                                                    float* __restrict__ outv) {
    const int t = threadIdx.x;
    const int wave = t >> 6;
    const int lane = t & 63;
    const int qm = lane & 15;
    const int quad = lane >> 4;
    const int b = blockIdx.x;
    const int li8 = qm * 8;
    const int gbase = lane & 48;

    for (int pass = 0; pass < 4; ++pass) {
        int n = pass * 16 + wave * 4 + quad;   // 0..63
        int node = b * NPB + n;
        bool valid = node < N_NODES_C;
        int d = 0, s0 = 0;
        if (valid) { d = deg[node]; s0 = base[node]; }
        int dmax = max(d, __shfl_xor(d, 16, 64));
        dmax = max(dmax, __shfl_xor(dmax, 32, 64));

        float a0 = 0.f, a1 = 0.f, a2 = 0.f, a3 = 0.f;
        float a4 = 0.f, a5 = 0.f, a6 = 0.f, a7 = 0.f;

        for (int j = 0; j < dmax; j += 16) {
            int jj = j + qm;
            unsigned sidx = (jj < d) ? esrc[s0 + jj] : (unsigned)SENT_ROW;
            for (int u = 0; u < 16 && j + u < dmax; u += 4) {
                unsigned i0 = __shfl(sidx, gbase + u, 64);
                unsigned i1 = __shfl(sidx, gbase + u + 1, 64);
                unsigned i2 = __shfl(sidx, gbase + u + 2, 64);
                unsigned i3 = __shfl(sidx, gbase + u + 3, 64);
                uint4 r0 = *(const uint4*)(tbl + (size_t)i0 * 128 + li8);
                uint4 r1 = *(const uint4*)(tbl + (size_t)i1 * 128 + li8);
                uint4 r2 = *(const uint4*)(tbl + (size_t)i2 * 128 + li8);
                uint4 r3 = *(const uint4*)(tbl + (size_t)i3 * 128 + li8);
                a0 += lo16f(r0.x); a1 += hi16f(r0.x);
                a2 += lo16f(r0.y); a3 += hi16f(r0.y);
                a4 += lo16f(r0.z); a5 += hi16f(r0.z);
                a6 += lo16f(r0.w); a7 += hi16f(r0.w);
                a0 += lo16f(r1.x); a1 += hi16f(r1.x);
                a2 += lo16f(r1.y); a3 += hi16f(r1.y);
                a4 += lo16f(r1.z); a5 += hi16f(r1.z);
                a6 += lo16f(r1.w); a7 += hi16f(r1.w);
                a0 += lo16f(r2.x); a1 += hi16f(r2.x);
                a2 += lo16f(r2.y); a3 += hi16f(r2.y);
                a4 += lo16f(r2.z); a5 += hi16f(r2.z);
                a6 += lo16f(r2.w); a7 += hi16f(r2.w);
                a0 += lo16f(r3.x); a1 += hi16f(r3.x);
                a2 += lo16f(r3.y); a3 += hi16f(r3.y);
                a4 += lo16f(r3.z); a5 += hi16f(r3.z);
                a6 += lo16f(r3.w); a7 += hi16f(r3.w);
            }
        }

        if (valid) {
            float inv = d > 0 ? 1.f / (float)d : 0.f;
            uint4 rp = *(const uint4*)(resid + (size_t)node * 128 + li8);
            float* op = outv + (size_t)node * 128 + li8;
            float4 o0, o1;
            o0.x = a0 * inv + lo16f(rp.x);
            o0.y = a1 * inv + hi16f(rp.x);
            o0.z = a2 * inv + lo16f(rp.y);
            o0.w = a3 * inv + hi16f(rp.y);
            o1.x = a4 * inv + lo16f(rp.z);
            o1.y = a5 * inv + hi16f(rp.z);
            o1.z = a6 * inv + lo16f(rp.w);
            o1.w = a7 * inv + hi16f(rp.w);
            *(float4*)op = o0;
            *(float4*)(op + 4) = o1;
        }
    }
}

// ---------------------------------------------------------------------------
// launch
// ---------------------------------------------------------------------------

extern "C" void kernel_launch(void* const* d_in, const int* in_sizes, int n_in,
                              void* d_out, int out_size, void* d_ws, size_t ws_size,
                              hipStream_t stream) {
    const float* x = (const float*)d_in[0];
    const int* ei = (const int*)d_in[1];
    const float* W1l = (const float*)d_in[2];
    const float* b1 = (const float*)d_in[3];
    const float* W1r = (const float*)d_in[4];
    const float* W2l = (const float*)d_in[5];
    const float* b2 = (const float*)d_in[6];
    const float* W2r = (const float*)d_in[7];
    float* out = (float*)d_out;

    const int* src = ei;
    const int* dst = ei + N_EDGES_C;

    // int workspace region (first 16 MiB)
    int* iw = (int*)d_ws;
    int* chist = iw;                              // 256 (196 used)
    int* cbase = iw + 256;                        // 256
    int* ccursor = iw + 512;                      // 256
    int* deg = iw + 768;                          // 100000
    int* base = iw + 100768;                      // 100000
    unsigned* epkt2 = (unsigned*)(iw + 200768);   // 1600000
    unsigned* esrc = (unsigned*)(iw + 1800768);   // 1600000 -> ends 3400768
    u16* T1l = (u16*)(iw + 3400832);              // 4 x 32768 u16 = 256 KB
    u16* T1r = T1l + 32768;
    u16* T2l = T1r + 32768;
    u16* T2r = T2l + 32768;                       // ends ~13.9 MB < 16 MiB
    // bf16 region at byte offset 16 MiB; stride 12.85M u16 (sentinel row pad)
    u16* ub = (u16*)((char*)d_ws + (16u << 20));
    u16* x_bf = ub;                               // [100001][128]
    u16* p2 = ub + 12850000;                      // [100001][128]
    u16* outp = ub + 25700000;                    // [100000][128]

    hipMemsetAsync(chist, 0, 1024, stream);

    // hist | weight transpose | sentinel zero
    prep_a<<<K2_BLOCKS + 128 + 1, 1024, 0, stream>>>(
        dst, W1l, W1r, W2l, W2r, T1l, T1r, T2l, T2r, chist, x_bf, p2);
    cscan<<<1, 256, 0, stream>>>(chist, cbase, ccursor);
    // coarse scatter || x conversion part 1
    scatter_conv<<<K2_BLOCKS + CONV1_BLOCKS, 1024, 0, stream>>>(
        src, dst, ccursor, epkt2, x, x_bf);
    // fine sort || x conversion part 2
    sort_conv<<<K2_BLOCKS + CONV2_BLOCKS, 1024, 0, stream>>>(
        cbase, chist, epkt2, esrc, deg, base, x, x_bf);

    // per bucket: gather-mean + GEMM L1 + GEMM L2 -> p2, outp
    fused_gemm_agg<<<NB, 512, 0, stream>>>(x_bf, deg, base, esrc, T1l, T1r, T2l,
                                           T2r, b1, b2, p2, outp, N_NODES_C);
    // out = mean_{src->node} p2 + outp   (fp32)
    agg_final<<<NB, 256, 0, stream>>>(p2, deg, base, esrc, outp, out);
}

// Round 10
// 336.539 us; speedup vs baseline: 1.7591x; 1.0023x over previous
//
#include <hip/hip_runtime.h>
#include <cstddef>

#define N_NODES_C 100000
#define N_EDGES_C 1600000

#define NPB 64               // nodes per block tile (= GEMM M-tile)
#define NB 1563              // ceil(100000/64)
#define SENT_ROW 100000      // zeroed sentinel row in feature tables

#define NCB 196              // coarse buckets of 512 nodes: ceil(100000/512)
#define K2_EPB 8192          // edges per coarse-scatter block
#define K2_BLOCKS 196        // ceil(1600000/8192)

#define CONV1_BLOCKS 1563    // conv float4 blocks in scatter_conv (1024/blk)
#define CONV2_BLOCKS 1562    // conv float4 blocks in sort_conv

typedef unsigned short u16;
typedef __attribute__((ext_vector_type(8))) short bf16x8;
typedef __attribute__((ext_vector_type(4))) float f32x4;

__device__ __forceinline__ u16 f2bf(float f) {
    unsigned u = __float_as_uint(f);
    u += 0x7fffu + ((u >> 16) & 1);  // round-to-nearest-even
    return (u16)(u >> 16);
}
__device__ __forceinline__ float lo16f(unsigned v) {
    return __uint_as_float(v << 16);
}
__device__ __forceinline__ float hi16f(unsigned v) {
    return __uint_as_float(v & 0xffff0000u);
}

__device__ __forceinline__ void conv_chunk(const float* __restrict__ x,
                                           u16* __restrict__ x_bf, int i) {
    float4 v = ((const float4*)x)[i];
    ushort4 o;
    o.x = f2bf(v.x); o.y = f2bf(v.y); o.z = f2bf(v.z); o.w = f2bf(v.w);
    ((ushort4*)x_bf)[i] = o;
}

// ---------------------------------------------------------------------------
// prep_a: coarse hist (196 blocks) | weight transpose (128 blocks) |
// sentinel zeroing (1 block). 1024 threads.
// ---------------------------------------------------------------------------

__global__ __launch_bounds__(1024) void prep_a(
    const int* __restrict__ dst,
    const float* __restrict__ W1l, const float* __restrict__ W1r,
    const float* __restrict__ W2l, const float* __restrict__ W2r,
    u16* __restrict__ T1l, u16* __restrict__ T1r,
    u16* __restrict__ T2l, u16* __restrict__ T2r,
    int* __restrict__ chist, u16* __restrict__ x_bf, u16* __restrict__ p2z) {
    const int b = blockIdx.x;
    const int t = threadIdx.x;
    if (b < K2_BLOCKS) {
        __shared__ int hist[NCB];
        if (t < NCB) hist[t] = 0;
        __syncthreads();
        const int e0 = b * K2_EPB;
#pragma unroll
        for (int r = 0; r < 2; ++r) {
            int i = (e0 >> 2) + r * 1024 + t;  // int4 index
            if (i * 4 < N_EDGES_C) {
                int4 d = ((const int4*)dst)[i];
                atomicAdd(&hist[d.x >> 9], 1);
                atomicAdd(&hist[d.y >> 9], 1);
                atomicAdd(&hist[d.z >> 9], 1);
                atomicAdd(&hist[d.w >> 9], 1);
            }
        }
        __syncthreads();
        if (t < NCB) {
            int c = hist[t];
            if (c) atomicAdd(&chist[t], c);
        }
    } else if (b < K2_BLOCKS + 128) {
        int id = (b - K2_BLOCKS) * 1024 + t;  // 0..131071
        int which = id >> 15;
        int r = id & 32767;
        if (which == 0) {        // [128][256] -> [256][128]
            int n = r >> 7, k = r & 127;
            T1l[r] = f2bf(W1l[k * 256 + n]);
        } else if (which == 1) {
            int n = r >> 7, k = r & 127;
            T1r[r] = f2bf(W1r[k * 256 + n]);
        } else if (which == 2) {  // [256][128] -> [128][256]
            int n = r >> 8, k = r & 255;
            T2l[r] = f2bf(W2l[k * 128 + n]);
        } else {
            int n = r >> 8, k = r & 255;
            T2r[r] = f2bf(W2r[k * 128 + n]);
        }
    } else {
        uint4 z; z.x = 0; z.y = 0; z.z = 0; z.w = 0;
        if (t < 16)
            ((uint4*)(x_bf + (size_t)SENT_ROW * 128))[t] = z;
        else if (t < 32)
            ((uint4*)(p2z + (size_t)SENT_ROW * 128))[t - 16] = z;
    }
}

// ---------------------------------------------------------------------------
// Coarse scan: exclusive scan of the 196 coarse-bucket counts.
// ---------------------------------------------------------------------------

__global__ __launch_bounds__(256) void cscan(const int* __restrict__ chist,
                                             int* __restrict__ cbase,
                                             int* __restrict__ ccursor) {
    __shared__ int s[256];
    int t = threadIdx.x;
    int v = (t < NCB) ? chist[t] : 0;
    s[t] = v;
    __syncthreads();
    for (int off = 1; off < 256; off <<= 1) {
        int u = (t >= off) ? s[t - off] : 0;
        __syncthreads();
        s[t] += u;
        __syncthreads();
    }
    if (t < NCB) {
        int e = s[t] - v;
        cbase[t] = e;
        ccursor[t] = e;
    }
}

// ---------------------------------------------------------------------------
// scatter_conv: coarse scatter (196 blocks) | x conversion part 1 (1563).
// packed = (local9 << 17) | src17
// ---------------------------------------------------------------------------

__global__ __launch_bounds__(1024) void scatter_conv(
    const int* __restrict__ src, const int* __restrict__ dst,
    int* __restrict__ ccursor, unsigned* __restrict__ epkt2,
    const float* __restrict__ x, u16* __restrict__ x_bf) {
    __shared__ unsigned spkt[K2_EPB];
    __shared__ unsigned char scb[K2_EPB];
    __shared__ int hist[NCB], lstart[NCB], lcur[NCB], grun[NCB], stmp[NCB];

    const int t = threadIdx.x;
    const int b = blockIdx.x;
    if (b >= K2_BLOCKS) {
        conv_chunk(x, x_bf, (b - K2_BLOCKS) * 1024 + t);  // i < 1600512
        return;
    }
    const int e0 = b * K2_EPB;
    const int cnt = min(K2_EPB, N_EDGES_C - e0);

    if (t < NCB) hist[t] = 0;
    __syncthreads();

    int4 dd[2], ss[2];
    int vi[2];
#pragma unroll
    for (int r = 0; r < 2; ++r) {
        int i = (e0 >> 2) + r * 1024 + t;  // int4 index
        vi[r] = (i * 4 < N_EDGES_C);
        if (vi[r]) {
            dd[r] = ((const int4*)dst)[i];
            ss[r] = ((const int4*)src)[i];
            atomicAdd(&hist[dd[r].x >> 9], 1);
            atomicAdd(&hist[dd[r].y >> 9], 1);
            atomicAdd(&hist[dd[r].z >> 9], 1);
            atomicAdd(&hist[dd[r].w >> 9], 1);
        }
    }
    __syncthreads();

    if (t < NCB) stmp[t] = hist[t];
    __syncthreads();
    for (int off = 1; off < NCB; off <<= 1) {
        int v = 0;
        if (t < NCB && t >= off) v = stmp[t - off];
        __syncthreads();
        if (t < NCB) stmp[t] += v;
        __syncthreads();
    }
    if (t < NCB) {
        int excl = stmp[t] - hist[t];
        lstart[t] = excl;
        lcur[t] = excl;
        if (hist[t]) grun[t] = atomicAdd(&ccursor[t], hist[t]);
    }
    __syncthreads();

#pragma unroll
    for (int r = 0; r < 2; ++r) {
        if (vi[r]) {
            int4 d = dd[r];
            int4 s4 = ss[r];
            {
                int cb = d.x >> 9;
                int pos = atomicAdd(&lcur[cb], 1);
                spkt[pos] = ((unsigned)(d.x & 511) << 17) | (unsigned)s4.x;
                scb[pos] = (unsigned char)cb;
            }
            {
                int cb = d.y >> 9;
                int pos = atomicAdd(&lcur[cb], 1);
                spkt[pos] = ((unsigned)(d.y & 511) << 17) | (unsigned)s4.y;
                scb[pos] = (unsigned char)cb;
            }
            {
                int cb = d.z >> 9;
                int pos = atomicAdd(&lcur[cb], 1);
                spkt[pos] = ((unsigned)(d.z & 511) << 17) | (unsigned)s4.z;
                scb[pos] = (unsigned char)cb;
            }
            {
                int cb = d.w >> 9;
                int pos = atomicAdd(&lcur[cb], 1);
                spkt[pos] = ((unsigned)(d.w & 511) << 17) | (unsigned)s4.w;
                scb[pos] = (unsigned char)cb;
            }
        }
    }
    __syncthreads();

#pragma unroll
    for (int k = 0; k < K2_EPB / 1024; ++k) {
        int i = k * 1024 + t;
        if (i < cnt) {
            int cb = scb[i];
            epkt2[grun[cb] + (i - lstart[cb])] = spkt[i];
        }
    }
}

// ---------------------------------------------------------------------------
// sort_conv: fine sort (196 blocks) | x conversion part 2 (1562 blocks).
// ---------------------------------------------------------------------------

__global__ __launch_bounds__(1024) void sort_conv(
    const int* __restrict__ cbase, const int* __restrict__ chist,
    const unsigned* __restrict__ epkt2, unsigned* __restrict__ esrc,
    int* __restrict__ deg, int* __restrict__ base,
    const float* __restrict__ x, u16* __restrict__ x_bf) {
    __shared__ int hist[512], lstart[512], lcur[512], stmp[512];
    const int t = threadIdx.x;
    const int c = blockIdx.x;
    if (c >= K2_BLOCKS) {
        conv_chunk(x, x_bf, 1600512 + (c - K2_BLOCKS) * 1024 + t);  // <3.2M
        return;
    }
    const int s0 = cbase[c];
    const int cnt = chist[c];

    if (t < 512) hist[t] = 0;
    __syncthreads();

    for (int i = t; i < cnt; i += 1024)
        atomicAdd(&hist[epkt2[s0 + i] >> 17], 1);
    __syncthreads();

    if (t < 512) stmp[t] = hist[t];
    __syncthreads();
    for (int off = 1; off < 512; off <<= 1) {
        int v = 0;
        if (t < 512 && t >= off) v = stmp[t - off];
        __syncthreads();
        if (t < 512) stmp[t] += v;
        __syncthreads();
    }
    if (t < 512) {
        int excl = stmp[t] - hist[t];
        lstart[t] = excl;
        lcur[t] = excl;
        int node = c * 512 + t;
        if (node < N_NODES_C) {
            deg[node] = hist[t];
            base[node] = s0 + excl;
        }
    }
    __syncthreads();

    for (int i = t; i < cnt; i += 1024) {
        unsigned p = epkt2[s0 + i];
        int pos = atomicAdd(&lcur[p >> 17], 1);
        esrc[s0 + pos] = p & 0x1ffffu;
    }
}

// ---------------------------------------------------------------------------
// Fused per-bucket kernel (512 thr = 8 waves, 4 blocks/CU = 32 waves/CU):
//   gather -> meanS; phase A -> hfrag; phase B -> p2/outp.
// Bs shrunk to 8KB (half-tile staged sequentially) => LDS 40KB => 4 blk/CU.
// (512,8) caps VGPR at 64 — kernel uses ~40 (round-7 measured), no spill.
// ---------------------------------------------------------------------------

__global__ __launch_bounds__(512, 8) void fused_gemm_agg(
    const u16* __restrict__ x_bf, const int* __restrict__ deg,
    const int* __restrict__ base, const unsigned* __restrict__ esrc,
    const u16* __restrict__ T1l, const u16* __restrict__ T1r,   // [256][128]
    const u16* __restrict__ T2l, const u16* __restrict__ T2r,   // [128][256]
    const float* __restrict__ b1, const float* __restrict__ b2,
    u16* __restrict__ p2, u16* __restrict__ outp, int M) {
    alignas(16) __shared__ u16 uni[64 * 256];  // 32KB: [meanS|xS] then hfrag
    alignas(16) __shared__ u16 Bs[4096];       // 8KB weight staging (half-tile)

    u16* const meanS = uni;           // [64][128], 16B-chunk ^ (row&7)
    u16* const xS = uni + 64 * 128;   // [64][128], same swizzle
    u16* const hfrag = uni;           // phase-B alias (32KB)

    const int tid = threadIdx.x;
    const int lane = tid & 63;
    const int wave = tid >> 6;
    const int qm = lane & 15;
    const int quad = lane >> 4;
    const int b = blockIdx.x;
    const int m0 = b * 64;

    // ---- issue xS staging early (lands during gather) ----
#pragma unroll
    for (int r = 0; r < 2; ++r) {
        int c = r * 512 + tid;          // 1024 chunks of 16B
        int row = c >> 4, q16 = c & 15;
        __builtin_amdgcn_global_load_lds(
            (const __attribute__((address_space(1))) unsigned*)(
                x_bf + (size_t)(m0 + row) * 128 + ((q16 ^ (row & 7)) * 8)),
            (__attribute__((address_space(3))) unsigned*)(xS + c * 8), 16, 0, 0);
    }

    // ---- gather + mean -> meanS (bf16, swizzled) ----
    const int li8 = qm * 8;
    const int gbase = lane & 48;  // group base lane within wave

    for (int pass = 0; pass < 2; ++pass) {
        int n = pass * 32 + wave * 4 + quad;   // 0..63
        int node = m0 + n;
        int d = 0, s0 = 0;
        if (node < N_NODES_C) { d = deg[node]; s0 = base[node]; }
        int dmax = max(d, __shfl_xor(d, 16, 64));
        dmax = max(dmax, __shfl_xor(dmax, 32, 64));

        float a0 = 0.f, a1 = 0.f, a2 = 0.f, a3 = 0.f;
        float a4 = 0.f, a5 = 0.f, a6 = 0.f, a7 = 0.f;

        for (int j = 0; j < dmax; j += 16) {
            int jj = j + qm;
            unsigned sidx = (jj < d) ? esrc[s0 + jj] : (unsigned)SENT_ROW;
            for (int u = 0; u < 16 && j + u < dmax; u += 4) {
                unsigned i0 = __shfl(sidx, gbase + u, 64);
                unsigned i1 = __shfl(sidx, gbase + u + 1, 64);
                unsigned i2 = __shfl(sidx, gbase + u + 2, 64);
                unsigned i3 = __shfl(sidx, gbase + u + 3, 64);
                uint4 r0 = *(const uint4*)(x_bf + (size_t)i0 * 128 + li8);
                uint4 r1 = *(const uint4*)(x_bf + (size_t)i1 * 128 + li8);
                uint4 r2 = *(const uint4*)(x_bf + (size_t)i2 * 128 + li8);
                uint4 r3 = *(const uint4*)(x_bf + (size_t)i3 * 128 + li8);
                a0 += lo16f(r0.x); a1 += hi16f(r0.x);
                a2 += lo16f(r0.y); a3 += hi16f(r0.y);
                a4 += lo16f(r0.z); a5 += hi16f(r0.z);
                a6 += lo16f(r0.w); a7 += hi16f(r0.w);
                a0 += lo16f(r1.x); a1 += hi16f(r1.x);
                a2 += lo16f(r1.y); a3 += hi16f(r1.y);
                a4 += lo16f(r1.z); a5 += hi16f(r1.z);
                a6 += lo16f(r1.w); a7 += hi16f(r1.w);
                a0 += lo16f(r2.x); a1 += hi16f(r2.x);
                a2 += lo16f(r2.y); a3 += hi16f(r2.y);
                a4 += lo16f(r2.z); a5 += hi16f(r2.z);
                a6 += lo16f(r2.w); a7 += hi16f(r2.w);
                a0 += lo16f(r3.x); a1 += hi16f(r3.x);
                a2 += lo16f(r3.y); a3 += hi16f(r3.y);
                a4 += lo16f(r3.z); a5 += hi16f(r3.z);
                a6 += lo16f(r3.w); a7 += hi16f(r3.w);
            }
        }

        float inv = d > 0 ? 1.f / (float)d : 0.f;
        uint4 o;
        o.x = (unsigned)f2bf(a0 * inv) | ((unsigned)f2bf(a1 * inv) << 16);
        o.y = (unsigned)f2bf(a2 * inv) | ((unsigned)f2bf(a3 * inv) << 16);
        o.z = (unsigned)f2bf(a4 * inv) | ((unsigned)f2bf(a5 * inv) << 16);
        o.w = (unsigned)f2bf(a6 * inv) | ((unsigned)f2bf(a7 * inv) << 16);
        *(uint4*)(meanS + n * 128 + ((qm ^ (n & 7)) * 8)) = o;
    }
    __syncthreads();

    // ------- phase A: h tile (8 waves: 4M x 2N-of-64, two 128-col halves) ----
    const int wr0 = (wave >> 1) * 16;   // rows 0/16/32/48
    const int wcA = (wave & 1) * 64;    // col offset within 128-half
    f32x4 acch[8];                      // [h*4 + j]
#pragma unroll
    for (int j = 0; j < 8; ++j) acch[j] = (f32x4){0.f, 0.f, 0.f, 0.f};

#pragma unroll
    for (int mat = 0; mat < 2; ++mat) {
        const u16* __restrict__ W = mat ? T1r : T1l;
        const u16* Al = mat ? xS : meanS;
#pragma unroll
        for (int k0 = 0; k0 < 128; k0 += 32) {
            int ch0 = k0 >> 3;
            int rowA = wr0 + qm;
            bf16x8 af = *(const bf16x8*)(Al + rowA * 128 +
                                         (((ch0 + quad) ^ (rowA & 7)) * 8));
#pragma unroll
            for (int h = 0; h < 2; ++h) {
                // stage half: Bs[128][32] (512 chunks, 1/thread), pre-swizzled
                {
                    int c = tid;
                    int row = c >> 2, kc = c & 3;
                    __builtin_amdgcn_global_load_lds(
                        (const __attribute__((address_space(1))) unsigned*)(
                            W + (size_t)(h * 128 + row) * 128 + k0 +
                            ((kc ^ (row & 3)) * 8)),
                        (__attribute__((address_space(3))) unsigned*)(Bs + c * 8),
                        16, 0, 0);
                }
                __syncthreads();
#pragma unroll
                for (int j = 0; j < 4; ++j) {
                    int rB = wcA + j * 16 + qm;  // local row in half
                    bf16x8 bv = *(const bf16x8*)(Bs + rB * 32 +
                                                 ((quad ^ (rB & 3)) * 8));
                    acch[h * 4 + j] = __builtin_amdgcn_mfma_f32_16x16x32_bf16(
                        af, bv, acch[h * 4 + j], 0, 0, 0);
                }
                __syncthreads();
            }
        }
    }

    // epilogue A: +b1, relu, write to hfrag (aliases meanS/xS — dead now)
#pragma unroll
    for (int h = 0; h < 2; ++h) {
#pragma unroll
        for (int j = 0; j < 4; ++j) {
            int n = h * 128 + wcA + j * 16 + qm;
            float bb = b1[n];
            int ks = n >> 5, quadB = (n >> 3) & 3, jB = n & 7;
#pragma unroll
            for (int r = 0; r < 4; ++r) {
                int mloc = wr0 + quad * 4 + r;
                float v = fmaxf(acch[h * 4 + j][r] + bb, 0.f);
                hfrag[((ks * 4 + (mloc >> 4)) * 16 + (mloc & 15)) * 32 +
                      quadB * 8 + jB] = f2bf(v);
            }
        }
    }
    __syncthreads();

    // ------- phase B: p2 / outp (8 waves: 4M x 2N; W2l then W2r) ----------
    const int wrB = (wave >> 1) * 16;   // rows 0/16/32/48
    const int wcB = (wave & 1) * 64;    // cols 0/64 (of 128)
    f32x4 accp[4], acco[4];
#pragma unroll
    for (int j = 0; j < 4; ++j) {
        accp[j] = (f32x4){0.f, 0.f, 0.f, 0.f};
        acco[j] = (f32x4){0.f, 0.f, 0.f, 0.f};
    }

#pragma unroll
    for (int ks = 0; ks < 8; ++ks) {
        bf16x8 af = *(const bf16x8*)(hfrag +
                                     ((ks * 4 + (wrB >> 4)) * 16 + qm) * 32 + quad * 8);
#pragma unroll
        for (int half = 0; half < 2; ++half) {
            const u16* W = half ? T2r : T2l;
            {
                int c = tid;
                int row = c >> 2, kc = c & 3;
                __builtin_amdgcn_global_load_lds(
                    (const __attribute__((address_space(1))) unsigned*)(
                        W + (size_t)row * 256 + ks * 32 + ((kc ^ (row & 3)) * 8)),
                    (__attribute__((address_space(3))) unsigned*)(Bs + c * 8),
                    16, 0, 0);
            }
            __syncthreads();
            f32x4* acc = half ? acco : accp;
#pragma unroll
            for (int j = 0; j < 4; ++j) {
                int rB = wcB + j * 16 + qm;
                bf16x8 bv = *(const bf16x8*)(Bs + rB * 32 +
                                             ((quad ^ (rB & 3)) * 8));
                acc[j] = __builtin_amdgcn_mfma_f32_16x16x32_bf16(af, bv,
                                                                 acc[j], 0, 0, 0);
            }
            __syncthreads();
        }
    }

    // epilogue B
#pragma unroll
    for (int j = 0; j < 4; ++j) {
        int n = wcB + j * 16 + qm;
        float bb2 = b2[n];
#pragma unroll
        for (int r = 0; r < 4; ++r) {
            int row = m0 + wrB + quad * 4 + r;
            if (row < M) {
                p2[(size_t)row * 128 + n] = f2bf(accp[j][r]);
                outp[(size_t)row * 128 + n] = f2bf(acco[j][r] + bb2);
            }
        }
    }
}

// ---------------------------------------------------------------------------
// Final aggregation: out = mean_{src->node} p2 + outp  (fp32). LDS-free.
// ---------------------------------------------------------------------------

__global__ __launch_bounds__(256, 8) void agg_final(const u16* __restrict__ tbl,
                                                    const int* __restrict__ deg,
                                                    const int* __restrict__ base,
                                                    const unsigned* __restrict__ esrc,
                                                    const u16* __restrict__ resid,
                                                    float* __restrict__ outv) {
    const int t = threadIdx.x;
    const int wave = t >> 6;
    const int lane = t & 63;
    const int qm = lane & 15;
    const int quad = lane >> 4;
    const int b = blockIdx.x;
    const int li8 = qm * 8;
    const int gbase = lane & 48;

    for (int pass = 0; pass < 4; ++pass) {
        int n = pass * 16 + wave * 4 + quad;   // 0..63
        int node = b * NPB + n;
        bool valid = node < N_NODES_C;
        int d = 0, s0 = 0;
        if (valid) { d = deg[node]; s0 = base[node]; }
        int dmax = max(d, __shfl_xor(d, 16, 64));
        dmax = max(dmax, __shfl_xor(dmax, 32, 64));

        float a0 = 0.f, a1 = 0.f, a2 = 0.f, a3 = 0.f;
        float a4 = 0.f, a5 = 0.f, a6 = 0.f, a7 = 0.f;

        for (int j = 0; j < dmax; j += 16) {
            int jj = j + qm;
            unsigned sidx = (jj < d) ? esrc[s0 + jj] : (unsigned)SENT_ROW;
            for (int u = 0; u < 16 && j + u < dmax; u += 4) {
                unsigned i0 = __shfl(sidx, gbase + u, 64);
                unsigned i1 = __shfl(sidx, gbase + u + 1, 64);
                unsigned i2 = __shfl(sidx, gbase + u + 2, 64);
                unsigned i3 = __shfl(sidx, gbase + u + 3, 64);
                uint4 r0 = *(const uint4*)(tbl + (size_t)i0 * 128 + li8);
                uint4 r1 = *(const uint4*)(tbl + (size_t)i1 * 128 + li8);
                uint4 r2 = *(const uint4*)(tbl + (size_t)i2 * 128 + li8);
                uint4 r3 = *(const uint4*)(tbl + (size_t)i3 * 128 + li8);
                a0 += lo16f(r0.x); a1 += hi16f(r0.x);
                a2 += lo16f(r0.y); a3 += hi16f(r0.y);
                a4 += lo16f(r0.z); a5 += hi16f(r0.z);
                a6 += lo16f(r0.w); a7 += hi16f(r0.w);
                a0 += lo16f(r1.x); a1 += hi16f(r1.x);
                a2 += lo16f(r1.y); a3 += hi16f(r1.y);
                a4 += lo16f(r1.z); a5 += hi16f(r1.z);
                a6 += lo16f(r1.w); a7 += hi16f(r1.w);
                a0 += lo16f(r2.x); a1 += hi16f(r2.x);
                a2 += lo16f(r2.y); a3 += hi16f(r2.y);
                a4 += lo16f(r2.z); a5 += hi16f(r2.z);
                a6 += lo16f(r2.w); a7 += hi16f(r2.w);
                a0 += lo16f(r3.x); a1 += hi16f(r3.x);
                a2 += lo16f(r3.y); a3 += hi16f(r3.y);
                a4 += lo16f(r3.z); a5 += hi16f(r3.z);
                a6 += lo16f(r3.w); a7 += hi16f(r3.w);
            }
        }

        if (valid) {
            float inv = d > 0 ? 1.f / (float)d : 0.f;
            uint4 rp = *(const uint4*)(resid + (size_t)node * 128 + li8);
            float* op = outv + (size_t)node * 128 + li8;
            float4 o0, o1;
            o0.x = a0 * inv + lo16f(rp.x);
            o0.y = a1 * inv + hi16f(rp.x);
            o0.z = a2 * inv + lo16f(rp.y);
            o0.w = a3 * inv + hi16f(rp.y);
            o1.x = a4 * inv + lo16f(rp.z);
            o1.y = a5 * inv + hi16f(rp.z);
            o1.z = a6 * inv + lo16f(rp.w);
            o1.w = a7 * inv + hi16f(rp.w);
            *(float4*)op = o0;
            *(float4*)(op + 4) = o1;
        }
    }
}

// ---------------------------------------------------------------------------
// launch
// ---------------------------------------------------------------------------

extern "C" void kernel_launch(void* const* d_in, const int* in_sizes, int n_in,
                              void* d_out, int out_size, void* d_ws, size_t ws_size,
                              hipStream_t stream) {
    const float* x = (const float*)d_in[0];
    const int* ei = (const int*)d_in[1];
    const float* W1l = (const float*)d_in[2];
    const float* b1 = (const float*)d_in[3];
    const float* W1r = (const float*)d_in[4];
    const float* W2l = (const float*)d_in[5];
    const float* b2 = (const float*)d_in[6];
    const float* W2r = (const float*)d_in[7];
    float* out = (float*)d_out;

    const int* src = ei;
    const int* dst = ei + N_EDGES_C;

    // int workspace region (first 16 MiB)
    int* iw = (int*)d_ws;
    int* chist = iw;                              // 256 (196 used)
    int* cbase = iw + 256;                        // 256
    int* ccursor = iw + 512;                      // 256
    int* deg = iw + 768;                          // 100000
    int* base = iw + 100768;                      // 100000
    unsigned* epkt2 = (unsigned*)(iw + 200768);   // 1600000
    unsigned* esrc = (unsigned*)(iw + 1800768);   // 1600000 -> ends 3400768
    u16* T1l = (u16*)(iw + 3400832);              // 4 x 32768 u16 = 256 KB
    u16* T1r = T1l + 32768;
    u16* T2l = T1r + 32768;
    u16* T2r = T2l + 32768;                       // ends ~13.9 MB < 16 MiB
    // bf16 region at byte offset 16 MiB; stride 12.85M u16 (sentinel row pad)
    u16* ub = (u16*)((char*)d_ws + (16u << 20));
    u16* x_bf = ub;                               // [100001][128]
    u16* p2 = ub + 12850000;                      // [100001][128]
    u16* outp = ub + 25700000;                    // [100000][128]

    hipMemsetAsync(chist, 0, 1024, stream);

    // hist | weight transpose | sentinel zero
    prep_a<<<K2_BLOCKS + 128 + 1, 1024, 0, stream>>>(
        dst, W1l, W1r, W2l, W2r, T1l, T1r, T2l, T2r, chist, x_bf, p2);
    cscan<<<1, 256, 0, stream>>>(chist, cbase, ccursor);
    // coarse scatter || x conversion part 1
    scatter_conv<<<K2_BLOCKS + CONV1_BLOCKS, 1024, 0, stream>>>(
        src, dst, ccursor, epkt2, x, x_bf);
    // fine sort || x conversion part 2
    sort_conv<<<K2_BLOCKS + CONV2_BLOCKS, 1024, 0, stream>>>(
        cbase, chist, epkt2, esrc, deg, base, x, x_bf);

    // per bucket: gather-mean + GEMM L1 + GEMM L2 -> p2, outp
    fused_gemm_agg<<<NB, 512, 0, stream>>>(x_bf, deg, base, esrc, T1l, T1r, T2l,
                                           T2r, b1, b2, p2, outp, N_NODES_C);
    // out = mean_{src->node} p2 + outp   (fp32)
    agg_final<<<NB, 256, 0, stream>>>(p2, deg, base, esrc, outp, out);
}

// Round 11
// 330.987 us; speedup vs baseline: 1.7886x; 1.0168x over previous
//
#include <hip/hip_runtime.h>
#include <cstddef>

#define N_NODES_C 100000
#define N_EDGES_C 1600000

#define NPB 64               // nodes per block tile (= GEMM M-tile)
#define NB 1563              // ceil(100000/64)
#define SENT_ROW 100000      // zeroed sentinel row in feature tables

#define NCB 392              // coarse buckets of 256 nodes: ceil(100000/256)
#define CAP 5120             // fixed slab per coarse bucket (mean 4096, +16 sigma)
#define SC_EPB 4096          // edges per scatter block
#define SC_BLOCKS 391        // ceil(1600000/4096)

#define CONV1_BLOCKS 1563    // conv float4 blocks in scatter_conv (1024/blk)
#define CONV2_BLOCKS 1562    // conv float4 blocks in sort_conv

typedef unsigned short u16;
typedef __attribute__((ext_vector_type(8))) short bf16x8;
typedef __attribute__((ext_vector_type(4))) float f32x4;

__device__ __forceinline__ u16 f2bf(float f) {
    unsigned u = __float_as_uint(f);
    u += 0x7fffu + ((u >> 16) & 1);  // round-to-nearest-even
    return (u16)(u >> 16);
}
__device__ __forceinline__ float lo16f(unsigned v) {
    return __uint_as_float(v << 16);
}
__device__ __forceinline__ float hi16f(unsigned v) {
    return __uint_as_float(v & 0xffff0000u);
}

__device__ __forceinline__ void conv_chunk(const float* __restrict__ x,
                                           u16* __restrict__ x_bf, int i) {
    float4 v = ((const float4*)x)[i];
    ushort4 o;
    o.x = f2bf(v.x); o.y = f2bf(v.y); o.z = f2bf(v.z); o.w = f2bf(v.w);
    ((ushort4*)x_bf)[i] = o;
}

// ---------------------------------------------------------------------------
// prep_a: weight transpose (128 blocks) | sentinel zero + ccursor zero (1).
// No histogram — fixed-capacity slabs make the coarse scan unnecessary.
// ---------------------------------------------------------------------------

__global__ __launch_bounds__(1024) void prep_a(
    const float* __restrict__ W1l, const float* __restrict__ W1r,
    const float* __restrict__ W2l, const float* __restrict__ W2r,
    u16* __restrict__ T1l, u16* __restrict__ T1r,
    u16* __restrict__ T2l, u16* __restrict__ T2r,
    int* __restrict__ ccursor, u16* __restrict__ x_bf, u16* __restrict__ p2z) {
    const int b = blockIdx.x;
    const int t = threadIdx.x;
    if (b < 128) {
        int id = b * 1024 + t;  // 0..131071
        int which = id >> 15;
        int r = id & 32767;
        if (which == 0) {        // [128][256] -> [256][128]
            int n = r >> 7, k = r & 127;
            T1l[r] = f2bf(W1l[k * 256 + n]);
        } else if (which == 1) {
            int n = r >> 7, k = r & 127;
            T1r[r] = f2bf(W1r[k * 256 + n]);
        } else if (which == 2) {  // [256][128] -> [128][256]
            int n = r >> 8, k = r & 255;
            T2l[r] = f2bf(W2l[k * 128 + n]);
        } else {
            int n = r >> 8, k = r & 255;
            T2r[r] = f2bf(W2r[k * 128 + n]);
        }
    } else {
        if (t < NCB) ccursor[t] = 0;
        uint4 z; z.x = 0; z.y = 0; z.z = 0; z.w = 0;
        if (t >= 512 && t < 528)
            ((uint4*)(x_bf + (size_t)SENT_ROW * 128))[t - 512] = z;
        else if (t >= 528 && t < 544)
            ((uint4*)(p2z + (size_t)SENT_ROW * 128))[t - 528] = z;
    }
}

// ---------------------------------------------------------------------------
// scatter_conv: coarse scatter into fixed slabs (391 blocks) | conv part 1.
// packed = (local8 << 17) | src17 ; slab cb at epkt2[cb*CAP ...].
// ---------------------------------------------------------------------------

__global__ __launch_bounds__(1024) void scatter_conv(
    const int* __restrict__ src, const int* __restrict__ dst,
    int* __restrict__ ccursor, unsigned* __restrict__ epkt2,
    const float* __restrict__ x, u16* __restrict__ x_bf) {
    __shared__ unsigned spkt[SC_EPB];
    __shared__ unsigned short scb[SC_EPB];
    __shared__ int hist[NCB], lstart[NCB], lcur[NCB], grun[NCB], stmp[NCB];

    const int t = threadIdx.x;
    const int b = blockIdx.x;
    if (b >= SC_BLOCKS) {
        conv_chunk(x, x_bf, (b - SC_BLOCKS) * 1024 + t);  // i < 1600512
        return;
    }
    const int e0 = b * SC_EPB;
    const int cnt = min(SC_EPB, N_EDGES_C - e0);

    if (t < NCB) hist[t] = 0;
    __syncthreads();

    int4 dd, ss;
    int i4 = (e0 >> 2) + t;          // one int4 per thread
    int vi = (i4 * 4 < N_EDGES_C);
    if (vi) {
        dd = ((const int4*)dst)[i4];
        ss = ((const int4*)src)[i4];
        atomicAdd(&hist[dd.x >> 8], 1);
        atomicAdd(&hist[dd.y >> 8], 1);
        atomicAdd(&hist[dd.z >> 8], 1);
        atomicAdd(&hist[dd.w >> 8], 1);
    }
    __syncthreads();

    if (t < NCB) stmp[t] = hist[t];
    __syncthreads();
    for (int off = 1; off < NCB; off <<= 1) {
        int v = 0;
        if (t < NCB && t >= off) v = stmp[t - off];
        __syncthreads();
        if (t < NCB) stmp[t] += v;
        __syncthreads();
    }
    if (t < NCB) {
        int excl = stmp[t] - hist[t];
        lstart[t] = excl;
        lcur[t] = excl;
        if (hist[t])
            grun[t] = t * CAP + atomicAdd(&ccursor[t], hist[t]);
    }
    __syncthreads();

    if (vi) {
        {
            int cb = dd.x >> 8;
            int pos = atomicAdd(&lcur[cb], 1);
            spkt[pos] = ((unsigned)(dd.x & 255) << 17) | (unsigned)ss.x;
            scb[pos] = (unsigned short)cb;
        }
        {
            int cb = dd.y >> 8;
            int pos = atomicAdd(&lcur[cb], 1);
            spkt[pos] = ((unsigned)(dd.y & 255) << 17) | (unsigned)ss.y;
            scb[pos] = (unsigned short)cb;
        }
        {
            int cb = dd.z >> 8;
            int pos = atomicAdd(&lcur[cb], 1);
            spkt[pos] = ((unsigned)(dd.z & 255) << 17) | (unsigned)ss.z;
            scb[pos] = (unsigned short)cb;
        }
        {
            int cb = dd.w >> 8;
            int pos = atomicAdd(&lcur[cb], 1);
            spkt[pos] = ((unsigned)(dd.w & 255) << 17) | (unsigned)ss.w;
            scb[pos] = (unsigned short)cb;
        }
    }
    __syncthreads();

#pragma unroll
    for (int k = 0; k < SC_EPB / 1024; ++k) {
        int i = k * 1024 + t;
        if (i < cnt) {
            int cb = scb[i];
            epkt2[grun[cb] + (i - lstart[cb])] = spkt[i];
        }
    }
}

// ---------------------------------------------------------------------------
// sort_conv: fine sort (392 blocks, one per slab) | conv part 2.
// Produces node-contiguous esrc (padded slab layout) + deg[] + base[].
// ---------------------------------------------------------------------------

__global__ __launch_bounds__(1024) void sort_conv(
    const int* __restrict__ ccursor, const unsigned* __restrict__ epkt2,
    unsigned* __restrict__ esrc, int* __restrict__ deg, int* __restrict__ base,
    const float* __restrict__ x, u16* __restrict__ x_bf) {
    __shared__ int hist[256], lstart[256], lcur[256], stmp[256];
    const int t = threadIdx.x;
    const int c = blockIdx.x;
    if (c >= NCB) {
        conv_chunk(x, x_bf, 1600512 + (c - NCB) * 1024 + t);  // < 3.2M
        return;
    }
    const int s0 = c * CAP;
    int cnt = ccursor[c];
    if (cnt > CAP) cnt = CAP;

    if (t < 256) hist[t] = 0;
    __syncthreads();

    for (int i = t; i < cnt; i += 1024)
        atomicAdd(&hist[epkt2[s0 + i] >> 17], 1);
    __syncthreads();

    if (t < 256) stmp[t] = hist[t];
    __syncthreads();
    for (int off = 1; off < 256; off <<= 1) {
        int v = 0;
        if (t < 256 && t >= off) v = stmp[t - off];
        __syncthreads();
        if (t < 256) stmp[t] += v;
        __syncthreads();
    }
    if (t < 256) {
        int excl = stmp[t] - hist[t];
        lstart[t] = excl;
        lcur[t] = excl;
        int node = c * 256 + t;
        if (node < N_NODES_C) {
            deg[node] = hist[t];
            base[node] = s0 + excl;
        }
    }
    __syncthreads();

    for (int i = t; i < cnt; i += 1024) {
        unsigned p = epkt2[s0 + i];
        int pos = atomicAdd(&lcur[p >> 17], 1);
        esrc[s0 + pos] = p & 0x1ffffu;
    }
}

// ---------------------------------------------------------------------------
// Fused per-bucket kernel (512 thr = 8 waves, 4 blocks/CU = 32 waves/CU):
//   gather -> meanS; phase A -> hfrag; phase B -> p2/outp.
// Bs 8KB (half-tile staged sequentially) => LDS 40KB => 4 blk/CU. (512,8)
// caps VGPR at 64 — kernel uses 32 (round-10 measured), no spill.
// ---------------------------------------------------------------------------

__global__ __launch_bounds__(512, 8) void fused_gemm_agg(
    const u16* __restrict__ x_bf, const int* __restrict__ deg,
    const int* __restrict__ base, const unsigned* __restrict__ esrc,
    const u16* __restrict__ T1l, const u16* __restrict__ T1r,   // [256][128]
    const u16* __restrict__ T2l, const u16* __restrict__ T2r,   // [128][256]
    const float* __restrict__ b1, const float* __restrict__ b2,
    u16* __restrict__ p2, u16* __restrict__ outp, int M) {
    alignas(16) __shared__ u16 uni[64 * 256];  // 32KB: [meanS|xS] then hfrag
    alignas(16) __shared__ u16 Bs[4096];       // 8KB weight staging (half-tile)

    u16* const meanS = uni;           // [64][128], 16B-chunk ^ (row&7)
    u16* const xS = uni + 64 * 128;   // [64][128], same swizzle
    u16* const hfrag = uni;           // phase-B alias (32KB)

    const int tid = threadIdx.x;
    const int lane = tid & 63;
    const int wave = tid >> 6;
    const int qm = lane & 15;
    const int quad = lane >> 4;
    const int b = blockIdx.x;
    const int m0 = b * 64;

    // ---- issue xS staging early (lands during gather) ----
#pragma unroll
    for (int r = 0; r < 2; ++r) {
        int c = r * 512 + tid;          // 1024 chunks of 16B
        int row = c >> 4, q16 = c & 15;
        __builtin_amdgcn_global_load_lds(
            (const __attribute__((address_space(1))) unsigned*)(
                x_bf + (size_t)(m0 + row) * 128 + ((q16 ^ (row & 7)) * 8)),
            (__attribute__((address_space(3))) unsigned*)(xS + c * 8), 16, 0, 0);
    }

    // ---- gather + mean -> meanS (bf16, swizzled) ----
    const int li8 = qm * 8;
    const int gbase = lane & 48;  // group base lane within wave

    for (int pass = 0; pass < 2; ++pass) {
        int n = pass * 32 + wave * 4 + quad;   // 0..63
        int node = m0 + n;
        int d = 0, s0 = 0;
        if (node < N_NODES_C) { d = deg[node]; s0 = base[node]; }
        int dmax = max(d, __shfl_xor(d, 16, 64));
        dmax = max(dmax, __shfl_xor(dmax, 32, 64));

        float a0 = 0.f, a1 = 0.f, a2 = 0.f, a3 = 0.f;
        float a4 = 0.f, a5 = 0.f, a6 = 0.f, a7 = 0.f;

        for (int j = 0; j < dmax; j += 16) {
            int jj = j + qm;
            unsigned sidx = (jj < d) ? esrc[s0 + jj] : (unsigned)SENT_ROW;
            for (int u = 0; u < 16 && j + u < dmax; u += 4) {
                unsigned i0 = __shfl(sidx, gbase + u, 64);
                unsigned i1 = __shfl(sidx, gbase + u + 1, 64);
                unsigned i2 = __shfl(sidx, gbase + u + 2, 64);
                unsigned i3 = __shfl(sidx, gbase + u + 3, 64);
                uint4 r0 = *(const uint4*)(x_bf + (size_t)i0 * 128 + li8);
                uint4 r1 = *(const uint4*)(x_bf + (size_t)i1 * 128 + li8);
                uint4 r2 = *(const uint4*)(x_bf + (size_t)i2 * 128 + li8);
                uint4 r3 = *(const uint4*)(x_bf + (size_t)i3 * 128 + li8);
                a0 += lo16f(r0.x); a1 += hi16f(r0.x);
                a2 += lo16f(r0.y); a3 += hi16f(r0.y);
                a4 += lo16f(r0.z); a5 += hi16f(r0.z);
                a6 += lo16f(r0.w); a7 += hi16f(r0.w);
                a0 += lo16f(r1.x); a1 += hi16f(r1.x);
                a2 += lo16f(r1.y); a3 += hi16f(r1.y);
                a4 += lo16f(r1.z); a5 += hi16f(r1.z);
                a6 += lo16f(r1.w); a7 += hi16f(r1.w);
                a0 += lo16f(r2.x); a1 += hi16f(r2.x);
                a2 += lo16f(r2.y); a3 += hi16f(r2.y);
                a4 += lo16f(r2.z); a5 += hi16f(r2.z);
                a6 += lo16f(r2.w); a7 += hi16f(r2.w);
                a0 += lo16f(r3.x); a1 += hi16f(r3.x);
                a2 += lo16f(r3.y); a3 += hi16f(r3.y);
                a4 += lo16f(r3.z); a5 += hi16f(r3.z);
                a6 += lo16f(r3.w); a7 += hi16f(r3.w);
            }
        }

        float inv = d > 0 ? 1.f / (float)d : 0.f;
        uint4 o;
        o.x = (unsigned)f2bf(a0 * inv) | ((unsigned)f2bf(a1 * inv) << 16);
        o.y = (unsigned)f2bf(a2 * inv) | ((unsigned)f2bf(a3 * inv) << 16);
        o.z = (unsigned)f2bf(a4 * inv) | ((unsigned)f2bf(a5 * inv) << 16);
        o.w = (unsigned)f2bf(a6 * inv) | ((unsigned)f2bf(a7 * inv) << 16);
        *(uint4*)(meanS + n * 128 + ((qm ^ (n & 7)) * 8)) = o;
    }
    __syncthreads();

    // ------- phase A: h tile (8 waves: 4M x 2N-of-64, two 128-col halves) ----
    const int wr0 = (wave >> 1) * 16;   // rows 0/16/32/48
    const int wcA = (wave & 1) * 64;    // col offset within 128-half
    f32x4 acch[8];                      // [h*4 + j]
#pragma unroll
    for (int j = 0; j < 8; ++j) acch[j] = (f32x4){0.f, 0.f, 0.f, 0.f};

#pragma unroll
    for (int mat = 0; mat < 2; ++mat) {
        const u16* __restrict__ W = mat ? T1r : T1l;
        const u16* Al = mat ? xS : meanS;
#pragma unroll
        for (int k0 = 0; k0 < 128; k0 += 32) {
            int ch0 = k0 >> 3;
            int rowA = wr0 + qm;
            bf16x8 af = *(const bf16x8*)(Al + rowA * 128 +
                                         (((ch0 + quad) ^ (rowA & 7)) * 8));
#pragma unroll
            for (int h = 0; h < 2; ++h) {
                // stage half: Bs[128][32] (512 chunks, 1/thread), pre-swizzled
                {
                    int c = tid;
                    int row = c >> 2, kc = c & 3;
                    __builtin_amdgcn_global_load_lds(
                        (const __attribute__((address_space(1))) unsigned*)(
                            W + (size_t)(h * 128 + row) * 128 + k0 +
                            ((kc ^ (row & 3)) * 8)),
                        (__attribute__((address_space(3))) unsigned*)(Bs + c * 8),
                        16, 0, 0);
                }
                __syncthreads();
#pragma unroll
                for (int j = 0; j < 4; ++j) {
                    int rB = wcA + j * 16 + qm;  // local row in half
                    bf16x8 bv = *(const bf16x8*)(Bs + rB * 32 +
                                                 ((quad ^ (rB & 3)) * 8));
                    acch[h * 4 + j] = __builtin_amdgcn_mfma_f32_16x16x32_bf16(
                        af, bv, acch[h * 4 + j], 0, 0, 0);
                }
                __syncthreads();
            }
        }
    }

    // epilogue A: +b1, relu, write to hfrag (aliases meanS/xS — dead now)
#pragma unroll
    for (int h = 0; h < 2; ++h) {
#pragma unroll
        for (int j = 0; j < 4; ++j) {
            int n = h * 128 + wcA + j * 16 + qm;
            float bb = b1[n];
            int ks = n >> 5, quadB = (n >> 3) & 3, jB = n & 7;
#pragma unroll
            for (int r = 0; r < 4; ++r) {
                int mloc = wr0 + quad * 4 + r;
                float v = fmaxf(acch[h * 4 + j][r] + bb, 0.f);
                hfrag[((ks * 4 + (mloc >> 4)) * 16 + (mloc & 15)) * 32 +
                      quadB * 8 + jB] = f2bf(v);
            }
        }
    }
    __syncthreads();

    // ------- phase B: p2 / outp (8 waves: 4M x 2N; W2l then W2r) ----------
    const int wrB = (wave >> 1) * 16;   // rows 0/16/32/48
    const int wcB = (wave & 1) * 64;    // cols 0/64 (of 128)
    f32x4 accp[4], acco[4];
#pragma unroll
    for (int j = 0; j < 4; ++j) {
        accp[j] = (f32x4){0.f, 0.f, 0.f, 0.f};
        acco[j] = (f32x4){0.f, 0.f, 0.f, 0.f};
    }

#pragma unroll
    for (int ks = 0; ks < 8; ++ks) {
        bf16x8 af = *(const bf16x8*)(hfrag +
                                     ((ks * 4 + (wrB >> 4)) * 16 + qm) * 32 + quad * 8);
#pragma unroll
        for (int half = 0; half < 2; ++half) {
            const u16* W = half ? T2r : T2l;
            {
                int c = tid;
                int row = c >> 2, kc = c & 3;
                __builtin_amdgcn_global_load_lds(
                    (const __attribute__((address_space(1))) unsigned*)(
                        W + (size_t)row * 256 + ks * 32 + ((kc ^ (row & 3)) * 8)),
                    (__attribute__((address_space(3))) unsigned*)(Bs + c * 8),
                    16, 0, 0);
            }
            __syncthreads();
            f32x4* acc = half ? acco : accp;
#pragma unroll
            for (int j = 0; j < 4; ++j) {
                int rB = wcB + j * 16 + qm;
                bf16x8 bv = *(const bf16x8*)(Bs + rB * 32 +
                                             ((quad ^ (rB & 3)) * 8));
                acc[j] = __builtin_amdgcn_mfma_f32_16x16x32_bf16(af, bv,
                                                                 acc[j], 0, 0, 0);
            }
            __syncthreads();
        }
    }

    // epilogue B
#pragma unroll
    for (int j = 0; j < 4; ++j) {
        int n = wcB + j * 16 + qm;
        float bb2 = b2[n];
#pragma unroll
        for (int r = 0; r < 4; ++r) {
            int row = m0 + wrB + quad * 4 + r;
            if (row < M) {
                p2[(size_t)row * 128 + n] = f2bf(accp[j][r]);
                outp[(size_t)row * 128 + n] = f2bf(acco[j][r] + bb2);
            }
        }
    }
}

// ---------------------------------------------------------------------------
// Final aggregation: out = mean_{src->node} p2 + outp  (fp32). LDS-free.
// ---------------------------------------------------------------------------

__global__ __launch_bounds__(256, 8) void agg_final(const u16* __restrict__ tbl,
                                                    const int* __restrict__ deg,
                                                    const int* __restrict__ base,
                                                    const unsigned* __restrict__ esrc,
                                                    const u16* __restrict__ resid,
                                                    float* __restrict__ outv) {
    const int t = threadIdx.x;
    const int wave = t >> 6;
    const int lane = t & 63;
    const int qm = lane & 15;
    const int quad = lane >> 4;
    const int b = blockIdx.x;
    const int li8 = qm * 8;
    const int gbase = lane & 48;

    for (int pass = 0; pass < 4; ++pass) {
        int n = pass * 16 + wave * 4 + quad;   // 0..63
        int node = b * NPB + n;
        bool valid = node < N_NODES_C;
        int d = 0, s0 = 0;
        if (valid) { d = deg[node]; s0 = base[node]; }
        int dmax = max(d, __shfl_xor(d, 16, 64));
        dmax = max(dmax, __shfl_xor(dmax, 32, 64));

        float a0 = 0.f, a1 = 0.f, a2 = 0.f, a3 = 0.f;
        float a4 = 0.f, a5 = 0.f, a6 = 0.f, a7 = 0.f;

        for (int j = 0; j < dmax; j += 16) {
            int jj = j + qm;
            unsigned sidx = (jj < d) ? esrc[s0 + jj] : (unsigned)SENT_ROW;
            for (int u = 0; u < 16 && j + u < dmax; u += 4) {
                unsigned i0 = __shfl(sidx, gbase + u, 64);
                unsigned i1 = __shfl(sidx, gbase + u + 1, 64);
                unsigned i2 = __shfl(sidx, gbase + u + 2, 64);
                unsigned i3 = __shfl(sidx, gbase + u + 3, 64);
                uint4 r0 = *(const uint4*)(tbl + (size_t)i0 * 128 + li8);
                uint4 r1 = *(const uint4*)(tbl + (size_t)i1 * 128 + li8);
                uint4 r2 = *(const uint4*)(tbl + (size_t)i2 * 128 + li8);
                uint4 r3 = *(const uint4*)(tbl + (size_t)i3 * 128 + li8);
                a0 += lo16f(r0.x); a1 += hi16f(r0.x);
                a2 += lo16f(r0.y); a3 += hi16f(r0.y);
                a4 += lo16f(r0.z); a5 += hi16f(r0.z);
                a6 += lo16f(r0.w); a7 += hi16f(r0.w);
                a0 += lo16f(r1.x); a1 += hi16f(r1.x);
                a2 += lo16f(r1.y); a3 += hi16f(r1.y);
                a4 += lo16f(r1.z); a5 += hi16f(r1.z);
                a6 += lo16f(r1.w); a7 += hi16f(r1.w);
                a0 += lo16f(r2.x); a1 += hi16f(r2.x);
                a2 += lo16f(r2.y); a3 += hi16f(r2.y);
                a4 += lo16f(r2.z); a5 += hi16f(r2.z);
                a6 += lo16f(r2.w); a7 += hi16f(r2.w);
                a0 += lo16f(r3.x); a1 += hi16f(r3.x);
                a2 += lo16f(r3.y); a3 += hi16f(r3.y);
                a4 += lo16f(r3.z); a5 += hi16f(r3.z);
                a6 += lo16f(r3.w); a7 += hi16f(r3.w);
            }
        }

        if (valid) {
            float inv = d > 0 ? 1.f / (float)d : 0.f;
            uint4 rp = *(const uint4*)(resid + (size_t)node * 128 + li8);
            float* op = outv + (size_t)node * 128 + li8;
            float4 o0, o1;
            o0.x = a0 * inv + lo16f(rp.x);
            o0.y = a1 * inv + hi16f(rp.x);
            o0.z = a2 * inv + lo16f(rp.y);
            o0.w = a3 * inv + hi16f(rp.y);
            o1.x = a4 * inv + lo16f(rp.z);
            o1.y = a5 * inv + hi16f(rp.z);
            o1.z = a6 * inv + lo16f(rp.w);
            o1.w = a7 * inv + hi16f(rp.w);
            *(float4*)op = o0;
            *(float4*)(op + 4) = o1;
        }
    }
}

// ---------------------------------------------------------------------------
// launch
// ---------------------------------------------------------------------------

extern "C" void kernel_launch(void* const* d_in, const int* in_sizes, int n_in,
                              void* d_out, int out_size, void* d_ws, size_t ws_size,
                              hipStream_t stream) {
    const float* x = (const float*)d_in[0];
    const int* ei = (const int*)d_in[1];
    const float* W1l = (const float*)d_in[2];
    const float* b1 = (const float*)d_in[3];
    const float* W1r = (const float*)d_in[4];
    const float* W2l = (const float*)d_in[5];
    const float* b2 = (const float*)d_in[6];
    const float* W2r = (const float*)d_in[7];
    float* out = (float*)d_out;

    const int* src = ei;
    const int* dst = ei + N_EDGES_C;

    // int workspace region (first 20 MiB)
    int* iw = (int*)d_ws;
    int* ccursor = iw;                            // 512 (392 used)
    int* deg = iw + 512;                          // 100352
    int* base = iw + 100864;                      // 100352
    unsigned* epkt2 = (unsigned*)(iw + 201216);   // 392*5120 = 2007040
    unsigned* esrc = (unsigned*)(iw + 2208256);   // 2007040 -> ends 4215296
    u16* T1l = (u16*)(iw + 4215296);              // 4 x 32768 u16 = 256 KB
    u16* T1r = T1l + 32768;
    u16* T2l = T1r + 32768;
    u16* T2r = T2l + 32768;                       // ends ~17.1 MB < 20 MiB
    // bf16 region at byte offset 20 MiB; stride 12.85M u16 (sentinel row pad)
    u16* ub = (u16*)((char*)d_ws + (20u << 20));
    u16* x_bf = ub;                               // [100001][128]
    u16* p2 = ub + 12850000;                      // [100001][128]
    u16* outp = ub + 25700000;                    // [100000][128]

    // weight transpose | sentinel zero | ccursor zero
    prep_a<<<129, 1024, 0, stream>>>(W1l, W1r, W2l, W2r, T1l, T1r, T2l, T2r,
                                     ccursor, x_bf, p2);
    // coarse scatter (fixed slabs) || x conversion part 1
    scatter_conv<<<SC_BLOCKS + CONV1_BLOCKS, 1024, 0, stream>>>(
        src, dst, ccursor, epkt2, x, x_bf);
    // fine sort || x conversion part 2
    sort_conv<<<NCB + CONV2_BLOCKS, 1024, 0, stream>>>(
        ccursor, epkt2, esrc, deg, base, x, x_bf);

    // per bucket: gather-mean + GEMM L1 + GEMM L2 -> p2, outp
    fused_gemm_agg<<<NB, 512, 0, stream>>>(x_bf, deg, base, esrc, T1l, T1r, T2l,
                                           T2r, b1, b2, p2, outp, N_NODES_C);
    // out = mean_{src->node} p2 + outp   (fp32)
    agg_final<<<NB, 256, 0, stream>>>(p2, deg, base, esrc, outp, out);
}

// Round 12
// 325.829 us; speedup vs baseline: 1.8169x; 1.0158x over previous
//
#include <hip/hip_runtime.h>
#include <cstddef>

#define N_NODES_C 100000
#define N_EDGES_C 1600000

#define NPB 64               // nodes per block tile (= GEMM M-tile)
#define NB 1563              // ceil(100000/64)
#define SENT_ROW 100000      // zeroed sentinel row in feature tables

#define NCB 392              // coarse buckets of 256 nodes: ceil(100000/256)
#define CAP 5120             // fixed slab per coarse bucket (mean 4096, +16 sigma)
#define SC_EPB 8192          // edges per scatter block
#define SC_BLOCKS 196        // ceil(1600000/8192)

#define WB_BLOCKS 128        // weight transpose blocks (1024 thr)
#define CONV1_BLOCKS 1563    // conv float4 blocks in scatter_conv (1024/blk)
#define CONV2_BLOCKS 1562    // conv float4 blocks in sort_conv

typedef unsigned short u16;
typedef __attribute__((ext_vector_type(8))) short bf16x8;
typedef __attribute__((ext_vector_type(4))) float f32x4;

__device__ __forceinline__ u16 f2bf(float f) {
    unsigned u = __float_as_uint(f);
    u += 0x7fffu + ((u >> 16) & 1);  // round-to-nearest-even
    return (u16)(u >> 16);
}
__device__ __forceinline__ float lo16f(unsigned v) {
    return __uint_as_float(v << 16);
}
__device__ __forceinline__ float hi16f(unsigned v) {
    return __uint_as_float(v & 0xffff0000u);
}

__device__ __forceinline__ void conv_chunk(const float* __restrict__ x,
                                           u16* __restrict__ x_bf, int i) {
    float4 v = ((const float4*)x)[i];
    ushort4 o;
    o.x = f2bf(v.x); o.y = f2bf(v.y); o.z = f2bf(v.z); o.w = f2bf(v.w);
    ((ushort4*)x_bf)[i] = o;
}

// ---------------------------------------------------------------------------
// scatter_conv: coarse scatter into fixed slabs (196 blocks, 8192 edges each)
// | weight transpose (128 blocks) | sentinel zero (1 block) | conv part 1
// (1563 blocks). ccursor pre-zeroed by hipMemsetAsync.
// packed = (local8 << 17) | src17 ; slab cb at epkt2[cb*CAP ...].
// ---------------------------------------------------------------------------

__global__ __launch_bounds__(1024) void scatter_conv(
    const int* __restrict__ src, const int* __restrict__ dst,
    int* __restrict__ ccursor, unsigned* __restrict__ epkt2,
    const float* __restrict__ W1l, const float* __restrict__ W1r,
    const float* __restrict__ W2l, const float* __restrict__ W2r,
    u16* __restrict__ T1l, u16* __restrict__ T1r,
    u16* __restrict__ T2l, u16* __restrict__ T2r,
    const float* __restrict__ x, u16* __restrict__ x_bf, u16* __restrict__ p2z) {
    __shared__ unsigned spkt[SC_EPB];
    __shared__ unsigned short scb[SC_EPB];
    __shared__ int hist[NCB], lstart[NCB], lcur[NCB], grun[NCB], stmp[NCB];

    const int t = threadIdx.x;
    const int b = blockIdx.x;
    if (b >= SC_BLOCKS) {
        if (b < SC_BLOCKS + WB_BLOCKS) {
            int id = (b - SC_BLOCKS) * 1024 + t;  // 0..131071
            int which = id >> 15;
            int r = id & 32767;
            if (which == 0) {        // [128][256] -> [256][128]
                int n = r >> 7, k = r & 127;
                T1l[r] = f2bf(W1l[k * 256 + n]);
            } else if (which == 1) {
                int n = r >> 7, k = r & 127;
                T1r[r] = f2bf(W1r[k * 256 + n]);
            } else if (which == 2) {  // [256][128] -> [128][256]
                int n = r >> 8, k = r & 255;
                T2l[r] = f2bf(W2l[k * 128 + n]);
            } else {
                int n = r >> 8, k = r & 255;
                T2r[r] = f2bf(W2r[k * 128 + n]);
            }
        } else if (b == SC_BLOCKS + WB_BLOCKS) {
            uint4 z; z.x = 0; z.y = 0; z.z = 0; z.w = 0;
            if (t < 16)
                ((uint4*)(x_bf + (size_t)SENT_ROW * 128))[t] = z;
            else if (t < 32)
                ((uint4*)(p2z + (size_t)SENT_ROW * 128))[t - 16] = z;
        } else {
            conv_chunk(x, x_bf, (b - SC_BLOCKS - WB_BLOCKS - 1) * 1024 + t);
        }
        return;
    }
    const int e0 = b * SC_EPB;
    const int cnt = min(SC_EPB, N_EDGES_C - e0);

    if (t < NCB) hist[t] = 0;
    __syncthreads();

    int4 dd[2], ss[2];
    int vi[2];
#pragma unroll
    for (int r = 0; r < 2; ++r) {
        int i = (e0 >> 2) + r * 1024 + t;  // int4 index
        vi[r] = (i * 4 < N_EDGES_C);
        if (vi[r]) {
            dd[r] = ((const int4*)dst)[i];
            ss[r] = ((const int4*)src)[i];
            atomicAdd(&hist[dd[r].x >> 8], 1);
            atomicAdd(&hist[dd[r].y >> 8], 1);
            atomicAdd(&hist[dd[r].z >> 8], 1);
            atomicAdd(&hist[dd[r].w >> 8], 1);
        }
    }
    __syncthreads();

    if (t < NCB) stmp[t] = hist[t];
    __syncthreads();
    for (int off = 1; off < NCB; off <<= 1) {
        int v = 0;
        if (t < NCB && t >= off) v = stmp[t - off];
        __syncthreads();
        if (t < NCB) stmp[t] += v;
        __syncthreads();
    }
    if (t < NCB) {
        int excl = stmp[t] - hist[t];
        lstart[t] = excl;
        lcur[t] = excl;
        if (hist[t])
            grun[t] = t * CAP + atomicAdd(&ccursor[t], hist[t]);
    }
    __syncthreads();

#pragma unroll
    for (int r = 0; r < 2; ++r) {
        if (vi[r]) {
            int4 d = dd[r];
            int4 s4 = ss[r];
            {
                int cb = d.x >> 8;
                int pos = atomicAdd(&lcur[cb], 1);
                spkt[pos] = ((unsigned)(d.x & 255) << 17) | (unsigned)s4.x;
                scb[pos] = (unsigned short)cb;
            }
            {
                int cb = d.y >> 8;
                int pos = atomicAdd(&lcur[cb], 1);
                spkt[pos] = ((unsigned)(d.y & 255) << 17) | (unsigned)s4.y;
                scb[pos] = (unsigned short)cb;
            }
            {
                int cb = d.z >> 8;
                int pos = atomicAdd(&lcur[cb], 1);
                spkt[pos] = ((unsigned)(d.z & 255) << 17) | (unsigned)s4.z;
                scb[pos] = (unsigned short)cb;
            }
            {
                int cb = d.w >> 8;
                int pos = atomicAdd(&lcur[cb], 1);
                spkt[pos] = ((unsigned)(d.w & 255) << 17) | (unsigned)s4.w;
                scb[pos] = (unsigned short)cb;
            }
        }
    }
    __syncthreads();

#pragma unroll
    for (int k = 0; k < SC_EPB / 1024; ++k) {
        int i = k * 1024 + t;
        if (i < cnt) {
            int cb = scb[i];
            epkt2[grun[cb] + (i - lstart[cb])] = spkt[i];
        }
    }
}

// ---------------------------------------------------------------------------
// sort_conv: fine sort (392 blocks, one per slab) | conv part 2.
// Produces node-contiguous esrc (padded slab layout) + deg[] + base[].
// ---------------------------------------------------------------------------

__global__ __launch_bounds__(1024) void sort_conv(
    const int* __restrict__ ccursor, const unsigned* __restrict__ epkt2,
    unsigned* __restrict__ esrc, int* __restrict__ deg, int* __restrict__ base,
    const float* __restrict__ x, u16* __restrict__ x_bf) {
    __shared__ int hist[256], lstart[256], lcur[256], stmp[256];
    const int t = threadIdx.x;
    const int c = blockIdx.x;
    if (c >= NCB) {
        conv_chunk(x, x_bf, 1600512 + (c - NCB) * 1024 + t);  // < 3.2M
        return;
    }
    const int s0 = c * CAP;
    int cnt = ccursor[c];
    if (cnt > CAP) cnt = CAP;

    if (t < 256) hist[t] = 0;
    __syncthreads();

    for (int i = t; i < cnt; i += 1024)
        atomicAdd(&hist[epkt2[s0 + i] >> 17], 1);
    __syncthreads();

    if (t < 256) stmp[t] = hist[t];
    __syncthreads();
    for (int off = 1; off < 256; off <<= 1) {
        int v = 0;
        if (t < 256 && t >= off) v = stmp[t - off];
        __syncthreads();
        if (t < 256) stmp[t] += v;
        __syncthreads();
    }
    if (t < 256) {
        int excl = stmp[t] - hist[t];
        lstart[t] = excl;
        lcur[t] = excl;
        int node = c * 256 + t;
        if (node < N_NODES_C) {
            deg[node] = hist[t];
            base[node] = s0 + excl;
        }
    }
    __syncthreads();

    for (int i = t; i < cnt; i += 1024) {
        unsigned p = epkt2[s0 + i];
        int pos = atomicAdd(&lcur[p >> 17], 1);
        esrc[s0 + pos] = p & 0x1ffffu;
    }
}

// ---------------------------------------------------------------------------
// Fused per-bucket kernel (512 thr = 8 waves, 4 blocks/CU = 32 waves/CU):
//   gather -> meanS; phase A -> hfrag; phase B -> p2/outp.
// Bs 8KB (half-tile staged sequentially) => LDS 40KB => 4 blk/CU. (512,8)
// caps VGPR at 64 — kernel uses 32 (round-10 measured), no spill.
// ---------------------------------------------------------------------------

__global__ __launch_bounds__(512, 8) void fused_gemm_agg(
    const u16* __restrict__ x_bf, const int* __restrict__ deg,
    const int* __restrict__ base, const unsigned* __restrict__ esrc,
    const u16* __restrict__ T1l, const u16* __restrict__ T1r,   // [256][128]
    const u16* __restrict__ T2l, const u16* __restrict__ T2r,   // [128][256]
    const float* __restrict__ b1, const float* __restrict__ b2,
    u16* __restrict__ p2, u16* __restrict__ outp, int M) {
    alignas(16) __shared__ u16 uni[64 * 256];  // 32KB: [meanS|xS] then hfrag
    alignas(16) __shared__ u16 Bs[4096];       // 8KB weight staging (half-tile)

    u16* const meanS = uni;           // [64][128], 16B-chunk ^ (row&7)
    u16* const xS = uni + 64 * 128;   // [64][128], same swizzle
    u16* const hfrag = uni;           // phase-B alias (32KB)

    const int tid = threadIdx.x;
    const int lane = tid & 63;
    const int wave = tid >> 6;
    const int qm = lane & 15;
    const int quad = lane >> 4;
    const int b = blockIdx.x;
    const int m0 = b * 64;

    // ---- issue xS staging early (lands during gather) ----
#pragma unroll
    for (int r = 0; r < 2; ++r) {
        int c = r * 512 + tid;          // 1024 chunks of 16B
        int row = c >> 4, q16 = c & 15;
        __builtin_amdgcn_global_load_lds(
            (const __attribute__((address_space(1))) unsigned*)(
                x_bf + (size_t)(m0 + row) * 128 + ((q16 ^ (row & 7)) * 8)),
            (__attribute__((address_space(3))) unsigned*)(xS + c * 8), 16, 0, 0);
    }

    // ---- gather + mean -> meanS (bf16, swizzled) ----
    const int li8 = qm * 8;
    const int gbase = lane & 48;  // group base lane within wave

    for (int pass = 0; pass < 2; ++pass) {
        int n = pass * 32 + wave * 4 + quad;   // 0..63
        int node = m0 + n;
        int d = 0, s0 = 0;
        if (node < N_NODES_C) { d = deg[node]; s0 = base[node]; }
        int dmax = max(d, __shfl_xor(d, 16, 64));
        dmax = max(dmax, __shfl_xor(dmax, 32, 64));

        float a0 = 0.f, a1 = 0.f, a2 = 0.f, a3 = 0.f;
        float a4 = 0.f, a5 = 0.f, a6 = 0.f, a7 = 0.f;

        for (int j = 0; j < dmax; j += 16) {
            int jj = j + qm;
            unsigned sidx = (jj < d) ? esrc[s0 + jj] : (unsigned)SENT_ROW;
            for (int u = 0; u < 16 && j + u < dmax; u += 4) {
                unsigned i0 = __shfl(sidx, gbase + u, 64);
                unsigned i1 = __shfl(sidx, gbase + u + 1, 64);
                unsigned i2 = __shfl(sidx, gbase + u + 2, 64);
                unsigned i3 = __shfl(sidx, gbase + u + 3, 64);
                uint4 r0 = *(const uint4*)(x_bf + (size_t)i0 * 128 + li8);
                uint4 r1 = *(const uint4*)(x_bf + (size_t)i1 * 128 + li8);
                uint4 r2 = *(const uint4*)(x_bf + (size_t)i2 * 128 + li8);
                uint4 r3 = *(const uint4*)(x_bf + (size_t)i3 * 128 + li8);
                a0 += lo16f(r0.x); a1 += hi16f(r0.x);
                a2 += lo16f(r0.y); a3 += hi16f(r0.y);
                a4 += lo16f(r0.z); a5 += hi16f(r0.z);
                a6 += lo16f(r0.w); a7 += hi16f(r0.w);
                a0 += lo16f(r1.x); a1 += hi16f(r1.x);
                a2 += lo16f(r1.y); a3 += hi16f(r1.y);
                a4 += lo16f(r1.z); a5 += hi16f(r1.z);
                a6 += lo16f(r1.w); a7 += hi16f(r1.w);
                a0 += lo16f(r2.x); a1 += hi16f(r2.x);
                a2 += lo16f(r2.y); a3 += hi16f(r2.y);
                a4 += lo16f(r2.z); a5 += hi16f(r2.z);
                a6 += lo16f(r2.w); a7 += hi16f(r2.w);
                a0 += lo16f(r3.x); a1 += hi16f(r3.x);
                a2 += lo16f(r3.y); a3 += hi16f(r3.y);
                a4 += lo16f(r3.z); a5 += hi16f(r3.z);
                a6 += lo16f(r3.w); a7 += hi16f(r3.w);
            }
        }

        float inv = d > 0 ? 1.f / (float)d : 0.f;
        uint4 o;
        o.x = (unsigned)f2bf(a0 * inv) | ((unsigned)f2bf(a1 * inv) << 16);
        o.y = (unsigned)f2bf(a2 * inv) | ((unsigned)f2bf(a3 * inv) << 16);
        o.z = (unsigned)f2bf(a4 * inv) | ((unsigned)f2bf(a5 * inv) << 16);
        o.w = (unsigned)f2bf(a6 * inv) | ((unsigned)f2bf(a7 * inv) << 16);
        *(uint4*)(meanS + n * 128 + ((qm ^ (n & 7)) * 8)) = o;
    }
    __syncthreads();

    // ------- phase A: h tile (8 waves: 4M x 2N-of-64, two 128-col halves) ----
    const int wr0 = (wave >> 1) * 16;   // rows 0/16/32/48
    const int wcA = (wave & 1) * 64;    // col offset within 128-half
    f32x4 acch[8];                      // [h*4 + j]
#pragma unroll
    for (int j = 0; j < 8; ++j) acch[j] = (f32x4){0.f, 0.f, 0.f, 0.f};

#pragma unroll
    for (int mat = 0; mat < 2; ++mat) {
        const u16* __restrict__ W = mat ? T1r : T1l;
        const u16* Al = mat ? xS : meanS;
#pragma unroll
        for (int k0 = 0; k0 < 128; k0 += 32) {
            int ch0 = k0 >> 3;
            int rowA = wr0 + qm;
            bf16x8 af = *(const bf16x8*)(Al + rowA * 128 +
                                         (((ch0 + quad) ^ (rowA & 7)) * 8));
#pragma unroll
            for (int h = 0; h < 2; ++h) {
                // stage half: Bs[128][32] (512 chunks, 1/thread), pre-swizzled
                {
                    int c = tid;
                    int row = c >> 2, kc = c & 3;
                    __builtin_amdgcn_global_load_lds(
                        (const __attribute__((address_space(1))) unsigned*)(
                            W + (size_t)(h * 128 + row) * 128 + k0 +
                            ((kc ^ (row & 3)) * 8)),
                        (__attribute__((address_space(3))) unsigned*)(Bs + c * 8),
                        16, 0, 0);
                }
                __syncthreads();
#pragma unroll
                for (int j = 0; j < 4; ++j) {
                    int rB = wcA + j * 16 + qm;  // local row in half
                    bf16x8 bv = *(const bf16x8*)(Bs + rB * 32 +
                                                 ((quad ^ (rB & 3)) * 8));
                    acch[h * 4 + j] = __builtin_amdgcn_mfma_f32_16x16x32_bf16(
                        af, bv, acch[h * 4 + j], 0, 0, 0);
                }
                __syncthreads();
            }
        }
    }

    // epilogue A: +b1, relu, write to hfrag (aliases meanS/xS — dead now)
#pragma unroll
    for (int h = 0; h < 2; ++h) {
#pragma unroll
        for (int j = 0; j < 4; ++j) {
            int n = h * 128 + wcA + j * 16 + qm;
            float bb = b1[n];
            int ks = n >> 5, quadB = (n >> 3) & 3, jB = n & 7;
#pragma unroll
            for (int r = 0; r < 4; ++r) {
                int mloc = wr0 + quad * 4 + r;
                float v = fmaxf(acch[h * 4 + j][r] + bb, 0.f);
                hfrag[((ks * 4 + (mloc >> 4)) * 16 + (mloc & 15)) * 32 +
                      quadB * 8 + jB] = f2bf(v);
            }
        }
    }
    __syncthreads();

    // ------- phase B: p2 / outp (8 waves: 4M x 2N; W2l then W2r) ----------
    const int wrB = (wave >> 1) * 16;   // rows 0/16/32/48
    const int wcB = (wave & 1) * 64;    // cols 0/64 (of 128)
    f32x4 accp[4], acco[4];
#pragma unroll
    for (int j = 0; j < 4; ++j) {
        accp[j] = (f32x4){0.f, 0.f, 0.f, 0.f};
        acco[j] = (f32x4){0.f, 0.f, 0.f, 0.f};
    }

#pragma unroll
    for (int ks = 0; ks < 8; ++ks) {
        bf16x8 af = *(const bf16x8*)(hfrag +
                                     ((ks * 4 + (wrB >> 4)) * 16 + qm) * 32 + quad * 8);
#pragma unroll
        for (int half = 0; half < 2; ++half) {
            const u16* W = half ? T2r : T2l;
            {
                int c = tid;
                int row = c >> 2, kc = c & 3;
                __builtin_amdgcn_global_load_lds(
                    (const __attribute__((address_space(1))) unsigned*)(
                        W + (size_t)row * 256 + ks * 32 + ((kc ^ (row & 3)) * 8)),
                    (__attribute__((address_space(3))) unsigned*)(Bs + c * 8),
                    16, 0, 0);
            }
            __syncthreads();
            f32x4* acc = half ? acco : accp;
#pragma unroll
            for (int j = 0; j < 4; ++j) {
                int rB = wcB + j * 16 + qm;
                bf16x8 bv = *(const bf16x8*)(Bs + rB * 32 +
                                             ((quad ^ (rB & 3)) * 8));
                acc[j] = __builtin_amdgcn_mfma_f32_16x16x32_bf16(af, bv,
                                                                 acc[j], 0, 0, 0);
            }
            __syncthreads();
        }
    }

    // epilogue B
#pragma unroll
    for (int j = 0; j < 4; ++j) {
        int n = wcB + j * 16 + qm;
        float bb2 = b2[n];
#pragma unroll
        for (int r = 0; r < 4; ++r) {
            int row = m0 + wrB + quad * 4 + r;
            if (row < M) {
                p2[(size_t)row * 128 + n] = f2bf(accp[j][r]);
                outp[(size_t)row * 128 + n] = f2bf(acco[j][r] + bb2);
            }
        }
    }
}

// ---------------------------------------------------------------------------
// Final aggregation: out = mean_{src->node} p2 + outp  (fp32). LDS-free.
// ---------------------------------------------------------------------------

__global__ __launch_bounds__(256, 8) void agg_final(const u16* __restrict__ tbl,
                                                    const int* __restrict__ deg,
                                                    const int* __restrict__ base,
                                                    const unsigned* __restrict__ esrc,
                                                    const u16* __restrict__ resid,
                                                    float* __restrict__ outv) {
    const int t = threadIdx.x;
    const int wave = t >> 6;
    const int lane = t & 63;
    const int qm = lane & 15;
    const int quad = lane >> 4;
    const int b = blockIdx.x;
    const int li8 = qm * 8;
    const int gbase = lane & 48;

    for (int pass = 0; pass < 4; ++pass) {
        int n = pass * 16 + wave * 4 + quad;   // 0..63
        int node = b * NPB + n;
        bool valid = node < N_NODES_C;
        int d = 0, s0 = 0;
        if (valid) { d = deg[node]; s0 = base[node]; }
        int dmax = max(d, __shfl_xor(d, 16, 64));
        dmax = max(dmax, __shfl_xor(dmax, 32, 64));

        float a0 = 0.f, a1 = 0.f, a2 = 0.f, a3 = 0.f;
        float a4 = 0.f, a5 = 0.f, a6 = 0.f, a7 = 0.f;

        for (int j = 0; j < dmax; j += 16) {
            int jj = j + qm;
            unsigned sidx = (jj < d) ? esrc[s0 + jj] : (unsigned)SENT_ROW;
            for (int u = 0; u < 16 && j + u < dmax; u += 4) {
                unsigned i0 = __shfl(sidx, gbase + u, 64);
                unsigned i1 = __shfl(sidx, gbase + u + 1, 64);
                unsigned i2 = __shfl(sidx, gbase + u + 2, 64);
                unsigned i3 = __shfl(sidx, gbase + u + 3, 64);
                uint4 r0 = *(const uint4*)(tbl + (size_t)i0 * 128 + li8);
                uint4 r1 = *(const uint4*)(tbl + (size_t)i1 * 128 + li8);
                uint4 r2 = *(const uint4*)(tbl + (size_t)i2 * 128 + li8);
                uint4 r3 = *(const uint4*)(tbl + (size_t)i3 * 128 + li8);
                a0 += lo16f(r0.x); a1 += hi16f(r0.x);
                a2 += lo16f(r0.y); a3 += hi16f(r0.y);
                a4 += lo16f(r0.z); a5 += hi16f(r0.z);
                a6 += lo16f(r0.w); a7 += hi16f(r0.w);
                a0 += lo16f(r1.x); a1 += hi16f(r1.x);
                a2 += lo16f(r1.y); a3 += hi16f(r1.y);
                a4 += lo16f(r1.z); a5 += hi16f(r1.z);
                a6 += lo16f(r1.w); a7 += hi16f(r1.w);
                a0 += lo16f(r2.x); a1 += hi16f(r2.x);
                a2 += lo16f(r2.y); a3 += hi16f(r2.y);
                a4 += lo16f(r2.z); a5 += hi16f(r2.z);
                a6 += lo16f(r2.w); a7 += hi16f(r2.w);
                a0 += lo16f(r3.x); a1 += hi16f(r3.x);
                a2 += lo16f(r3.y); a3 += hi16f(r3.y);
                a4 += lo16f(r3.z); a5 += hi16f(r3.z);
                a6 += lo16f(r3.w); a7 += hi16f(r3.w);
            }
        }

        if (valid) {
            float inv = d > 0 ? 1.f / (float)d : 0.f;
            uint4 rp = *(const uint4*)(resid + (size_t)node * 128 + li8);
            float* op = outv + (size_t)node * 128 + li8;
            float4 o0, o1;
            o0.x = a0 * inv + lo16f(rp.x);
            o0.y = a1 * inv + hi16f(rp.x);
            o0.z = a2 * inv + lo16f(rp.y);
            o0.w = a3 * inv + hi16f(rp.y);
            o1.x = a4 * inv + lo16f(rp.z);
            o1.y = a5 * inv + hi16f(rp.z);
            o1.z = a6 * inv + lo16f(rp.w);
            o1.w = a7 * inv + hi16f(rp.w);
            *(float4*)op = o0;
            *(float4*)(op + 4) = o1;
        }
    }
}

// ---------------------------------------------------------------------------
// launch
// ---------------------------------------------------------------------------

extern "C" void kernel_launch(void* const* d_in, const int* in_sizes, int n_in,
                              void* d_out, int out_size, void* d_ws, size_t ws_size,
                              hipStream_t stream) {
    const float* x = (const float*)d_in[0];
    const int* ei = (const int*)d_in[1];
    const float* W1l = (const float*)d_in[2];
    const float* b1 = (const float*)d_in[3];
    const float* W1r = (const float*)d_in[4];
    const float* W2l = (const float*)d_in[5];
    const float* b2 = (const float*)d_in[6];
    const float* W2r = (const float*)d_in[7];
    float* out = (float*)d_out;

    const int* src = ei;
    const int* dst = ei + N_EDGES_C;

    // int workspace region (first 20 MiB)
    int* iw = (int*)d_ws;
    int* ccursor = iw;                            // 512 (392 used)
    int* deg = iw + 512;                          // 100352
    int* base = iw + 100864;                      // 100352
    unsigned* epkt2 = (unsigned*)(iw + 201216);   // 392*5120 = 2007040
    unsigned* esrc = (unsigned*)(iw + 2208256);   // 2007040 -> ends 4215296
    u16* T1l = (u16*)(iw + 4215296);              // 4 x 32768 u16 = 256 KB
    u16* T1r = T1l + 32768;
    u16* T2l = T1r + 32768;
    u16* T2r = T2l + 32768;                       // ends ~17.1 MB < 20 MiB
    // bf16 region at byte offset 20 MiB; stride 12.85M u16 (sentinel row pad)
    u16* ub = (u16*)((char*)d_ws + (20u << 20));
    u16* x_bf = ub;                               // [100001][128]
    u16* p2 = ub + 12850000;                      // [100001][128]
    u16* outp = ub + 25700000;                    // [100000][128]

    hipMemsetAsync(ccursor, 0, NCB * sizeof(int), stream);

    // coarse scatter (fixed slabs) | weight transpose | sentinel | conv part 1
    scatter_conv<<<SC_BLOCKS + WB_BLOCKS + 1 + CONV1_BLOCKS, 1024, 0, stream>>>(
        src, dst, ccursor, epkt2, W1l, W1r, W2l, W2r, T1l, T1r, T2l, T2r,
        x, x_bf, p2);
    // fine sort || x conversion part 2
    sort_conv<<<NCB + CONV2_BLOCKS, 1024, 0, stream>>>(
        ccursor, epkt2, esrc, deg, base, x, x_bf);

    // per bucket: gather-mean + GEMM L1 + GEMM L2 -> p2, outp
    fused_gemm_agg<<<NB, 512, 0, stream>>>(x_bf, deg, base, esrc, T1l, T1r, T2l,
                                           T2r, b1, b2, p2, outp, N_NODES_C);
    // out = mean_{src->node} p2 + outp   (fp32)
    agg_final<<<NB, 256, 0, stream>>>(p2, deg, base, esrc, outp, out);
}